// Round 2
// baseline (10473.388 us; speedup 1.0000x reference)
//
#include <hip/hip_runtime.h>
#include <hip/hip_bf16.h>
#include <math.h>

typedef __hip_bfloat16 bf16;

#define B_ 8
#define HEADS_ 4
#define KV_ 960
#define HW_ 1024
#define CKV_ 3840   // KV_*HEADS_

// ---------------------------------------------------------------------------
// wave/block reduce helpers
// ---------------------------------------------------------------------------
__device__ __forceinline__ float wredsum(float v) {
#pragma unroll
  for (int o = 32; o > 0; o >>= 1) v += __shfl_xor(v, o);
  return v;
}
__device__ __forceinline__ float wredmax(float v) {
#pragma unroll
  for (int o = 32; o > 0; o >>= 1) v = fmaxf(v, __shfl_xor(v, o));
  return v;
}

// ---------------------------------------------------------------------------
// K1: 1x1 conv as GEMM.  Y[b][m][n] = sum_k W[m][k] * X[b][k][n],  N = 1024.
// grid: (N/256, M/16, nb); block 256. Each thread: 16 m-rows, 1 n.
// ---------------------------------------------------------------------------
template <typename OutT>
__global__ void __launch_bounds__(256) gemm_wx(const float* __restrict__ W,
                                               const float* __restrict__ X,
                                               OutT* __restrict__ Y,
                                               int M, int K) {
  const int n = (blockIdx.x << 8) + threadIdx.x;
  const int m0 = blockIdx.y << 4;
  const int b = blockIdx.z;
  const float* Xb = X + ((size_t)b * K << 10) + n;
  const float* Wb = W + (size_t)m0 * K;
  float acc[16];
#pragma unroll
  for (int i = 0; i < 16; i++) acc[i] = 0.f;
#pragma unroll 4
  for (int k = 0; k < K; k++) {
    float x = Xb[k << 10];
#pragma unroll
    for (int i = 0; i < 16; i++) acc[i] += Wb[i * K + k] * x;
  }
  size_t base = (((size_t)b * M + m0) << 10) + n;
#pragma unroll
  for (int i = 0; i < 16; i++) {
    float r = acc[i];
    if constexpr (__is_same(OutT, bf16)) {
      Y[base + ((size_t)i << 10)] = __float2bfloat16(r);
    } else {
      Y[base + ((size_t)i << 10)] = r;
    }
  }
}

// ---------------------------------------------------------------------------
// K2: depthwise 3x3 (pad 1) on 32x32 planes, optional fused l2norm over plane.
// grid: nb*C blocks; block 1024 = one (b,ch) plane.
// ---------------------------------------------------------------------------
template <bool NORM>
__global__ void __launch_bounds__(1024) dw3x3(const bf16* __restrict__ in,
                                              const float* __restrict__ w9,
                                              bf16* __restrict__ out, int C) {
  __shared__ float tile[34][34];
  __shared__ float red[16];
  const int bc = blockIdx.x;
  const int ch = bc % C;
  const int tid = threadIdx.x;
  const int x = tid & 31, y = tid >> 5;
  const bf16* ip = in + ((size_t)bc << 10);

  tile[y + 1][x + 1] = __bfloat162float(ip[tid]);
  if (y == 0) { tile[0][x + 1] = 0.f; tile[33][x + 1] = 0.f; }
  if (x == 0) { tile[y + 1][0] = 0.f; tile[y + 1][33] = 0.f; }
  if (tid == 0) { tile[0][0] = 0.f; tile[0][33] = 0.f; tile[33][0] = 0.f; tile[33][33] = 0.f; }
  __syncthreads();

  const float* wc = w9 + ch * 9;
  float w[9];
#pragma unroll
  for (int u = 0; u < 9; u++) w[u] = wc[u];
  float s = 0.f;
#pragma unroll
  for (int dy = 0; dy < 3; dy++)
#pragma unroll
    for (int dx = 0; dx < 3; dx++) s += tile[y + dy][x + dx] * w[dy * 3 + dx];

  bf16* op = out + ((size_t)bc << 10);
  if (NORM) {
    float ss = wredsum(s * s);
    const int lane = tid & 63, wid = tid >> 6;
    if (lane == 0) red[wid] = ss;
    __syncthreads();
    if (wid == 0) {
      float r = (lane < 16) ? red[lane] : 0.f;
      r = wredsum(r);
      if (lane == 0) red[0] = 1.0f / fmaxf(sqrtf(r), 1e-12f);
    }
    __syncthreads();
    op[tid] = __float2bfloat16(s * red[0]);
  } else {
    op[tid] = __float2bfloat16(s);
  }
}

// ---------------------------------------------------------------------------
// K3: grouped 3x3 (2 in-ch per group, pad 1) + fused l2norm over plane.
// grid: nb*C4 blocks; block 1024 = one (b,o) output plane.
// ---------------------------------------------------------------------------
__global__ void __launch_bounds__(1024) gq3x3norm(const bf16* __restrict__ in,
                                                  const float* __restrict__ wq,
                                                  bf16* __restrict__ out, int C4) {
  __shared__ float t0[34][34];
  __shared__ float t1[34][34];
  __shared__ float red[16];
  const int bo = blockIdx.x;
  const int o = bo % C4;
  const int b = bo / C4;
  const int ic0 = (o >> 1) << 1;
  const int tid = threadIdx.x;
  const int x = tid & 31, y = tid >> 5;
  const bf16* p0 = in + (((size_t)b * C4 + ic0) << 10);

  t0[y + 1][x + 1] = __bfloat162float(p0[tid]);
  t1[y + 1][x + 1] = __bfloat162float(p0[1024 + tid]);
  if (y == 0) { t0[0][x + 1] = 0.f; t0[33][x + 1] = 0.f; t1[0][x + 1] = 0.f; t1[33][x + 1] = 0.f; }
  if (x == 0) { t0[y + 1][0] = 0.f; t0[y + 1][33] = 0.f; t1[y + 1][0] = 0.f; t1[y + 1][33] = 0.f; }
  if (tid == 0) {
    t0[0][0] = t0[0][33] = t0[33][0] = t0[33][33] = 0.f;
    t1[0][0] = t1[0][33] = t1[33][0] = t1[33][33] = 0.f;
  }
  __syncthreads();

  const float* w = wq + o * 18;
  float s = 0.f;
#pragma unroll
  for (int dy = 0; dy < 3; dy++)
#pragma unroll
    for (int dx = 0; dx < 3; dx++) {
      s += t0[y + dy][x + dx] * w[dy * 3 + dx];
      s += t1[y + dy][x + dx] * w[9 + dy * 3 + dx];
    }

  float ss = wredsum(s * s);
  const int lane = tid & 63, wid = tid >> 6;
  if (lane == 0) red[wid] = ss;
  __syncthreads();
  if (wid == 0) {
    float r = (lane < 16) ? red[lane] : 0.f;
    r = wredsum(r);
    if (lane == 0) red[0] = 1.0f / fmaxf(sqrtf(r), 1e-12f);
  }
  __syncthreads();
  out[((size_t)bo << 10) + tid] = __float2bfloat16(s * red[0]);
}

// ---------------------------------------------------------------------------
// K4: attn[b][h][i][j] = scale * sum_n q[b][h*c+i][n] * k[b][h*960+j][n]
// grid: (960/64, c/64, nb*4); block 256; 64x64 tile, 4x4 micro-tile.
// ---------------------------------------------------------------------------
__global__ void __launch_bounds__(256) attn_gemm(const bf16* __restrict__ q,
                                                 const bf16* __restrict__ k,
                                                 float* __restrict__ attn,
                                                 int c, float scale) {
  __shared__ float qs[64][65];
  __shared__ float ks[64][65];
  const int tid = threadIdx.x;
  const int tx = tid & 15, ty = tid >> 4;
  const int bh = blockIdx.z, b = bh >> 2, h = bh & 3;
  const int i0 = blockIdx.y << 6, j0 = blockIdx.x << 6;
  const bf16* qp = q + (((size_t)b * 4 * c + (size_t)h * c + i0) << 10);
  const bf16* kp = k + (((size_t)b * CKV_ + h * KV_ + j0) << 10);

  float acc[4][4];
#pragma unroll
  for (int a = 0; a < 4; a++)
#pragma unroll
    for (int d = 0; d < 4; d++) acc[a][d] = 0.f;

  for (int n0 = 0; n0 < 1024; n0 += 64) {
    __syncthreads();
    for (int e = tid; e < 4096; e += 256) {
      int r = e >> 6, cc = e & 63;
      qs[r][cc] = __bfloat162float(qp[((size_t)r << 10) + n0 + cc]);
      ks[r][cc] = __bfloat162float(kp[((size_t)r << 10) + n0 + cc]);
    }
    __syncthreads();
#pragma unroll 8
    for (int nn = 0; nn < 64; nn++) {
      float kv[4], qv[4];
#pragma unroll
      for (int jj = 0; jj < 4; jj++) kv[jj] = ks[tx + (jj << 4)][nn];
#pragma unroll
      for (int ii = 0; ii < 4; ii++) qv[ii] = qs[(ty << 2) + ii][nn];
#pragma unroll
      for (int ii = 0; ii < 4; ii++)
#pragma unroll
        for (int jj = 0; jj < 4; jj++) acc[ii][jj] += qv[ii] * kv[jj];
    }
  }
#pragma unroll
  for (int ii = 0; ii < 4; ii++)
#pragma unroll
    for (int jj = 0; jj < 4; jj++) {
      size_t idx = ((size_t)bh * c + i0 + (ty << 2) + ii) * 960 + j0 + tx + (jj << 4);
      attn[idx] = acc[ii][jj] * scale;
    }
}

// ---------------------------------------------------------------------------
// K5: per-(b,h) mean/rstd over c*960 elements (biased var, eps 1e-5)
// grid: nb*4 blocks of 1024
// ---------------------------------------------------------------------------
__global__ void __launch_bounds__(1024) inorm_stats(const float* __restrict__ attn,
                                                    float* __restrict__ stats, int c) {
  __shared__ float r1[16], r2[16];
  const int bh = blockIdx.x;
  const size_t n = (size_t)c * 960;
  const float* p = attn + (size_t)bh * n;
  float s = 0.f, s2 = 0.f;
  for (size_t i = threadIdx.x; i < n; i += 1024) {
    float a = p[i];
    s += a;
    s2 += a * a;
  }
  s = wredsum(s);
  s2 = wredsum(s2);
  const int lane = threadIdx.x & 63, wid = threadIdx.x >> 6;
  if (lane == 0) { r1[wid] = s; r2[wid] = s2; }
  __syncthreads();
  if (wid == 0) {
    float a = (lane < 16) ? r1[lane] : 0.f;
    float b = (lane < 16) ? r2[lane] : 0.f;
    a = wredsum(a);
    b = wredsum(b);
    if (lane == 0) {
      float mu = a / (float)n;
      float var = b / (float)n - mu * mu;
      stats[bh * 2] = mu;
      stats[bh * 2 + 1] = rsqrtf(var + 1e-5f);
    }
  }
}

// ---------------------------------------------------------------------------
// K6: row softmax over 960: probs = softmax((attn-mu)*rstd), bf16 out
// grid: nb*4*c rows; block 256
// ---------------------------------------------------------------------------
__global__ void __launch_bounds__(256) softmax_rows(const float* __restrict__ attn,
                                                    const float* __restrict__ stats,
                                                    bf16* __restrict__ probs, int c) {
  __shared__ float rm[4], rs[4];
  const int row = blockIdx.x;
  const int bh = row / c;
  const float* p = attn + (size_t)row * 960;
  bf16* op = probs + (size_t)row * 960;
  const float mu = stats[bh * 2], rstd = stats[bh * 2 + 1];
  const int tid = threadIdx.x;

  float v[4];
  float mx = -1e30f;
#pragma unroll
  for (int u = 0; u < 4; u++) {
    int j = tid + (u << 8);
    if (j < 960) {
      v[u] = (p[j] - mu) * rstd;
      mx = fmaxf(mx, v[u]);
    } else {
      v[u] = -1e30f;
    }
  }
  mx = wredmax(mx);
  const int lane = tid & 63, wid = tid >> 6;
  if (lane == 0) rm[wid] = mx;
  __syncthreads();
  mx = fmaxf(fmaxf(rm[0], rm[1]), fmaxf(rm[2], rm[3]));

  float sum = 0.f;
#pragma unroll
  for (int u = 0; u < 4; u++) {
    int j = tid + (u << 8);
    if (j < 960) {
      v[u] = __expf(v[u] - mx);
      sum += v[u];
    }
  }
  sum = wredsum(sum);
  if (lane == 0) rs[wid] = sum;
  __syncthreads();
  sum = rs[0] + rs[1] + rs[2] + rs[3];
  const float inv = 1.0f / sum;
#pragma unroll
  for (int u = 0; u < 4; u++) {
    int j = tid + (u << 8);
    if (j < 960) op[j] = __float2bfloat16(v[u] * inv);
  }
}

// ---------------------------------------------------------------------------
// K7: out[b][i][n] = 0.25 * sum_h sum_j probs[b][h][i][j] * v[b][h*960+j][n]
// grid: (1024/64, c/64, nb); block 256; 64x64 tile, 4x4 micro-tile
// ---------------------------------------------------------------------------
__global__ void __launch_bounds__(256) pv_gemm(const bf16* __restrict__ probs,
                                               const bf16* __restrict__ v,
                                               float* __restrict__ out, int c) {
  __shared__ float ps[64][65];
  __shared__ float vs[64][65];
  const int tid = threadIdx.x;
  const int tx = tid & 15, ty = tid >> 4;
  const int b = blockIdx.z;
  const int i0 = blockIdx.y << 6, n0 = blockIdx.x << 6;

  float acc[4][4];
#pragma unroll
  for (int a = 0; a < 4; a++)
#pragma unroll
    for (int d = 0; d < 4; d++) acc[a][d] = 0.f;

  for (int h = 0; h < 4; h++) {
    const bf16* pp = probs + ((size_t)(b * 4 + h) * c + i0) * 960;
    const bf16* vp = v + (((size_t)b * CKV_ + h * KV_) << 10) + n0;
    for (int j0 = 0; j0 < 960; j0 += 64) {
      __syncthreads();
      for (int e = tid; e < 4096; e += 256) {
        int r = e >> 6, cc = e & 63;
        ps[r][cc] = __bfloat162float(pp[(size_t)r * 960 + j0 + cc]);
        vs[r][cc] = __bfloat162float(vp[((size_t)(j0 + r) << 10) + cc]);
      }
      __syncthreads();
#pragma unroll 8
      for (int jj = 0; jj < 64; jj++) {
        float pvv[4], vv[4];
#pragma unroll
        for (int ii = 0; ii < 4; ii++) pvv[ii] = ps[(ty << 2) + ii][jj];
#pragma unroll
        for (int nn = 0; nn < 4; nn++) vv[nn] = vs[jj][tx + (nn << 4)];
#pragma unroll
        for (int ii = 0; ii < 4; ii++)
#pragma unroll
          for (int nn = 0; nn < 4; nn++) acc[ii][nn] += pvv[ii] * vv[nn];
      }
    }
  }
#pragma unroll
  for (int ii = 0; ii < 4; ii++)
#pragma unroll
    for (int nn = 0; nn < 4; nn++) {
      size_t idx = (((size_t)b * c + i0 + (ty << 2) + ii) << 10) + n0 + tx + (nn << 4);
      out[idx] = acc[ii][nn] * 0.25f;
    }
}

// ---------------------------------------------------------------------------
// launcher — adaptive on ws_size.
// Tier A (full batch, nb=8): needs 239,075,584 B with liveness overlap:
//   [kbuf 62.9M][vbuf 62.9M][stage|attnb 62.9M][qbuf|probs 33.5M][outacc 16.8M][stats]
// Tier B (per-batch loop, nb=1): needs 29,884,928 B, same overlap scheme.
// ---------------------------------------------------------------------------
static void run_pipeline(const float* const emb[4], const float* emb_all,
                         const float* const Wm[4], const float* const Wq[4],
                         const float* const Wp[4],
                         const float* Wmk, const float* Wmv,
                         const float* Wk, const float* Wv,
                         float* out, const size_t* out_off,
                         char* ws, int nb, hipStream_t stream) {
  // region sizes for nb batches
  const size_t sz_kv   = (size_t)nb * CKV_ * HW_ * sizeof(bf16);  // kbuf / vbuf / stage|attn
  const size_t sz_qp   = (size_t)nb * 2048 * HW_ * sizeof(bf16);  // qbuf | probs
  bf16* kbuf   = (bf16*)ws;
  bf16* vbuf   = (bf16*)(ws + sz_kv);
  char* r_sa   = ws + 2 * sz_kv;          // stage | attnb
  bf16* stage  = (bf16*)r_sa;
  float* attnb = (float*)r_sa;            // 32*c*960*4 <= nb*3840*1024*2 for c<=512
  char* r_qp   = ws + 3 * sz_kv;
  bf16* qbuf   = (bf16*)r_qp;
  bf16* probsb = (bf16*)r_qp;             // nb*4*c*960*2 <= sz_qp
  float* outacc = (float*)(ws + 3 * sz_kv + sz_qp);
  float* stats  = (float*)(ws + 3 * sz_kv + sz_qp + (size_t)nb * 512 * HW_ * sizeof(float));

  const float scale = 1.0f / sqrtf((float)KV_);
  const int CHs[4] = {64, 128, 256, 512};

  // shared K
  gemm_wx<bf16><<<dim3(4, CKV_ / 16, nb), 256, 0, stream>>>(Wmk, emb_all, stage, CKV_, KV_);
  dw3x3<true><<<nb * CKV_, 1024, 0, stream>>>(stage, Wk, kbuf, CKV_);
  // shared V
  gemm_wx<bf16><<<dim3(4, CKV_ / 16, nb), 256, 0, stream>>>(Wmv, emb_all, stage, CKV_, KV_);
  dw3x3<false><<<nb * CKV_, 1024, 0, stream>>>(stage, Wv, vbuf, CKV_);

  for (int br = 0; br < 4; br++) {
    const int c = CHs[br];
    const int C4 = c * 4;
    // q = l2norm(grouped3x3(Wm @ emb))
    gemm_wx<bf16><<<dim3(4, C4 / 16, nb), 256, 0, stream>>>(Wm[br], emb[br], stage, C4, c);
    gq3x3norm<<<nb * C4, 1024, 0, stream>>>(stage, Wq[br], qbuf, C4);
    // attn = scale * q @ k^T   (writes attnb region = stage region; stage is dead)
    attn_gemm<<<dim3(KV_ / 64, c / 64, nb * HEADS_), 256, 0, stream>>>(qbuf, kbuf, attnb, c, scale);
    // instance norm + softmax  (probs region = qbuf region; qbuf is dead)
    inorm_stats<<<nb * HEADS_, 1024, 0, stream>>>(attnb, stats, c);
    softmax_rows<<<nb * HEADS_ * c, 256, 0, stream>>>(attnb, stats, probsb, c);
    // out = 0.25 * sum_h probs @ v
    pv_gemm<<<dim3(HW_ / 64, c / 64, nb), 256, 0, stream>>>(probsb, vbuf, outacc, c);
    // final 1x1 projection -> d_out
    gemm_wx<float><<<dim3(4, c / 16, nb), 256, 0, stream>>>(Wp[br], outacc, out + out_off[br], c, c);
  }
}

extern "C" void kernel_launch(void* const* d_in, const int* in_sizes, int n_in,
                              void* d_out, int out_size, void* d_ws, size_t ws_size,
                              hipStream_t stream) {
  const float* emb[4] = {(const float*)d_in[0], (const float*)d_in[1],
                         (const float*)d_in[2], (const float*)d_in[3]};
  const float* emb_all = (const float*)d_in[4];
  const float* Wm[4] = {(const float*)d_in[5], (const float*)d_in[8],
                        (const float*)d_in[11], (const float*)d_in[14]};
  const float* Wq[4] = {(const float*)d_in[6], (const float*)d_in[9],
                        (const float*)d_in[12], (const float*)d_in[15]};
  const float* Wp[4] = {(const float*)d_in[7], (const float*)d_in[10],
                        (const float*)d_in[13], (const float*)d_in[16]};
  const float* Wmk = (const float*)d_in[17];
  const float* Wmv = (const float*)d_in[18];
  const float* Wk = (const float*)d_in[19];
  const float* Wv = (const float*)d_in[20];
  float* out = (float*)d_out;

  const int CHs[4] = {64, 128, 256, 512};
  const size_t out_off_full[4] = {0, 524288, 1572864, 3670016};

  const size_t needA = 239075584;  // full-batch footprint
  if (ws_size >= needA) {
    run_pipeline(emb, emb_all, Wm, Wq, Wp, Wmk, Wmv, Wk, Wv,
                 out, out_off_full, (char*)d_ws, B_, stream);
  } else {
    // per-batch loop: same kernels, nb=1, batch-offset pointers (~29.9 MB ws)
    for (int b = 0; b < B_; b++) {
      const float* embB[4];
      for (int i = 0; i < 4; i++) embB[i] = emb[i] + (size_t)b * CHs[i] * HW_;
      const float* emb_allB = emb_all + (size_t)b * KV_ * HW_;
      size_t out_offB[4];
      for (int i = 0; i < 4; i++) out_offB[i] = out_off_full[i] + (size_t)b * CHs[i] * HW_;
      run_pipeline(embB, emb_allB, Wm, Wq, Wp, Wmk, Wmv, Wk, Wv,
                   out, out_offB, (char*)d_ws, 1, stream);
    }
  }
}

// Round 3
// 7067.348 us; speedup vs baseline: 1.4819x; 1.4819x over previous
//
#include <hip/hip_runtime.h>
#include <hip/hip_bf16.h>
#include <math.h>

typedef __hip_bfloat16 bf16;
typedef __attribute__((ext_vector_type(8))) short short8;
typedef __attribute__((ext_vector_type(4))) float f32x4;

#define B_ 8
#define HEADS_ 4
#define KV_ 960
#define HW_ 1024
#define CKV_ 3840   // KV_*HEADS_

// ---------------------------------------------------------------------------
// helpers
// ---------------------------------------------------------------------------
__device__ __forceinline__ float wredsum(float v) {
#pragma unroll
  for (int o = 32; o > 0; o >>= 1) v += __shfl_xor(v, o);
  return v;
}
__device__ __forceinline__ float wredmax(float v) {
#pragma unroll
  for (int o = 32; o > 0; o >>= 1) v = fmaxf(v, __shfl_xor(v, o));
  return v;
}

__device__ __forceinline__ void gl_lds16(const void* g, void* l) {
  __builtin_amdgcn_global_load_lds(
      (const __attribute__((address_space(1))) unsigned*)g,
      (__attribute__((address_space(3))) unsigned*)l, 16, 0, 0);
}

// ---------------------------------------------------------------------------
// K0a: elementwise f32 -> bf16 cast (weights). n % 4 == 0.
// ---------------------------------------------------------------------------
__global__ void __launch_bounds__(256) castw(const float* __restrict__ in,
                                             bf16* __restrict__ out, int n) {
  int i = (blockIdx.x * 256 + threadIdx.x) * 4;
  if (i < n) {
    float4 v = *(const float4*)(in + i);
    out[i] = __float2bfloat16(v.x);
    out[i + 1] = __float2bfloat16(v.y);
    out[i + 2] = __float2bfloat16(v.z);
    out[i + 3] = __float2bfloat16(v.w);
  }
}

// ---------------------------------------------------------------------------
// K0b: transpose+cast: in [z][R][1024] (f32 or bf16) -> out [z][1024][R] bf16.
// grid (1024/32, R/32, nz); block 256.
// ---------------------------------------------------------------------------
template <typename InT>
__global__ void __launch_bounds__(256) tcast(const InT* __restrict__ in,
                                             bf16* __restrict__ out, int R,
                                             long long inZ, long long outZ) {
  __shared__ float t[32][33];
  const int x = threadIdx.x & 31, y0 = threadIdx.x >> 5;
  const int c0 = blockIdx.x << 5, r0 = blockIdx.y << 5;
  const InT* ip = in + (long long)blockIdx.z * inZ + (long long)r0 * 1024 + c0;
  bf16* op = out + (long long)blockIdx.z * outZ + (long long)c0 * R + r0;
#pragma unroll
  for (int i = 0; i < 4; i++) {
    int r = y0 + i * 8;
    float v;
    if constexpr (__is_same(InT, float)) v = ip[(long long)r * 1024 + x];
    else v = __bfloat162float(ip[(long long)r * 1024 + x]);
    t[r][x] = v;
  }
  __syncthreads();
#pragma unroll
  for (int i = 0; i < 4; i++) {
    int cc = y0 + i * 8;
    op[(long long)cc * R + x] = __float2bfloat16(t[x][cc]);
  }
}

// ---------------------------------------------------------------------------
// K_GEMM: batched MFMA GEMM.  D[z][m][n] = scale * sum_h sum_k A[m][k]*Bt[n][k]
//   A:  bf16, row stride K, base + z*aZ + h*aH
//   Bt: bf16, row stride K (k-contiguous), base + z*bZ + h*bH
//   OUTMODE 0: f32  Y[z*yZ + m*ldy + n]
//   OUTMODE 1: bf16 Y[z*yZ + m*ldy + n]
//   OUTMODE 2: bf16 Y[z*yZ + n*ldy + m]  (transposed store)
// 128x128 tile, BK=32, 4 waves (2x2 of 64x64), 16x16x32 bf16 MFMA.
// Boundary: clamped loads (rows >= M / N re-read last row), guarded stores.
// ---------------------------------------------------------------------------
template <int OUTMODE>
__global__ void __launch_bounds__(256) gemm_mfma(
    const bf16* __restrict__ A, const bf16* __restrict__ Bt, void* __restrict__ Y,
    int M, int N, int K, int nh,
    long long aZ, long long aH, long long bZ, long long bH,
    long long yZ, int ldy, float scale) {
  __shared__ bf16 As[128 * 32];
  __shared__ bf16 Bs[128 * 32];
  const int tid = threadIdx.x;
  const int lane = tid & 63;
  const int wave = tid >> 6;
  const int wr = wave >> 1, wc = wave & 1;
  const int z = blockIdx.z;
  const int m0 = blockIdx.y << 7, n0 = blockIdx.x << 7;

  f32x4 acc[4][4];
#pragma unroll
  for (int i = 0; i < 4; i++)
#pragma unroll
    for (int j = 0; j < 4; j++) acc[i][j] = (f32x4){0.f, 0.f, 0.f, 0.f};

  const int frow = lane & 15;          // fragment row/col within 16
  const int kb = (lane >> 4) * 8;      // k sub-offset (bf16) within 32

  for (int h = 0; h < nh; h++) {
    const bf16* Ah = A + (long long)z * aZ + (long long)h * aH;
    const bf16* Bh = Bt + (long long)z * bZ + (long long)h * bH;
    for (int k0 = 0; k0 < K; k0 += 32) {
      __syncthreads();
      // stage A,B tiles: 128 rows x 32 k bf16 = 8KB each; 2 wave-loads per
      // tile per wave; LDS dest linear (wave-uniform base + lane*16).
#pragma unroll
      for (int t = 0; t < 2; t++) {
        int e = (wave * 2 + t) * 64 + lane;   // 0..511
        int row = e >> 2, slot = e & 3;
        int gr = m0 + row; gr = gr < M ? gr : M - 1;
        gl_lds16(Ah + (long long)gr * K + k0 + slot * 8,
                 (char*)As + (wave * 2 + t) * 1024);
        int rn = n0 + row; rn = rn < N ? rn : N - 1;
        gl_lds16(Bh + (long long)rn * K + k0 + slot * 8,
                 (char*)Bs + (wave * 2 + t) * 1024);
      }
      __syncthreads();   // compiler emits vmcnt(0) drain -> LDS valid
      short8 af[4], bfr[4];
#pragma unroll
      for (int fm = 0; fm < 4; fm++)
        af[fm] = *(const short8*)&As[(wr * 64 + fm * 16 + frow) * 32 + kb];
#pragma unroll
      for (int fn = 0; fn < 4; fn++)
        bfr[fn] = *(const short8*)&Bs[(wc * 64 + fn * 16 + frow) * 32 + kb];
#pragma unroll
      for (int fm = 0; fm < 4; fm++)
#pragma unroll
        for (int fn = 0; fn < 4; fn++)
          acc[fm][fn] = __builtin_amdgcn_mfma_f32_16x16x32_bf16(
              af[fm], bfr[fn], acc[fm][fn], 0, 0, 0);
    }
  }

  const int rq = (lane >> 4) << 2;  // C/D: row=(lane>>4)*4+reg, col=lane&15
#pragma unroll
  for (int fm = 0; fm < 4; fm++) {
    const int mrow = m0 + wr * 64 + fm * 16 + rq;
#pragma unroll
    for (int fn = 0; fn < 4; fn++) {
      const int ncol = n0 + wc * 64 + fn * 16 + frow;
      if (ncol >= N) continue;
      if constexpr (OUTMODE == 0) {
        float* Yp = (float*)Y + (long long)z * yZ;
#pragma unroll
        for (int i = 0; i < 4; i++)
          if (mrow + i < M)
            Yp[(long long)(mrow + i) * ldy + ncol] = acc[fm][fn][i] * scale;
      } else if constexpr (OUTMODE == 1) {
        bf16* Yp = (bf16*)Y + (long long)z * yZ;
#pragma unroll
        for (int i = 0; i < 4; i++)
          if (mrow + i < M)
            Yp[(long long)(mrow + i) * ldy + ncol] =
                __float2bfloat16(acc[fm][fn][i] * scale);
      } else {
        if (mrow < M) {   // M%4==0 so whole quad in-range
          bf16* Yp = (bf16*)Y + (long long)z * yZ + (long long)ncol * ldy + mrow;
#pragma unroll
          for (int i = 0; i < 4; i++)
            Yp[i] = __float2bfloat16(acc[fm][fn][i] * scale);
        }
      }
    }
  }
}

// ---------------------------------------------------------------------------
// K2: depthwise 3x3 (pad 1) on 32x32 planes, optional fused l2norm over plane.
// ---------------------------------------------------------------------------
template <bool NORM>
__global__ void __launch_bounds__(1024) dw3x3(const bf16* __restrict__ in,
                                              const float* __restrict__ w9,
                                              bf16* __restrict__ out, int C) {
  __shared__ float tile[34][34];
  __shared__ float red[16];
  const int bc = blockIdx.x;
  const int ch = bc % C;
  const int tid = threadIdx.x;
  const int x = tid & 31, y = tid >> 5;
  const bf16* ip = in + ((size_t)bc << 10);

  tile[y + 1][x + 1] = __bfloat162float(ip[tid]);
  if (y == 0) { tile[0][x + 1] = 0.f; tile[33][x + 1] = 0.f; }
  if (x == 0) { tile[y + 1][0] = 0.f; tile[y + 1][33] = 0.f; }
  if (tid == 0) { tile[0][0] = 0.f; tile[0][33] = 0.f; tile[33][0] = 0.f; tile[33][33] = 0.f; }
  __syncthreads();

  const float* wc = w9 + ch * 9;
  float w[9];
#pragma unroll
  for (int u = 0; u < 9; u++) w[u] = wc[u];
  float s = 0.f;
#pragma unroll
  for (int dy = 0; dy < 3; dy++)
#pragma unroll
    for (int dx = 0; dx < 3; dx++) s += tile[y + dy][x + dx] * w[dy * 3 + dx];

  bf16* op = out + ((size_t)bc << 10);
  if (NORM) {
    float ss = wredsum(s * s);
    const int lane = tid & 63, wid = tid >> 6;
    if (lane == 0) red[wid] = ss;
    __syncthreads();
    if (wid == 0) {
      float r = (lane < 16) ? red[lane] : 0.f;
      r = wredsum(r);
      if (lane == 0) red[0] = 1.0f / fmaxf(sqrtf(r), 1e-12f);
    }
    __syncthreads();
    op[tid] = __float2bfloat16(s * red[0]);
  } else {
    op[tid] = __float2bfloat16(s);
  }
}

// ---------------------------------------------------------------------------
// K3: grouped 3x3 (2 in-ch per group, pad 1) + fused l2norm over plane.
// ---------------------------------------------------------------------------
__global__ void __launch_bounds__(1024) gq3x3norm(const bf16* __restrict__ in,
                                                  const float* __restrict__ wq,
                                                  bf16* __restrict__ out, int C4) {
  __shared__ float t0[34][34];
  __shared__ float t1[34][34];
  __shared__ float red[16];
  const int bo = blockIdx.x;
  const int o = bo % C4;
  const int b = bo / C4;
  const int ic0 = (o >> 1) << 1;
  const int tid = threadIdx.x;
  const int x = tid & 31, y = tid >> 5;
  const bf16* p0 = in + (((size_t)b * C4 + ic0) << 10);

  t0[y + 1][x + 1] = __bfloat162float(p0[tid]);
  t1[y + 1][x + 1] = __bfloat162float(p0[1024 + tid]);
  if (y == 0) { t0[0][x + 1] = 0.f; t0[33][x + 1] = 0.f; t1[0][x + 1] = 0.f; t1[33][x + 1] = 0.f; }
  if (x == 0) { t0[y + 1][0] = 0.f; t0[y + 1][33] = 0.f; t1[y + 1][0] = 0.f; t1[y + 1][33] = 0.f; }
  if (tid == 0) {
    t0[0][0] = t0[0][33] = t0[33][0] = t0[33][33] = 0.f;
    t1[0][0] = t1[0][33] = t1[33][0] = t1[33][33] = 0.f;
  }
  __syncthreads();

  const float* w = wq + o * 18;
  float s = 0.f;
#pragma unroll
  for (int dy = 0; dy < 3; dy++)
#pragma unroll
    for (int dx = 0; dx < 3; dx++) {
      s += t0[y + dy][x + dx] * w[dy * 3 + dx];
      s += t1[y + dy][x + dx] * w[9 + dy * 3 + dx];
    }

  float ss = wredsum(s * s);
  const int lane = tid & 63, wid = tid >> 6;
  if (lane == 0) red[wid] = ss;
  __syncthreads();
  if (wid == 0) {
    float r = (lane < 16) ? red[lane] : 0.f;
    r = wredsum(r);
    if (lane == 0) red[0] = 1.0f / fmaxf(sqrtf(r), 1e-12f);
  }
  __syncthreads();
  out[((size_t)bo << 10) + tid] = __float2bfloat16(s * red[0]);
}

// ---------------------------------------------------------------------------
// K5: per-(b,h) mean/rstd over c*960 elements (biased var, eps 1e-5)
// ---------------------------------------------------------------------------
__global__ void __launch_bounds__(1024) inorm_stats(const float* __restrict__ attn,
                                                    float* __restrict__ stats, int c) {
  __shared__ float r1[16], r2[16];
  const int bh = blockIdx.x;
  const size_t n = (size_t)c * 960;
  const float* p = attn + (size_t)bh * n;
  float s = 0.f, s2 = 0.f;
  for (size_t i = threadIdx.x; i < n; i += 1024) {
    float a = p[i];
    s += a;
    s2 += a * a;
  }
  s = wredsum(s);
  s2 = wredsum(s2);
  const int lane = threadIdx.x & 63, wid = threadIdx.x >> 6;
  if (lane == 0) { r1[wid] = s; r2[wid] = s2; }
  __syncthreads();
  if (wid == 0) {
    float a = (lane < 16) ? r1[lane] : 0.f;
    float b = (lane < 16) ? r2[lane] : 0.f;
    a = wredsum(a);
    b = wredsum(b);
    if (lane == 0) {
      float mu = a / (float)n;
      float var = b / (float)n - mu * mu;
      stats[bh * 2] = mu;
      stats[bh * 2 + 1] = rsqrtf(var + 1e-5f);
    }
  }
}

// ---------------------------------------------------------------------------
// K6: row softmax over 960: probs = softmax((attn-mu)*rstd), bf16 out
// ---------------------------------------------------------------------------
__global__ void __launch_bounds__(256) softmax_rows(const float* __restrict__ attn,
                                                    const float* __restrict__ stats,
                                                    bf16* __restrict__ probs, int c) {
  __shared__ float rm[4], rs[4];
  const int row = blockIdx.x;
  const int bh = row / c;
  const float* p = attn + (size_t)row * 960;
  bf16* op = probs + (size_t)row * 960;
  const float mu = stats[bh * 2], rstd = stats[bh * 2 + 1];
  const int tid = threadIdx.x;

  float v[4];
  float mx = -1e30f;
#pragma unroll
  for (int u = 0; u < 4; u++) {
    int j = tid + (u << 8);
    if (j < 960) {
      v[u] = (p[j] - mu) * rstd;
      mx = fmaxf(mx, v[u]);
    } else {
      v[u] = -1e30f;
    }
  }
  mx = wredmax(mx);
  const int lane = tid & 63, wid = tid >> 6;
  if (lane == 0) rm[wid] = mx;
  __syncthreads();
  mx = fmaxf(fmaxf(rm[0], rm[1]), fmaxf(rm[2], rm[3]));

  float sum = 0.f;
#pragma unroll
  for (int u = 0; u < 4; u++) {
    int j = tid + (u << 8);
    if (j < 960) {
      v[u] = __expf(v[u] - mx);
      sum += v[u];
    }
  }
  sum = wredsum(sum);
  if (lane == 0) rs[wid] = sum;
  __syncthreads();
  sum = rs[0] + rs[1] + rs[2] + rs[3];
  const float inv = 1.0f / sum;
#pragma unroll
  for (int u = 0; u < 4; u++) {
    int j = tid + (u << 8);
    if (j < 960) op[j] = __float2bfloat16(v[u] * inv);
  }
}

// ---------------------------------------------------------------------------
// pipeline (nb batches). Weight bf16 buffers pre-cast by caller.
// dyn layout: [kbuf][vt][stage][vbuf|attnb][qbuf|probs][embT_all][embT_i][OtT]
// ---------------------------------------------------------------------------
static void run_pipeline(const float* const emb[4], const float* emb_all,
                         const float* const Wq[4],
                         const float* const Wm[4], const float* const Wp[4],
                         const float* Wk, const float* Wv,
                         bf16* Wmk_bf, bf16* Wmv_bf, bf16* Wm_bf, bf16* Wp_bf,
                         float* stats, float* out, const size_t* out_off,
                         char* dyn, int nb, hipStream_t stream) {
  const size_t szKV = (size_t)nb * 7864320;   // nb*3840*1024*2
  bf16* kbuf = (bf16*)dyn;
  bf16* vt   = (bf16*)(dyn + szKV);
  bf16* stage = (bf16*)(dyn + 2 * szKV);
  char* r_va = dyn + 3 * szKV;
  bf16* vbuf = (bf16*)r_va;
  float* attnb = (float*)r_va;
  char* r_qp = dyn + 4 * szKV;
  bf16* qbuf = (bf16*)r_qp;
  bf16* probsb = (bf16*)r_qp;
  bf16* embT_all = (bf16*)(dyn + 4 * szKV + (size_t)nb * 4194304);
  bf16* embT_i = (bf16*)(dyn + 4 * szKV + (size_t)nb * 6160384);
  bf16* OtT = (bf16*)(dyn + 4 * szKV + (size_t)nb * 7208960);

  const float qk_scale = 1.0f / sqrtf((float)KV_);
  const int CHs[4] = {64, 128, 256, 512};

  // emb_all^T (bf16, k-contiguous)
  tcast<float><<<dim3(32, 30, nb), 256, 0, stream>>>(emb_all, embT_all, 960, 983040LL, 983040LL);
  // K path
  gemm_mfma<1><<<dim3(8, 30, nb), 256, 0, stream>>>(
      Wmk_bf, embT_all, stage, 3840, 1024, 960, 1, 0, 0, 983040LL, 0, 3932160LL, 1024, 1.f);
  dw3x3<true><<<nb * CKV_, 1024, 0, stream>>>(stage, Wk, kbuf, CKV_);
  // V path
  gemm_mfma<1><<<dim3(8, 30, nb), 256, 0, stream>>>(
      Wmv_bf, embT_all, stage, 3840, 1024, 960, 1, 0, 0, 983040LL, 0, 3932160LL, 1024, 1.f);
  dw3x3<false><<<nb * CKV_, 1024, 0, stream>>>(stage, Wv, vbuf, CKV_);
  // v^T per (b,h): [n][j]
  tcast<bf16><<<dim3(32, 30, nb * 4), 256, 0, stream>>>(vbuf, vt, 960, 983040LL, 983040LL);

  for (int br = 0; br < 4; br++) {
    const int c = CHs[br];
    const int C4 = c * 4;
    const int mtiles = (c + 127) / 128;
    castw<<<(C4 * c + 1023) / 1024, 256, 0, stream>>>(Wm[br], Wm_bf, C4 * c);
    castw<<<(c * c + 1023) / 1024, 256, 0, stream>>>(Wp[br], Wp_bf, c * c);
    tcast<float><<<dim3(32, c / 32, nb), 256, 0, stream>>>(
        emb[br], embT_i, c, (long long)c * 1024, (long long)c * 1024);
    // q-expand: [b][4c][1024] bf16
    gemm_mfma<1><<<dim3(8, C4 / 128, nb), 256, 0, stream>>>(
        Wm_bf, embT_i, stage, C4, 1024, c, 1, 0, 0, (long long)c * 1024, 0,
        (long long)C4 * 1024, 1024, 1.f);
    gq3x3norm<<<nb * C4, 1024, 0, stream>>>(stage, Wq[br], qbuf, C4);
    // attn = scale * q k^T : z = (b,h), N=960 partial tile
    gemm_mfma<0><<<dim3(8, mtiles, nb * 4), 256, 0, stream>>>(
        qbuf, kbuf, attnb, c, 960, 1024, 1, (long long)c * 1024, 0, 983040LL, 0,
        (long long)c * 960, 960, qk_scale);
    inorm_stats<<<nb * 4, 1024, 0, stream>>>(attnb, stats, c);
    softmax_rows<<<nb * 4 * c, 256, 0, stream>>>(attnb, stats, probsb, c);
    // PV with head-sum (nh=4), 0.25 folded, transposed bf16 out Ot[b][n][i]
    gemm_mfma<2><<<dim3(8, mtiles, nb), 256, 0, stream>>>(
        probsb, vt, OtT, c, 1024, 960, 4, (long long)4 * c * 960, (long long)c * 960,
        3932160LL, 983040LL, (long long)1024 * c, c, 0.25f);
    // final projection: f32 to d_out
    gemm_mfma<0><<<dim3(8, mtiles, nb), 256, 0, stream>>>(
        Wp_bf, OtT, out + out_off[br], c, 1024, c, 1, 0, 0, (long long)1024 * c, 0,
        (long long)c * 1024, 1024, 1.f);
  }
}

extern "C" void kernel_launch(void* const* d_in, const int* in_sizes, int n_in,
                              void* d_out, int out_size, void* d_ws, size_t ws_size,
                              hipStream_t stream) {
  const float* emb[4] = {(const float*)d_in[0], (const float*)d_in[1],
                         (const float*)d_in[2], (const float*)d_in[3]};
  const float* emb_all = (const float*)d_in[4];
  const float* Wm[4] = {(const float*)d_in[5], (const float*)d_in[8],
                        (const float*)d_in[11], (const float*)d_in[14]};
  const float* Wq[4] = {(const float*)d_in[6], (const float*)d_in[9],
                        (const float*)d_in[12], (const float*)d_in[15]};
  const float* Wp[4] = {(const float*)d_in[7], (const float*)d_in[10],
                        (const float*)d_in[13], (const float*)d_in[16]};
  const float* Wmk = (const float*)d_in[17];
  const float* Wmv = (const float*)d_in[18];
  const float* Wk = (const float*)d_in[19];
  const float* Wv = (const float*)d_in[20];
  float* out = (float*)d_out;

  // fixed weight region
  char* ws = (char*)d_ws;
  bf16* Wmk_bf = (bf16*)ws;                    // 7,372,800
  bf16* Wmv_bf = (bf16*)(ws + 7372800);        // 7,372,800
  bf16* Wm_bf  = (bf16*)(ws + 14745600);       // 2,097,152 (max 2048x512)
  bf16* Wp_bf  = (bf16*)(ws + 16842752);       // 524,288  (max 512x512)
  float* stats = (float*)(ws + 17367040);      // 256 (+pad)
  char* dyn    = ws + 17368064;

  castw<<<3600, 256, 0, stream>>>(Wmk, Wmk_bf, 3686400);
  castw<<<3600, 256, 0, stream>>>(Wmv, Wmv_bf, 3686400);

  const int CHs[4] = {64, 128, 256, 512};
  const size_t out_off_full[4] = {0, 524288, 1572864, 3670016};

  const size_t needA = 17368064 + 8ull * (4 * 7864320 + 8257536);  // ~335.1 MB
  if (ws_size >= needA) {
    run_pipeline(emb, emb_all, Wq, Wm, Wp, Wk, Wv,
                 Wmk_bf, Wmv_bf, Wm_bf, Wp_bf, stats,
                 out, out_off_full, dyn, B_, stream);
  } else {
    for (int b = 0; b < B_; b++) {
      const float* embB[4];
      for (int i = 0; i < 4; i++) embB[i] = emb[i] + (size_t)b * CHs[i] * HW_;
      const float* emb_allB = emb_all + (size_t)b * KV_ * HW_;
      size_t out_offB[4];
      for (int i = 0; i < 4; i++) out_offB[i] = out_off_full[i] + (size_t)b * CHs[i] * HW_;
      run_pipeline(embB, emb_allB, Wq, Wm, Wp, Wk, Wv,
                   Wmk_bf, Wmv_bf, Wm_bf, Wp_bf, stats,
                   out, out_offB, dyn, 1, stream);
    }
  }
}

// Round 4
// 1329.106 us; speedup vs baseline: 7.8800x; 5.3174x over previous
//
#include <hip/hip_runtime.h>
#include <hip/hip_bf16.h>
#include <math.h>

typedef __hip_bfloat16 bf16;
typedef __attribute__((ext_vector_type(8))) short short8;
typedef __attribute__((ext_vector_type(4))) float f32x4;

#define B_ 8
#define HEADS_ 4
#define KV_ 960
#define HW_ 1024
#define CKV_ 3840   // KV_*HEADS_

// ---------------------------------------------------------------------------
// helpers
// ---------------------------------------------------------------------------
__device__ __forceinline__ float wredsum(float v) {
#pragma unroll
  for (int o = 32; o > 0; o >>= 1) v += __shfl_xor(v, o);
  return v;
}
__device__ __forceinline__ float wredmax(float v) {
#pragma unroll
  for (int o = 32; o > 0; o >>= 1) v = fmaxf(v, __shfl_xor(v, o));
  return v;
}

__device__ __forceinline__ void gl_lds16(const void* g, void* l) {
  __builtin_amdgcn_global_load_lds(
      (const __attribute__((address_space(1))) unsigned*)g,
      (__attribute__((address_space(3))) unsigned*)l, 16, 0, 0);
}

// ---------------------------------------------------------------------------
// K0a: elementwise f32 -> bf16 cast (weights). n % 4 == 0.
// ---------------------------------------------------------------------------
__global__ void __launch_bounds__(256) castw(const float* __restrict__ in,
                                             bf16* __restrict__ out, int n) {
  int i = (blockIdx.x * 256 + threadIdx.x) * 4;
  if (i < n) {
    float4 v = *(const float4*)(in + i);
    out[i] = __float2bfloat16(v.x);
    out[i + 1] = __float2bfloat16(v.y);
    out[i + 2] = __float2bfloat16(v.z);
    out[i + 3] = __float2bfloat16(v.w);
  }
}

// ---------------------------------------------------------------------------
// K0b: transpose+cast: in [z][R][1024] (f32 or bf16) -> out [z][1024][R] bf16.
// grid (1024/32, R/32, nz); block 256.
// ---------------------------------------------------------------------------
template <typename InT>
__global__ void __launch_bounds__(256) tcast(const InT* __restrict__ in,
                                             bf16* __restrict__ out, int R,
                                             long long inZ, long long outZ) {
  __shared__ float t[32][33];
  const int x = threadIdx.x & 31, y0 = threadIdx.x >> 5;
  const int c0 = blockIdx.x << 5, r0 = blockIdx.y << 5;
  const InT* ip = in + (long long)blockIdx.z * inZ + (long long)r0 * 1024 + c0;
  bf16* op = out + (long long)blockIdx.z * outZ + (long long)c0 * R + r0;
#pragma unroll
  for (int i = 0; i < 4; i++) {
    int r = y0 + i * 8;
    float v;
    if constexpr (__is_same(InT, float)) v = ip[(long long)r * 1024 + x];
    else v = __bfloat162float(ip[(long long)r * 1024 + x]);
    t[r][x] = v;
  }
  __syncthreads();
#pragma unroll
  for (int i = 0; i < 4; i++) {
    int cc = y0 + i * 8;
    op[(long long)cc * R + x] = __float2bfloat16(t[x][cc]);
  }
}

// ---------------------------------------------------------------------------
// K_GEMM: batched MFMA GEMM.  D[z][m][n] = scale * sum_h sum_k A[m][k]*Bt[n][k]
//   OUTMODE 0: f32 Y[m][n] / 1: bf16 Y[m][n] / 2: bf16 Y[n][m] (transposed)
// 128x128 tile, BK=32, 4 waves (2x2 of 64x64), 16x16x32 bf16 MFMA.
// ---------------------------------------------------------------------------
template <int OUTMODE>
__global__ void __launch_bounds__(256) gemm_mfma(
    const bf16* __restrict__ A, const bf16* __restrict__ Bt, void* __restrict__ Y,
    int M, int N, int K, int nh,
    long long aZ, long long aH, long long bZ, long long bH,
    long long yZ, int ldy, float scale) {
  __shared__ bf16 As[128 * 32];
  __shared__ bf16 Bs[128 * 32];
  const int tid = threadIdx.x;
  const int lane = tid & 63;
  const int wave = tid >> 6;
  const int wr = wave >> 1, wc = wave & 1;
  const int z = blockIdx.z;
  const int m0 = blockIdx.y << 7, n0 = blockIdx.x << 7;

  f32x4 acc[4][4];
#pragma unroll
  for (int i = 0; i < 4; i++)
#pragma unroll
    for (int j = 0; j < 4; j++) acc[i][j] = (f32x4){0.f, 0.f, 0.f, 0.f};

  const int frow = lane & 15;
  const int kb = (lane >> 4) * 8;

  for (int h = 0; h < nh; h++) {
    const bf16* Ah = A + (long long)z * aZ + (long long)h * aH;
    const bf16* Bh = Bt + (long long)z * bZ + (long long)h * bH;
    for (int k0 = 0; k0 < K; k0 += 32) {
      __syncthreads();
#pragma unroll
      for (int t = 0; t < 2; t++) {
        int e = (wave * 2 + t) * 64 + lane;   // 0..511
        int row = e >> 2, slot = e & 3;
        int gr = m0 + row; gr = gr < M ? gr : M - 1;
        gl_lds16(Ah + (long long)gr * K + k0 + slot * 8,
                 (char*)As + (wave * 2 + t) * 1024);
        int rn = n0 + row; rn = rn < N ? rn : N - 1;
        gl_lds16(Bh + (long long)rn * K + k0 + slot * 8,
                 (char*)Bs + (wave * 2 + t) * 1024);
      }
      __syncthreads();
      short8 af[4], bfr[4];
#pragma unroll
      for (int fm = 0; fm < 4; fm++)
        af[fm] = *(const short8*)&As[(wr * 64 + fm * 16 + frow) * 32 + kb];
#pragma unroll
      for (int fn = 0; fn < 4; fn++)
        bfr[fn] = *(const short8*)&Bs[(wc * 64 + fn * 16 + frow) * 32 + kb];
#pragma unroll
      for (int fm = 0; fm < 4; fm++)
#pragma unroll
        for (int fn = 0; fn < 4; fn++)
          acc[fm][fn] = __builtin_amdgcn_mfma_f32_16x16x32_bf16(
              af[fm], bfr[fn], acc[fm][fn], 0, 0, 0);
    }
  }

  const int rq = (lane >> 4) << 2;  // C/D: row=(lane>>4)*4+reg, col=lane&15
#pragma unroll
  for (int fm = 0; fm < 4; fm++) {
    const int mrow = m0 + wr * 64 + fm * 16 + rq;
#pragma unroll
    for (int fn = 0; fn < 4; fn++) {
      const int ncol = n0 + wc * 64 + fn * 16 + frow;
      if (ncol >= N) continue;
      if constexpr (OUTMODE == 0) {
        float* Yp = (float*)Y + (long long)z * yZ;
#pragma unroll
        for (int i = 0; i < 4; i++)
          if (mrow + i < M)
            Yp[(long long)(mrow + i) * ldy + ncol] = acc[fm][fn][i] * scale;
      } else if constexpr (OUTMODE == 1) {
        bf16* Yp = (bf16*)Y + (long long)z * yZ;
#pragma unroll
        for (int i = 0; i < 4; i++)
          if (mrow + i < M)
            Yp[(long long)(mrow + i) * ldy + ncol] =
                __float2bfloat16(acc[fm][fn][i] * scale);
      } else {
        if (mrow < M) {
          bf16* Yp = (bf16*)Y + (long long)z * yZ + (long long)ncol * ldy + mrow;
#pragma unroll
          for (int i = 0; i < 4; i++)
            Yp[i] = __float2bfloat16(acc[fm][fn][i] * scale);
        }
      }
    }
  }
}

// ---------------------------------------------------------------------------
// K2: depthwise 3x3 (pad 1) on 32x32 planes, optional fused l2norm over plane.
// ---------------------------------------------------------------------------
template <bool NORM>
__global__ void __launch_bounds__(1024) dw3x3(const bf16* __restrict__ in,
                                              const float* __restrict__ w9,
                                              bf16* __restrict__ out, int C) {
  __shared__ float tile[34][34];
  __shared__ float red[16];
  const int bc = blockIdx.x;
  const int ch = bc % C;
  const int tid = threadIdx.x;
  const int x = tid & 31, y = tid >> 5;
  const bf16* ip = in + ((size_t)bc << 10);

  tile[y + 1][x + 1] = __bfloat162float(ip[tid]);
  if (y == 0) { tile[0][x + 1] = 0.f; tile[33][x + 1] = 0.f; }
  if (x == 0) { tile[y + 1][0] = 0.f; tile[y + 1][33] = 0.f; }
  if (tid == 0) { tile[0][0] = 0.f; tile[0][33] = 0.f; tile[33][0] = 0.f; tile[33][33] = 0.f; }
  __syncthreads();

  const float* wc = w9 + ch * 9;
  float w[9];
#pragma unroll
  for (int u = 0; u < 9; u++) w[u] = wc[u];
  float s = 0.f;
#pragma unroll
  for (int dy = 0; dy < 3; dy++)
#pragma unroll
    for (int dx = 0; dx < 3; dx++) s += tile[y + dy][x + dx] * w[dy * 3 + dx];

  bf16* op = out + ((size_t)bc << 10);
  if (NORM) {
    float ss = wredsum(s * s);
    const int lane = tid & 63, wid = tid >> 6;
    if (lane == 0) red[wid] = ss;
    __syncthreads();
    if (wid == 0) {
      float r = (lane < 16) ? red[lane] : 0.f;
      r = wredsum(r);
      if (lane == 0) red[0] = 1.0f / fmaxf(sqrtf(r), 1e-12f);
    }
    __syncthreads();
    op[tid] = __float2bfloat16(s * red[0]);
  } else {
    op[tid] = __float2bfloat16(s);
  }
}

// ---------------------------------------------------------------------------
// K3: grouped 3x3 (2 in-ch per group, pad 1) + fused l2norm over plane.
// ---------------------------------------------------------------------------
__global__ void __launch_bounds__(1024) gq3x3norm(const bf16* __restrict__ in,
                                                  const float* __restrict__ wq,
                                                  bf16* __restrict__ out, int C4) {
  __shared__ float t0[34][34];
  __shared__ float t1[34][34];
  __shared__ float red[16];
  const int bo = blockIdx.x;
  const int o = bo % C4;
  const int b = bo / C4;
  const int ic0 = (o >> 1) << 1;
  const int tid = threadIdx.x;
  const int x = tid & 31, y = tid >> 5;
  const bf16* p0 = in + (((size_t)b * C4 + ic0) << 10);

  t0[y + 1][x + 1] = __bfloat162float(p0[tid]);
  t1[y + 1][x + 1] = __bfloat162float(p0[1024 + tid]);
  if (y == 0) { t0[0][x + 1] = 0.f; t0[33][x + 1] = 0.f; t1[0][x + 1] = 0.f; t1[33][x + 1] = 0.f; }
  if (x == 0) { t0[y + 1][0] = 0.f; t0[y + 1][33] = 0.f; t1[y + 1][0] = 0.f; t1[y + 1][33] = 0.f; }
  if (tid == 0) {
    t0[0][0] = t0[0][33] = t0[33][0] = t0[33][33] = 0.f;
    t1[0][0] = t1[0][33] = t1[33][0] = t1[33][33] = 0.f;
  }
  __syncthreads();

  const float* w = wq + o * 18;
  float s = 0.f;
#pragma unroll
  for (int dy = 0; dy < 3; dy++)
#pragma unroll
    for (int dx = 0; dx < 3; dx++) {
      s += t0[y + dy][x + dx] * w[dy * 3 + dx];
      s += t1[y + dy][x + dx] * w[9 + dy * 3 + dx];
    }

  float ss = wredsum(s * s);
  const int lane = tid & 63, wid = tid >> 6;
  if (lane == 0) red[wid] = ss;
  __syncthreads();
  if (wid == 0) {
    float r = (lane < 16) ? red[lane] : 0.f;
    r = wredsum(r);
    if (lane == 0) red[0] = 1.0f / fmaxf(sqrtf(r), 1e-12f);
  }
  __syncthreads();
  out[((size_t)bo << 10) + tid] = __float2bfloat16(s * red[0]);
}

// ---------------------------------------------------------------------------
// K5a: partial mean/var sums. grid = nz*8 blocks of 256; slice s of z.
// part[(z*8+s)*2 + {0,1}] = {sum, sumsq} over len/8 elements.
// ---------------------------------------------------------------------------
__global__ void __launch_bounds__(256) inorm_part(const float* __restrict__ attn,
                                                  float* __restrict__ part, int c) {
  __shared__ float r1[4], r2[4];
  const int z = blockIdx.x >> 3, sl = blockIdx.x & 7;
  const int len = c * 960, seg = len >> 3;
  const float* p = attn + (size_t)z * len + (size_t)sl * seg;
  float s = 0.f, s2 = 0.f;
  for (int i = threadIdx.x; i < seg; i += 256) {
    float a = p[i];
    s += a; s2 += a * a;
  }
  s = wredsum(s); s2 = wredsum(s2);
  const int lane = threadIdx.x & 63, wid = threadIdx.x >> 6;
  if (lane == 0) { r1[wid] = s; r2[wid] = s2; }
  __syncthreads();
  if (threadIdx.x == 0) {
    part[(size_t)blockIdx.x * 2] = r1[0] + r1[1] + r1[2] + r1[3];
    part[(size_t)blockIdx.x * 2 + 1] = r2[0] + r2[1] + r2[2] + r2[3];
  }
}

// K5b: combine 8 partials per z -> stats[z] = {mu, rstd}. 1 block, 64 thr.
__global__ void __launch_bounds__(64) inorm_fin(const float* __restrict__ part,
                                                float* __restrict__ stats,
                                                int nz, int c) {
  const int t = threadIdx.x;
  if (t < nz) {
    float s = 0.f, s2 = 0.f;
#pragma unroll
    for (int i = 0; i < 8; i++) {
      s += part[(t * 8 + i) * 2];
      s2 += part[(t * 8 + i) * 2 + 1];
    }
    const float n = (float)(c * 960);
    float mu = s / n;
    float var = s2 / n - mu * mu;
    stats[t * 2] = mu;
    stats[t * 2 + 1] = rsqrtf(var + 1e-5f);
  }
}

// ---------------------------------------------------------------------------
// K6: row softmax over 960: probs = softmax((attn-mu)*rstd), bf16 out
// ---------------------------------------------------------------------------
__global__ void __launch_bounds__(256) softmax_rows(const float* __restrict__ attn,
                                                    const float* __restrict__ stats,
                                                    bf16* __restrict__ probs, int c) {
  __shared__ float rm[4], rs[4];
  const int row = blockIdx.x;
  const int bh = row / c;
  const float* p = attn + (size_t)row * 960;
  bf16* op = probs + (size_t)row * 960;
  const float mu = stats[bh * 2], rstd = stats[bh * 2 + 1];
  const int tid = threadIdx.x;

  float v[4];
  float mx = -1e30f;
#pragma unroll
  for (int u = 0; u < 4; u++) {
    int j = tid + (u << 8);
    if (j < 960) {
      v[u] = (p[j] - mu) * rstd;
      mx = fmaxf(mx, v[u]);
    } else {
      v[u] = -1e30f;
    }
  }
  mx = wredmax(mx);
  const int lane = tid & 63, wid = tid >> 6;
  if (lane == 0) rm[wid] = mx;
  __syncthreads();
  mx = fmaxf(fmaxf(rm[0], rm[1]), fmaxf(rm[2], rm[3]));

  float sum = 0.f;
#pragma unroll
  for (int u = 0; u < 4; u++) {
    int j = tid + (u << 8);
    if (j < 960) {
      v[u] = __expf(v[u] - mx);
      sum += v[u];
    }
  }
  sum = wredsum(sum);
  if (lane == 0) rs[wid] = sum;
  __syncthreads();
  sum = rs[0] + rs[1] + rs[2] + rs[3];
  const float inv = 1.0f / sum;
#pragma unroll
  for (int u = 0; u < 4; u++) {
    int j = tid + (u << 8);
    if (j < 960) op[j] = __float2bfloat16(v[u] * inv);
  }
}

// ---------------------------------------------------------------------------
// Workspace plan (per group of nb batches). Byte sizes:
//   P1 = kbuf                    nb*7,864,320
//   P2 = vt                      nb*7,864,320
//   P3 = kexp/vexp/qexp | attnb  nb*7,864,320
//   P4 = [embT_all + Wmv_bf] | vhalf | embT_i/qbuf | probs
//        max(nb*4,194,304, nb*1,966,080 + 7,372,800, chunkB*7,864,320)
//   P5 = Wmk_bf | OtT            max(nb*1,048,576, 7,372,800)
//   fixed: Wm_bf 2,097,152 + Wp_bf 524,288 + stats 4,096
// nb=8 total: 233,312,256 B  (fits the >=239,075,584 proven in round 2)
// ---------------------------------------------------------------------------
static size_t p4_size(int nb) {
  const int chunkB = (nb + 1) / 2;
  size_t a = (size_t)nb * 4194304;
  size_t b = (size_t)nb * 1966080 + 7372800;
  size_t c = (size_t)chunkB * 7864320;
  size_t m = a > b ? a : b;
  return m > c ? m : c;
}
static size_t p5_size(int nb) {
  size_t a = (size_t)nb * 1048576;
  return a > 7372800 ? a : 7372800;
}
static size_t total_need(int nb) {
  return 3 * (size_t)nb * 7864320 + p4_size(nb) + p5_size(nb) + 2625536;
}

static void run_group(const float* const emb[4], const float* emb_all,
                      const float* const Wq[4], const float* const Wm[4],
                      const float* const Wp[4],
                      const float* Wmk, const float* Wmv,
                      const float* Wk, const float* Wv,
                      float* out, const size_t* out_off,
                      char* ws, int nb, hipStream_t stream) {
  const size_t szBig = (size_t)nb * 7864320;
  char* P1 = ws;
  char* P2 = P1 + szBig;
  char* P3 = P2 + szBig;
  char* P4 = P3 + szBig;
  char* P5 = P4 + p4_size(nb);
  char* FX = P5 + p5_size(nb);

  bf16* kbuf = (bf16*)P1;
  bf16* vt   = (bf16*)P2;
  bf16* kvexp = (bf16*)P3;     // kexp, then vexp, then qexp
  float* attnb = (float*)P3;
  bf16* embT_all = (bf16*)P4;
  bf16* Wmv_bf = (bf16*)(P4 + (size_t)nb * 1966080);
  bf16* vhalf = (bf16*)P4;
  bf16* qbuf = (bf16*)P4;      // also embT_i (<= qbuf size), probs
  bf16* probsb = (bf16*)P4;
  bf16* Wmk_bf = (bf16*)P5;
  bf16* OtT = (bf16*)P5;
  bf16* Wm_bf = (bf16*)FX;
  bf16* Wp_bf = (bf16*)(FX + 2097152);
  float* stats = (float*)(FX + 2621440);        // 256 B
  float* part  = (float*)(FX + 2621440 + 512);  // 2048 B

  const float qk_scale = 1.0f / sqrtf((float)KV_);
  const int CHs[4] = {64, 128, 256, 512};
  const int chunkB = (nb + 1) / 2;

  // -- prologue: shared K/V --------------------------------------------------
  castw<<<3600, 256, 0, stream>>>(Wmk, Wmk_bf, 3686400);
  castw<<<3600, 256, 0, stream>>>(Wmv, Wmv_bf, 3686400);
  tcast<float><<<dim3(32, 30, nb), 256, 0, stream>>>(emb_all, embT_all, 960,
                                                     983040LL, 983040LL);
  // K: expand (P3) -> dw3x3+l2norm -> kbuf (P1)
  gemm_mfma<1><<<dim3(8, 30, nb), 256, 0, stream>>>(
      Wmk_bf, embT_all, kvexp, 3840, 1024, 960, 1, 0, 0, 983040LL, 0,
      3932160LL, 1024, 1.f);
  dw3x3<true><<<nb * CKV_, 1024, 0, stream>>>(kvexp, Wk, kbuf, CKV_);
  // V: expand (P3; embT_all dead after) -> chunks: dw3x3 -> vhalf -> tcast -> vt
  gemm_mfma<1><<<dim3(8, 30, nb), 256, 0, stream>>>(
      Wmv_bf, embT_all, kvexp, 3840, 1024, 960, 1, 0, 0, 983040LL, 0,
      3932160LL, 1024, 1.f);
  for (int cb = 0; cb < nb; cb += chunkB) {
    int cn = (nb - cb) < chunkB ? (nb - cb) : chunkB;
    dw3x3<false><<<cn * CKV_, 1024, 0, stream>>>(kvexp + (size_t)cb * 3932160,
                                                 Wv, vhalf, CKV_);
    tcast<bf16><<<dim3(32, 30, cn * 4), 256, 0, stream>>>(
        vhalf, vt + (size_t)cb * 3932160, 960, 983040LL, 983040LL);
  }

  // -- branches --------------------------------------------------------------
  for (int br = 0; br < 4; br++) {
    const int c = CHs[br];
    const int C4 = c * 4;
    const int mtiles = (c + 127) / 128;
    castw<<<(C4 * c + 1023) / 1024, 256, 0, stream>>>(Wm[br], Wm_bf, C4 * c);
    castw<<<(c * c + 1023) / 1024, 256, 0, stream>>>(Wp[br], Wp_bf, c * c);
    // embT_i in P4 (qbuf region)
    tcast<float><<<dim3(32, c / 32, nb), 256, 0, stream>>>(
        emb[br], qbuf, c, (long long)c * 1024, (long long)c * 1024);
    // q-expand -> P3 (qexp)
    gemm_mfma<1><<<dim3(8, C4 / 128, nb), 256, 0, stream>>>(
        Wm_bf, qbuf, kvexp, C4, 1024, c, 1, 0, 0, (long long)c * 1024, 0,
        (long long)C4 * 1024, 1024, 1.f);
    // grouped 3x3 + l2norm: P3 -> qbuf (P4)
    gq3x3norm<<<nb * C4, 1024, 0, stream>>>(kvexp, Wq[br], qbuf, C4);
    // attn = scale * q k^T -> attnb (P3)
    gemm_mfma<0><<<dim3(8, mtiles, nb * 4), 256, 0, stream>>>(
        qbuf, kbuf, attnb, c, 960, 1024, 1, (long long)c * 1024, 0, 983040LL,
        0, (long long)c * 960, 960, qk_scale);
    // instance norm + softmax -> probs (P4)
    inorm_part<<<nb * 4 * 8, 256, 0, stream>>>(attnb, part, c);
    inorm_fin<<<1, 64, 0, stream>>>(part, stats, nb * 4, c);
    softmax_rows<<<nb * 4 * c, 256, 0, stream>>>(attnb, stats, probsb, c);
    // PV head-sum (nh=4, 0.25 folded) -> Ot[n][i] bf16 (P5)
    gemm_mfma<2><<<dim3(8, mtiles, nb), 256, 0, stream>>>(
        probsb, vt, OtT, c, 1024, 960, 4, (long long)4 * c * 960,
        (long long)c * 960, 3932160LL, 983040LL, (long long)1024 * c, c, 0.25f);
    // final projection -> f32 d_out
    gemm_mfma<0><<<dim3(8, mtiles, nb), 256, 0, stream>>>(
        Wp_bf, OtT, out + out_off[br], c, 1024, c, 1, 0, 0,
        (long long)1024 * c, 0, (long long)c * 1024, 1024, 1.f);
  }
}

extern "C" void kernel_launch(void* const* d_in, const int* in_sizes, int n_in,
                              void* d_out, int out_size, void* d_ws, size_t ws_size,
                              hipStream_t stream) {
  const float* emb[4] = {(const float*)d_in[0], (const float*)d_in[1],
                         (const float*)d_in[2], (const float*)d_in[3]};
  const float* emb_all = (const float*)d_in[4];
  const float* Wm[4] = {(const float*)d_in[5], (const float*)d_in[8],
                        (const float*)d_in[11], (const float*)d_in[14]};
  const float* Wq[4] = {(const float*)d_in[6], (const float*)d_in[9],
                        (const float*)d_in[12], (const float*)d_in[15]};
  const float* Wp[4] = {(const float*)d_in[7], (const float*)d_in[10],
                        (const float*)d_in[13], (const float*)d_in[16]};
  const float* Wmk = (const float*)d_in[17];
  const float* Wmv = (const float*)d_in[18];
  const float* Wk = (const float*)d_in[19];
  const float* Wv = (const float*)d_in[20];
  float* out = (float*)d_out;

  const int CHs[4] = {64, 128, 256, 512};
  const size_t out_off_full[4] = {0, 524288, 1572864, 3670016};

  int nb = 1;
  if (ws_size >= total_need(8)) nb = 8;
  else if (ws_size >= total_need(4)) nb = 4;
  else if (ws_size >= total_need(2)) nb = 2;

  for (int b0 = 0; b0 < B_; b0 += nb) {
    const float* embB[4];
    for (int i = 0; i < 4; i++) embB[i] = emb[i] + (size_t)b0 * CHs[i] * HW_;
    const float* emb_allB = emb_all + (size_t)b0 * KV_ * HW_;
    size_t out_offB[4];
    for (int i = 0; i < 4; i++)
      out_offB[i] = out_off_full[i] + (size_t)b0 * CHs[i] * HW_;
    run_group(embB, emb_allB, Wq, Wm, Wp, Wmk, Wmv, Wk, Wv,
              out, out_offB, (char*)d_ws, nb, stream);
  }
}

// Round 5
// 1113.225 us; speedup vs baseline: 9.4082x; 1.1939x over previous
//
#include <hip/hip_runtime.h>
#include <hip/hip_bf16.h>
#include <math.h>

typedef __hip_bfloat16 bf16;
typedef __attribute__((ext_vector_type(8))) short short8;
typedef __attribute__((ext_vector_type(4))) float f32x4;

#define B_ 8
#define HEADS_ 4
#define KV_ 960
#define HW_ 1024
#define CKV_ 3840   // KV_*HEADS_

// ---------------------------------------------------------------------------
// helpers
// ---------------------------------------------------------------------------
__device__ __forceinline__ float wredsum(float v) {
#pragma unroll
  for (int o = 32; o > 0; o >>= 1) v += __shfl_xor(v, o);
  return v;
}
__device__ __forceinline__ float wredmax(float v) {
#pragma unroll
  for (int o = 32; o > 0; o >>= 1) v = fmaxf(v, __shfl_xor(v, o));
  return v;
}

__device__ __forceinline__ float bfu2f(unsigned short u) {
  union { unsigned int i; float f; } c;
  c.i = ((unsigned int)u) << 16;
  return c.f;
}
__device__ __forceinline__ unsigned short f2bfu(float f) {
  bf16 h = __float2bfloat16(f);
  return *(unsigned short*)&h;
}

__device__ __forceinline__ void gl_lds16(const void* g, void* l) {
  __builtin_amdgcn_global_load_lds(
      (const __attribute__((address_space(1))) unsigned*)g,
      (__attribute__((address_space(3))) unsigned*)l, 16, 0, 0);
}

// ---------------------------------------------------------------------------
// K0a: elementwise f32 -> bf16 cast (weights). n % 4 == 0.
// ---------------------------------------------------------------------------
__global__ void __launch_bounds__(256) castw(const float* __restrict__ in,
                                             bf16* __restrict__ out, int n) {
  int i = (blockIdx.x * 256 + threadIdx.x) * 4;
  if (i < n) {
    float4 v = *(const float4*)(in + i);
    out[i] = __float2bfloat16(v.x);
    out[i + 1] = __float2bfloat16(v.y);
    out[i + 2] = __float2bfloat16(v.z);
    out[i + 3] = __float2bfloat16(v.w);
  }
}

// ---------------------------------------------------------------------------
// K0b: transpose+cast: in [z][R][1024] (f32 or bf16) -> out [z][1024][R] bf16.
// grid (1024/32, R/32, nz); block 256.
// ---------------------------------------------------------------------------
template <typename InT>
__global__ void __launch_bounds__(256) tcast(const InT* __restrict__ in,
                                             bf16* __restrict__ out, int R,
                                             long long inZ, long long outZ) {
  __shared__ float t[32][33];
  const int x = threadIdx.x & 31, y0 = threadIdx.x >> 5;
  const int c0 = blockIdx.x << 5, r0 = blockIdx.y << 5;
  const InT* ip = in + (long long)blockIdx.z * inZ + (long long)r0 * 1024 + c0;
  bf16* op = out + (long long)blockIdx.z * outZ + (long long)c0 * R + r0;
#pragma unroll
  for (int i = 0; i < 4; i++) {
    int r = y0 + i * 8;
    float v;
    if constexpr (__is_same(InT, float)) v = ip[(long long)r * 1024 + x];
    else v = __bfloat162float(ip[(long long)r * 1024 + x]);
    t[r][x] = v;
  }
  __syncthreads();
#pragma unroll
  for (int i = 0; i < 4; i++) {
    int cc = y0 + i * 8;
    op[(long long)cc * R + x] = __float2bfloat16(t[x][cc]);
  }
}

// ---------------------------------------------------------------------------
// K_GEMM: batched MFMA GEMM.  D[z][m][n] = scale * sum_h sum_k A[m][k]*Bt[n][k]
//   OUTMODE 0: f32 Y[m][n] / 1: bf16 Y[m][n] / 2: bf16 Y[n][m] (transposed)
//   STATS: block-reduce sum/sumsq of stored values into
//          part[(z*32 + by*8 + bx)*2 + {0,1}]  (deterministic, no atomics)
// 128x128 tile, BK=32, 4 waves (2x2 of 64x64), 16x16x32 bf16 MFMA.
// ---------------------------------------------------------------------------
template <int OUTMODE, bool STATS>
__global__ void __launch_bounds__(256) gemm_mfma(
    const bf16* __restrict__ A, const bf16* __restrict__ Bt, void* __restrict__ Y,
    int M, int N, int K, int nh,
    long long aZ, long long aH, long long bZ, long long bH,
    long long yZ, int ldy, float scale, float* __restrict__ part) {
  __shared__ bf16 As[128 * 32];
  __shared__ bf16 Bs[128 * 32];
  __shared__ float rs1[4], rs2[4];
  const int tid = threadIdx.x;
  const int lane = tid & 63;
  const int wave = tid >> 6;
  const int wr = wave >> 1, wc = wave & 1;
  const int z = blockIdx.z;
  const int m0 = blockIdx.y << 7, n0 = blockIdx.x << 7;

  f32x4 acc[4][4];
#pragma unroll
  for (int i = 0; i < 4; i++)
#pragma unroll
    for (int j = 0; j < 4; j++) acc[i][j] = (f32x4){0.f, 0.f, 0.f, 0.f};

  const int frow = lane & 15;
  const int kb = (lane >> 4) * 8;

  for (int h = 0; h < nh; h++) {
    const bf16* Ah = A + (long long)z * aZ + (long long)h * aH;
    const bf16* Bh = Bt + (long long)z * bZ + (long long)h * bH;
    for (int k0 = 0; k0 < K; k0 += 32) {
      __syncthreads();
#pragma unroll
      for (int t = 0; t < 2; t++) {
        int e = (wave * 2 + t) * 64 + lane;   // 0..511
        int row = e >> 2, slot = e & 3;
        int gr = m0 + row; gr = gr < M ? gr : M - 1;
        gl_lds16(Ah + (long long)gr * K + k0 + slot * 8,
                 (char*)As + (wave * 2 + t) * 1024);
        int rn = n0 + row; rn = rn < N ? rn : N - 1;
        gl_lds16(Bh + (long long)rn * K + k0 + slot * 8,
                 (char*)Bs + (wave * 2 + t) * 1024);
      }
      __syncthreads();
      short8 af[4], bfr[4];
#pragma unroll
      for (int fm = 0; fm < 4; fm++)
        af[fm] = *(const short8*)&As[(wr * 64 + fm * 16 + frow) * 32 + kb];
#pragma unroll
      for (int fn = 0; fn < 4; fn++)
        bfr[fn] = *(const short8*)&Bs[(wc * 64 + fn * 16 + frow) * 32 + kb];
#pragma unroll
      for (int fm = 0; fm < 4; fm++)
#pragma unroll
        for (int fn = 0; fn < 4; fn++)
          acc[fm][fn] = __builtin_amdgcn_mfma_f32_16x16x32_bf16(
              af[fm], bfr[fn], acc[fm][fn], 0, 0, 0);
    }
  }

  const int rq = (lane >> 4) << 2;  // C/D: row=(lane>>4)*4+reg, col=lane&15
  float lsum = 0.f, lsq = 0.f;
#pragma unroll
  for (int fm = 0; fm < 4; fm++) {
    const int mrow = m0 + wr * 64 + fm * 16 + rq;
#pragma unroll
    for (int fn = 0; fn < 4; fn++) {
      const int ncol = n0 + wc * 64 + fn * 16 + frow;
      if (ncol >= N) continue;
      if constexpr (OUTMODE == 0) {
        float* Yp = (float*)Y + (long long)z * yZ;
#pragma unroll
        for (int i = 0; i < 4; i++)
          if (mrow + i < M) {
            float v = acc[fm][fn][i] * scale;
            Yp[(long long)(mrow + i) * ldy + ncol] = v;
            if constexpr (STATS) { lsum += v; lsq += v * v; }
          }
      } else if constexpr (OUTMODE == 1) {
        bf16* Yp = (bf16*)Y + (long long)z * yZ;
#pragma unroll
        for (int i = 0; i < 4; i++)
          if (mrow + i < M)
            Yp[(long long)(mrow + i) * ldy + ncol] =
                __float2bfloat16(acc[fm][fn][i] * scale);
      } else {
        if (mrow < M) {
          bf16* Yp = (bf16*)Y + (long long)z * yZ + (long long)ncol * ldy + mrow;
#pragma unroll
          for (int i = 0; i < 4; i++)
            Yp[i] = __float2bfloat16(acc[fm][fn][i] * scale);
        }
      }
    }
  }
  if constexpr (STATS) {
    lsum = wredsum(lsum);
    lsq = wredsum(lsq);
    if (lane == 0) { rs1[wave] = lsum; rs2[wave] = lsq; }
    __syncthreads();
    if (tid == 0) {
      int slot = blockIdx.y * 8 + blockIdx.x;
      part[((long long)z * 32 + slot) * 2] = rs1[0] + rs1[1] + rs1[2] + rs1[3];
      part[((long long)z * 32 + slot) * 2 + 1] = rs2[0] + rs2[1] + rs2[2] + rs2[3];
    }
  }
}

// ---------------------------------------------------------------------------
// K2: depthwise 3x3 (pad 1) on 32x32 planes, optional fused l2norm.
// block 256, 4 px/thread, ushort4 vector I/O. grid: nb*C.
// ---------------------------------------------------------------------------
template <bool NORM>
__global__ void __launch_bounds__(256) dw3x3v(const bf16* __restrict__ in,
                                              const float* __restrict__ w9,
                                              bf16* __restrict__ out, int C) {
  __shared__ float tile[34][36];
  __shared__ float red[4];
  const int bc = blockIdx.x;
  const int ch = bc % C;
  const int tid = threadIdx.x;
  const int y = tid >> 3;          // 0..31
  const int x0 = (tid & 7) << 2;   // 0,4,...,28
  const bf16* ip = in + ((size_t)bc << 10);

  ushort4 u = *(const ushort4*)(ip + (y << 5) + x0);
  tile[y + 1][x0 + 1] = bfu2f(u.x);
  tile[y + 1][x0 + 2] = bfu2f(u.y);
  tile[y + 1][x0 + 3] = bfu2f(u.z);
  tile[y + 1][x0 + 4] = bfu2f(u.w);
  if (tid < 34) { tile[0][tid] = 0.f; tile[33][tid] = 0.f; }
  if (tid < 32) { tile[tid + 1][0] = 0.f; tile[tid + 1][33] = 0.f; }
  __syncthreads();

  const float* wc = w9 + ch * 9;
  float s[4] = {0.f, 0.f, 0.f, 0.f};
#pragma unroll
  for (int dy = 0; dy < 3; dy++) {
    const float* tr = &tile[y + dy][x0];
    float c0 = tr[0], c1 = tr[1], c2 = tr[2], c3 = tr[3], c4 = tr[4], c5 = tr[5];
    float wa = wc[dy * 3], wb = wc[dy * 3 + 1], wd = wc[dy * 3 + 2];
    s[0] += c0 * wa + c1 * wb + c2 * wd;
    s[1] += c1 * wa + c2 * wb + c3 * wd;
    s[2] += c2 * wa + c3 * wb + c4 * wd;
    s[3] += c3 * wa + c4 * wb + c5 * wd;
  }

  float inv = 1.f;
  if (NORM) {
    float ss = s[0] * s[0] + s[1] * s[1] + s[2] * s[2] + s[3] * s[3];
    ss = wredsum(ss);
    const int lane = tid & 63, wid = tid >> 6;
    if (lane == 0) red[wid] = ss;
    __syncthreads();
    inv = 1.0f / fmaxf(sqrtf(red[0] + red[1] + red[2] + red[3]), 1e-12f);
  }
  ushort4 o4;
  o4.x = f2bfu(s[0] * inv);
  o4.y = f2bfu(s[1] * inv);
  o4.z = f2bfu(s[2] * inv);
  o4.w = f2bfu(s[3] * inv);
  *(ushort4*)(out + ((size_t)bc << 10) + (y << 5) + x0) = o4;
}

// ---------------------------------------------------------------------------
// K3: grouped 3x3 (2 in-ch per group, pad 1) + fused l2norm.
// block 256, 4 px/thread, ushort4 I/O. grid: nb*C4.
// ---------------------------------------------------------------------------
__global__ void __launch_bounds__(256) gq3x3v(const bf16* __restrict__ in,
                                              const float* __restrict__ wq,
                                              bf16* __restrict__ out, int C4) {
  __shared__ float t0[34][36];
  __shared__ float t1[34][36];
  __shared__ float red[4];
  const int bo = blockIdx.x;
  const int o = bo % C4;
  const int b = bo / C4;
  const int ic0 = (o >> 1) << 1;
  const int tid = threadIdx.x;
  const int y = tid >> 3;
  const int x0 = (tid & 7) << 2;
  const bf16* p0 = in + (((size_t)b * C4 + ic0) << 10);

  ushort4 u0 = *(const ushort4*)(p0 + (y << 5) + x0);
  ushort4 u1 = *(const ushort4*)(p0 + 1024 + (y << 5) + x0);
  t0[y + 1][x0 + 1] = bfu2f(u0.x);
  t0[y + 1][x0 + 2] = bfu2f(u0.y);
  t0[y + 1][x0 + 3] = bfu2f(u0.z);
  t0[y + 1][x0 + 4] = bfu2f(u0.w);
  t1[y + 1][x0 + 1] = bfu2f(u1.x);
  t1[y + 1][x0 + 2] = bfu2f(u1.y);
  t1[y + 1][x0 + 3] = bfu2f(u1.z);
  t1[y + 1][x0 + 4] = bfu2f(u1.w);
  if (tid < 34) {
    t0[0][tid] = 0.f; t0[33][tid] = 0.f;
    t1[0][tid] = 0.f; t1[33][tid] = 0.f;
  }
  if (tid < 32) {
    t0[tid + 1][0] = 0.f; t0[tid + 1][33] = 0.f;
    t1[tid + 1][0] = 0.f; t1[tid + 1][33] = 0.f;
  }
  __syncthreads();

  const float* w = wq + o * 18;
  float s[4] = {0.f, 0.f, 0.f, 0.f};
#pragma unroll
  for (int dy = 0; dy < 3; dy++) {
    {
      const float* tr = &t0[y + dy][x0];
      float c0 = tr[0], c1 = tr[1], c2 = tr[2], c3 = tr[3], c4 = tr[4], c5 = tr[5];
      float wa = w[dy * 3], wb = w[dy * 3 + 1], wd = w[dy * 3 + 2];
      s[0] += c0 * wa + c1 * wb + c2 * wd;
      s[1] += c1 * wa + c2 * wb + c3 * wd;
      s[2] += c2 * wa + c3 * wb + c4 * wd;
      s[3] += c3 * wa + c4 * wb + c5 * wd;
    }
    {
      const float* tr = &t1[y + dy][x0];
      float c0 = tr[0], c1 = tr[1], c2 = tr[2], c3 = tr[3], c4 = tr[4], c5 = tr[5];
      float wa = w[9 + dy * 3], wb = w[9 + dy * 3 + 1], wd = w[9 + dy * 3 + 2];
      s[0] += c0 * wa + c1 * wb + c2 * wd;
      s[1] += c1 * wa + c2 * wb + c3 * wd;
      s[2] += c2 * wa + c3 * wb + c4 * wd;
      s[3] += c3 * wa + c4 * wb + c5 * wd;
    }
  }

  float ss = s[0] * s[0] + s[1] * s[1] + s[2] * s[2] + s[3] * s[3];
  ss = wredsum(ss);
  const int lane = tid & 63, wid = tid >> 6;
  if (lane == 0) red[wid] = ss;
  __syncthreads();
  float inv = 1.0f / fmaxf(sqrtf(red[0] + red[1] + red[2] + red[3]), 1e-12f);

  ushort4 o4;
  o4.x = f2bfu(s[0] * inv);
  o4.y = f2bfu(s[1] * inv);
  o4.z = f2bfu(s[2] * inv);
  o4.w = f2bfu(s[3] * inv);
  *(ushort4*)(out + ((size_t)bo << 10) + (y << 5) + x0) = o4;
}

// ---------------------------------------------------------------------------
// K5b: combine per-(z,slot) partials -> stats[z] = {mu, rstd}. 1 block, 64 thr.
// ---------------------------------------------------------------------------
__global__ void __launch_bounds__(64) inorm_fin(const float* __restrict__ part,
                                                float* __restrict__ stats,
                                                int nz, int nslots, int c) {
  const int t = threadIdx.x;
  if (t < nz) {
    float s = 0.f, s2 = 0.f;
    for (int i = 0; i < nslots; i++) {
      s += part[(t * 32 + i) * 2];
      s2 += part[(t * 32 + i) * 2 + 1];
    }
    const float n = (float)(c * 960);
    float mu = s / n;
    float var = s2 / n - mu * mu;
    stats[t * 2] = mu;
    stats[t * 2 + 1] = rsqrtf(var + 1e-5f);
  }
}

// ---------------------------------------------------------------------------
// K6: row softmax over 960: probs = softmax((attn-mu)*rstd), bf16 out
// ---------------------------------------------------------------------------
__global__ void __launch_bounds__(256) softmax_rows(const float* __restrict__ attn,
                                                    const float* __restrict__ stats,
                                                    bf16* __restrict__ probs, int c) {
  __shared__ float rm[4], rs[4];
  const int row = blockIdx.x;
  const int bh = row / c;
  const float* p = attn + (size_t)row * 960;
  bf16* op = probs + (size_t)row * 960;
  const float mu = stats[bh * 2], rstd = stats[bh * 2 + 1];
  const int tid = threadIdx.x;

  float v[4];
  float mx = -1e30f;
#pragma unroll
  for (int u = 0; u < 4; u++) {
    int j = tid + (u << 8);
    if (j < 960) {
      v[u] = (p[j] - mu) * rstd;
      mx = fmaxf(mx, v[u]);
    } else {
      v[u] = -1e30f;
    }
  }
  mx = wredmax(mx);
  const int lane = tid & 63, wid = tid >> 6;
  if (lane == 0) rm[wid] = mx;
  __syncthreads();
  mx = fmaxf(fmaxf(rm[0], rm[1]), fmaxf(rm[2], rm[3]));

  float sum = 0.f;
#pragma unroll
  for (int u = 0; u < 4; u++) {
    int j = tid + (u << 8);
    if (j < 960) {
      v[u] = __expf(v[u] - mx);
      sum += v[u];
    }
  }
  sum = wredsum(sum);
  if (lane == 0) rs[wid] = sum;
  __syncthreads();
  sum = rs[0] + rs[1] + rs[2] + rs[3];
  const float inv = 1.0f / sum;
#pragma unroll
  for (int u = 0; u < 4; u++) {
    int j = tid + (u << 8);
    if (j < 960) op[j] = __float2bfloat16(v[u] * inv);
  }
}

// ---------------------------------------------------------------------------
// Workspace plan (per group of nb batches). Byte sizes:
//   P1 = kbuf                    nb*7,864,320
//   P2 = vt                      nb*7,864,320
//   P3 = kexp/vexp/qexp | attnb  nb*7,864,320
//   P4 = [embT_all + Wmv_bf] | vhalf | embT_i/qbuf | probs
//   P5 = Wmk_bf | OtT            max(nb*1,048,576, 7,372,800)
//   FX: Wm_bf 2,097,152 + Wp_bf 524,288 + stats 512 + part 8,192
// nb=8 total: 233,321,472 B  (<= 239,075,584 proven available in round 2)
// ---------------------------------------------------------------------------
static size_t p4_size(int nb) {
  const int chunkB = (nb + 1) / 2;
  size_t a = (size_t)nb * 4194304;
  size_t b = (size_t)nb * 1966080 + 7372800;
  size_t c = (size_t)chunkB * 7864320;
  size_t m = a > b ? a : b;
  return m > c ? m : c;
}
static size_t p5_size(int nb) {
  size_t a = (size_t)nb * 1048576;
  return a > 7372800 ? a : 7372800;
}
static size_t total_need(int nb) {
  return 3 * (size_t)nb * 7864320 + p4_size(nb) + p5_size(nb) + 2630144;
}

static void run_group(const float* const emb[4], const float* emb_all,
                      const float* const Wq[4], const float* const Wm[4],
                      const float* const Wp[4],
                      const float* Wmk, const float* Wmv,
                      const float* Wk, const float* Wv,
                      float* out, const size_t* out_off,
                      char* ws, int nb, hipStream_t stream) {
  const size_t szBig = (size_t)nb * 7864320;
  char* P1 = ws;
  char* P2 = P1 + szBig;
  char* P3 = P2 + szBig;
  char* P4 = P3 + szBig;
  char* P5 = P4 + p4_size(nb);
  char* FX = P5 + p5_size(nb);

  bf16* kbuf = (bf16*)P1;
  bf16* vt   = (bf16*)P2;
  bf16* kvexp = (bf16*)P3;     // kexp, then vexp, then qexp
  float* attnb = (float*)P3;
  bf16* embT_all = (bf16*)P4;
  bf16* Wmv_bf = (bf16*)(P4 + (size_t)nb * 1966080);
  bf16* vhalf = (bf16*)P4;
  bf16* qbuf = (bf16*)P4;      // also embT_i, probs
  bf16* probsb = (bf16*)P4;
  bf16* Wmk_bf = (bf16*)P5;
  bf16* OtT = (bf16*)P5;
  bf16* Wm_bf = (bf16*)FX;
  bf16* Wp_bf = (bf16*)(FX + 2097152);
  float* stats = (float*)(FX + 2621440);        // 512 B
  float* part  = (float*)(FX + 2621952);        // 8192 B

  const float qk_scale = 1.0f / sqrtf((float)KV_);
  const int CHs[4] = {64, 128, 256, 512};
  const int chunkB = (nb + 1) / 2;

  // -- prologue: shared K/V --------------------------------------------------
  castw<<<3600, 256, 0, stream>>>(Wmk, Wmk_bf, 3686400);
  castw<<<3600, 256, 0, stream>>>(Wmv, Wmv_bf, 3686400);
  tcast<float><<<dim3(32, 30, nb), 256, 0, stream>>>(emb_all, embT_all, 960,
                                                     983040LL, 983040LL);
  // K: expand (P3) -> dw3x3+l2norm -> kbuf (P1)
  gemm_mfma<1, false><<<dim3(8, 30, nb), 256, 0, stream>>>(
      Wmk_bf, embT_all, kvexp, 3840, 1024, 960, 1, 0, 0, 983040LL, 0,
      3932160LL, 1024, 1.f, nullptr);
  dw3x3v<true><<<nb * CKV_, 256, 0, stream>>>(kvexp, Wk, kbuf, CKV_);
  // V: expand (P3) -> chunks: dw3x3 -> vhalf -> tcast -> vt
  gemm_mfma<1, false><<<dim3(8, 30, nb), 256, 0, stream>>>(
      Wmv_bf, embT_all, kvexp, 3840, 1024, 960, 1, 0, 0, 983040LL, 0,
      3932160LL, 1024, 1.f, nullptr);
  for (int cb = 0; cb < nb; cb += chunkB) {
    int cn = (nb - cb) < chunkB ? (nb - cb) : chunkB;
    dw3x3v<false><<<cn * CKV_, 256, 0, stream>>>(kvexp + (size_t)cb * 3932160,
                                                 Wv, vhalf, CKV_);
    tcast<bf16><<<dim3(32, 30, cn * 4), 256, 0, stream>>>(
        vhalf, vt + (size_t)cb * 3932160, 960, 983040LL, 983040LL);
  }

  // -- branches --------------------------------------------------------------
  for (int br = 0; br < 4; br++) {
    const int c = CHs[br];
    const int C4 = c * 4;
    const int mtiles = (c + 127) / 128;
    castw<<<(C4 * c + 1023) / 1024, 256, 0, stream>>>(Wm[br], Wm_bf, C4 * c);
    castw<<<(c * c + 1023) / 1024, 256, 0, stream>>>(Wp[br], Wp_bf, c * c);
    // embT_i in P4 (qbuf region)
    tcast<float><<<dim3(32, c / 32, nb), 256, 0, stream>>>(
        emb[br], qbuf, c, (long long)c * 1024, (long long)c * 1024);
    // q-expand -> P3 (qexp)
    gemm_mfma<1, false><<<dim3(8, C4 / 128, nb), 256, 0, stream>>>(
        Wm_bf, qbuf, kvexp, C4, 1024, c, 1, 0, 0, (long long)c * 1024, 0,
        (long long)C4 * 1024, 1024, 1.f, nullptr);
    // grouped 3x3 + l2norm: P3 -> qbuf (P4)
    gq3x3v<<<nb * C4, 256, 0, stream>>>(kvexp, Wq[br], qbuf, C4);
    // attn = scale * q k^T -> attnb (P3), with fused stats partials
    gemm_mfma<0, true><<<dim3(8, mtiles, nb * 4), 256, 0, stream>>>(
        qbuf, kbuf, attnb, c, 960, 1024, 1, (long long)c * 1024, 0, 983040LL,
        0, (long long)c * 960, 960, qk_scale, part);
    inorm_fin<<<1, 64, 0, stream>>>(part, stats, nb * 4, mtiles * 8, c);
    softmax_rows<<<nb * 4 * c, 256, 0, stream>>>(attnb, stats, probsb, c);
    // PV head-sum (nh=4, 0.25 folded) -> Ot[n][i] bf16 (P5)
    gemm_mfma<2, false><<<dim3(8, mtiles, nb), 256, 0, stream>>>(
        probsb, vt, OtT, c, 1024, 960, 4, (long long)4 * c * 960,
        (long long)c * 960, 3932160LL, 983040LL, (long long)1024 * c, c,
        0.25f, nullptr);
    // final projection -> f32 d_out
    gemm_mfma<0, false><<<dim3(8, mtiles, nb), 256, 0, stream>>>(
        Wp_bf, OtT, out + out_off[br], c, 1024, c, 1, 0, 0,
        (long long)1024 * c, 0, (long long)c * 1024, 1024, 1.f, nullptr);
  }
}

extern "C" void kernel_launch(void* const* d_in, const int* in_sizes, int n_in,
                              void* d_out, int out_size, void* d_ws, size_t ws_size,
                              hipStream_t stream) {
  const float* emb[4] = {(const float*)d_in[0], (const float*)d_in[1],
                         (const float*)d_in[2], (const float*)d_in[3]};
  const float* emb_all = (const float*)d_in[4];
  const float* Wm[4] = {(const float*)d_in[5], (const float*)d_in[8],
                        (const float*)d_in[11], (const float*)d_in[14]};
  const float* Wq[4] = {(const float*)d_in[6], (const float*)d_in[9],
                        (const float*)d_in[12], (const float*)d_in[15]};
  const float* Wp[4] = {(const float*)d_in[7], (const float*)d_in[10],
                        (const float*)d_in[13], (const float*)d_in[16]};
  const float* Wmk = (const float*)d_in[17];
  const float* Wmv = (const float*)d_in[18];
  const float* Wk = (const float*)d_in[19];
  const float* Wv = (const float*)d_in[20];
  float* out = (float*)d_out;

  const int CHs[4] = {64, 128, 256, 512};
  const size_t out_off_full[4] = {0, 524288, 1572864, 3670016};

  int nb = 1;
  if (ws_size >= total_need(8)) nb = 8;
  else if (ws_size >= total_need(4)) nb = 4;
  else if (ws_size >= total_need(2)) nb = 2;

  for (int b0 = 0; b0 < B_; b0 += nb) {
    const float* embB[4];
    for (int i = 0; i < 4; i++) embB[i] = emb[i] + (size_t)b0 * CHs[i] * HW_;
    const float* emb_allB = emb_all + (size_t)b0 * KV_ * HW_;
    size_t out_offB[4];
    for (int i = 0; i < 4; i++)
      out_offB[i] = out_off_full[i] + (size_t)b0 * CHs[i] * HW_;
    run_group(embB, emb_allB, Wq, Wm, Wp, Wmk, Wmv, Wk, Wv,
              out, out_offB, (char*)d_ws, nb, stream);
  }
}

// Round 6
// 1092.937 us; speedup vs baseline: 9.5828x; 1.0186x over previous
//
#include <hip/hip_runtime.h>
#include <hip/hip_bf16.h>
#include <math.h>

typedef __hip_bfloat16 bf16;
typedef __attribute__((ext_vector_type(8))) short short8;
typedef __attribute__((ext_vector_type(4))) float f32x4;

#define B_ 8
#define HEADS_ 4
#define KV_ 960
#define HW_ 1024
#define CKV_ 3840   // KV_*HEADS_

// ---------------------------------------------------------------------------
// helpers
// ---------------------------------------------------------------------------
__device__ __forceinline__ float wredsum(float v) {
#pragma unroll
  for (int o = 32; o > 0; o >>= 1) v += __shfl_xor(v, o);
  return v;
}
__device__ __forceinline__ float wredmax(float v) {
#pragma unroll
  for (int o = 32; o > 0; o >>= 1) v = fmaxf(v, __shfl_xor(v, o));
  return v;
}

__device__ __forceinline__ float bfu2f(unsigned short u) {
  union { unsigned int i; float f; } c;
  c.i = ((unsigned int)u) << 16;
  return c.f;
}
__device__ __forceinline__ unsigned short f2bfu(float f) {
  bf16 h = __float2bfloat16(f);
  return *(unsigned short*)&h;
}

__device__ __forceinline__ void gl_lds16(const void* g, void* l) {
  __builtin_amdgcn_global_load_lds(
      (const __attribute__((address_space(1))) unsigned*)g,
      (__attribute__((address_space(3))) unsigned*)l, 16, 0, 0);
}

// ---------------------------------------------------------------------------
// K0a: elementwise f32 -> bf16 cast (weights). n % 4 == 0.
// ---------------------------------------------------------------------------
__global__ void __launch_bounds__(256) castw(const float* __restrict__ in,
                                             bf16* __restrict__ out, int n) {
  int i = (blockIdx.x * 256 + threadIdx.x) * 4;
  if (i < n) {
    float4 v = *(const float4*)(in + i);
    out[i] = __float2bfloat16(v.x);
    out[i + 1] = __float2bfloat16(v.y);
    out[i + 2] = __float2bfloat16(v.z);
    out[i + 3] = __float2bfloat16(v.w);
  }
}

// ---------------------------------------------------------------------------
// K0b: transpose+cast: in [z][R][1024] (f32 or bf16) -> out [z][1024][R] bf16.
// grid (1024/32, R/32, nz); block 256.
// ---------------------------------------------------------------------------
template <typename InT>
__global__ void __launch_bounds__(256) tcast(const InT* __restrict__ in,
                                             bf16* __restrict__ out, int R,
                                             long long inZ, long long outZ) {
  __shared__ float t[32][33];
  const int x = threadIdx.x & 31, y0 = threadIdx.x >> 5;
  const int c0 = blockIdx.x << 5, r0 = blockIdx.y << 5;
  const InT* ip = in + (long long)blockIdx.z * inZ + (long long)r0 * 1024 + c0;
  bf16* op = out + (long long)blockIdx.z * outZ + (long long)c0 * R + r0;
#pragma unroll
  for (int i = 0; i < 4; i++) {
    int r = y0 + i * 8;
    float v;
    if constexpr (__is_same(InT, float)) v = ip[(long long)r * 1024 + x];
    else v = __bfloat162float(ip[(long long)r * 1024 + x]);
    t[r][x] = v;
  }
  __syncthreads();
#pragma unroll
  for (int i = 0; i < 4; i++) {
    int cc = y0 + i * 8;
    op[(long long)cc * R + x] = __float2bfloat16(t[x][cc]);
  }
}

// ---------------------------------------------------------------------------
// K_GEMM: batched MFMA GEMM.  D[z][m][n] = scale * sum_h sum_k A[m][k]*Bt[n][k]
//   OUTMODE 0: f32 Y[m][n] / 1: bf16 Y[m][n] / 2: bf16 Y[n][m] (transposed)
//   STATS: deterministic per-block partial sum/sumsq of stored f32 values.
// 128x128 tile, BK=32, 4 waves, 16x16x32 bf16 MFMA.
// R6: double-buffered LDS (stage next || MFMA cur, one barrier/iter),
//     conflict-free LDS via source-permutation (ks ^= (row>>1)&3),
//     bijective XCD-chunked block remap (all launches have gridDim.x==8).
// ---------------------------------------------------------------------------
template <int OUTMODE, bool STATS>
__global__ void __launch_bounds__(256) gemm_mfma(
    const bf16* __restrict__ A, const bf16* __restrict__ Bt, void* __restrict__ Y,
    int M, int N, int K, int nh,
    long long aZ, long long aH, long long bZ, long long bH,
    long long yZ, int ldy, float scale, float* __restrict__ part) {
  __shared__ bf16 As[2][128 * 32];
  __shared__ bf16 Bs[2][128 * 32];
  __shared__ float rs1[4], rs2[4];
  const int tid = threadIdx.x;
  const int lane = tid & 63;
  const int wave = tid >> 6;
  const int wr = wave >> 1, wc = wave & 1;

  // ---- bijective XCD-chunked remap over the whole grid (nwg % 8 == 0) ----
  const int gy = gridDim.y, gz = gridDim.z;
  int orig = (blockIdx.z * gy + blockIdx.y) * 8 + blockIdx.x;
  int cpx = (gy * gz);              // nwg/8 = gy*gz since gx==8
  int flat = (orig & 7) * cpx + (orig >> 3);
  const int lx = flat & 7;          // gx == 8
  int rest = flat >> 3;
  const int ly = rest % gy;
  const int lz = rest / gy;

  const int z = lz;
  const int m0 = ly << 7, n0 = lx << 7;

  f32x4 acc[4][4];
#pragma unroll
  for (int i = 0; i < 4; i++)
#pragma unroll
    for (int j = 0; j < 4; j++) acc[i][j] = (f32x4){0.f, 0.f, 0.f, 0.f};

  const int frow = lane & 15;
  const int kq = lane >> 4;                 // k-slot 0..3 (8 bf16 each)

  // staging lambda: iteration stages 128x32 A,B tiles into buf.
  // LDS slot e = (wave*2+t)*64 + lane holds global (row=e>>2, ks=(e&3)^((row>>1)&3)).
  const bf16* Ah = A + (long long)z * aZ;   // pointers track NEXT stage's h
  const bf16* Bh = Bt + (long long)z * bZ;
  int k0n = 0;

  auto stage = [&](int buf) {
#pragma unroll
    for (int t = 0; t < 2; t++) {
      const int e = (wave * 2 + t) * 64 + lane;
      const int row = e >> 2;
      const int ks = (e & 3) ^ ((row >> 1) & 3);
      int gr = m0 + row; gr = gr < M ? gr : M - 1;
      gl_lds16(Ah + (long long)gr * K + k0n + ks * 8,
               (char*)&As[buf][0] + (wave * 2 + t) * 1024);
      int rn = n0 + row; rn = rn < N ? rn : N - 1;
      gl_lds16(Bh + (long long)rn * K + k0n + ks * 8,
               (char*)&Bs[buf][0] + (wave * 2 + t) * 1024);
    }
  };

  const int kpt = K >> 5;
  const int iters = nh * kpt;
  stage(0);
  __syncthreads();                 // vmcnt(0) drain + barrier (compiler emits)

  int buf = 0;
  for (int it = 0; it < iters; ++it) {
    if (it + 1 < iters) {
      k0n += 32;
      if (k0n == K) { k0n = 0; Ah += aH; Bh += bH; }
      stage(buf ^ 1);              // issue next tile's loads (overlap w/ MFMA)
    }
    short8 af[4], bfr[4];
#pragma unroll
    for (int fm = 0; fm < 4; fm++) {
      const int row = wr * 64 + fm * 16 + frow;
      af[fm] = *(const short8*)&As[buf][((row << 2) | (kq ^ ((row >> 1) & 3))) << 3];
    }
#pragma unroll
    for (int fn = 0; fn < 4; fn++) {
      const int row = wc * 64 + fn * 16 + frow;
      bfr[fn] = *(const short8*)&Bs[buf][((row << 2) | (kq ^ ((row >> 1) & 3))) << 3];
    }
#pragma unroll
    for (int fm = 0; fm < 4; fm++)
#pragma unroll
      for (int fn = 0; fn < 4; fn++)
        acc[fm][fn] = __builtin_amdgcn_mfma_f32_16x16x32_bf16(
            af[fm], bfr[fn], acc[fm][fn], 0, 0, 0);
    __syncthreads();               // drains vmcnt(0) (next stage) + barrier
    buf ^= 1;
  }

  const int rq = kq << 2;          // C/D: row=(lane>>4)*4+reg, col=lane&15
  float lsum = 0.f, lsq = 0.f;
#pragma unroll
  for (int fm = 0; fm < 4; fm++) {
    const int mrow = m0 + wr * 64 + fm * 16 + rq;
#pragma unroll
    for (int fn = 0; fn < 4; fn++) {
      const int ncol = n0 + wc * 64 + fn * 16 + frow;
      if (ncol >= N) continue;
      if constexpr (OUTMODE == 0) {
        float* Yp = (float*)Y + (long long)z * yZ;
#pragma unroll
        for (int i = 0; i < 4; i++)
          if (mrow + i < M) {
            float v = acc[fm][fn][i] * scale;
            Yp[(long long)(mrow + i) * ldy + ncol] = v;
            if constexpr (STATS) { lsum += v; lsq += v * v; }
          }
      } else if constexpr (OUTMODE == 1) {
        bf16* Yp = (bf16*)Y + (long long)z * yZ;
#pragma unroll
        for (int i = 0; i < 4; i++)
          if (mrow + i < M)
            Yp[(long long)(mrow + i) * ldy + ncol] =
                __float2bfloat16(acc[fm][fn][i] * scale);
      } else {
        if (mrow < M) {
          bf16* Yp = (bf16*)Y + (long long)z * yZ + (long long)ncol * ldy + mrow;
#pragma unroll
          for (int i = 0; i < 4; i++)
            Yp[i] = __float2bfloat16(acc[fm][fn][i] * scale);
        }
      }
    }
  }
  if constexpr (STATS) {
    lsum = wredsum(lsum);
    lsq = wredsum(lsq);
    if (lane == 0) { rs1[wave] = lsum; rs2[wave] = lsq; }
    __syncthreads();
    if (tid == 0) {
      int slot = ly * 8 + lx;
      part[((long long)z * 32 + slot) * 2] = rs1[0] + rs1[1] + rs1[2] + rs1[3];
      part[((long long)z * 32 + slot) * 2 + 1] = rs2[0] + rs2[1] + rs2[2] + rs2[3];
    }
  }
}

// ---------------------------------------------------------------------------
// K2: depthwise 3x3 (pad 1) on 32x32 planes, optional fused l2norm.
// block 256, 4 px/thread, ushort4 vector I/O. grid: nb*C.
// ---------------------------------------------------------------------------
template <bool NORM>
__global__ void __launch_bounds__(256) dw3x3v(const bf16* __restrict__ in,
                                              const float* __restrict__ w9,
                                              bf16* __restrict__ out, int C) {
  __shared__ float tile[34][36];
  __shared__ float red[4];
  const int bc = blockIdx.x;
  const int ch = bc % C;
  const int tid = threadIdx.x;
  const int y = tid >> 3;          // 0..31
  const int x0 = (tid & 7) << 2;   // 0,4,...,28
  const bf16* ip = in + ((size_t)bc << 10);

  ushort4 u = *(const ushort4*)(ip + (y << 5) + x0);
  tile[y + 1][x0 + 1] = bfu2f(u.x);
  tile[y + 1][x0 + 2] = bfu2f(u.y);
  tile[y + 1][x0 + 3] = bfu2f(u.z);
  tile[y + 1][x0 + 4] = bfu2f(u.w);
  if (tid < 34) { tile[0][tid] = 0.f; tile[33][tid] = 0.f; }
  if (tid < 32) { tile[tid + 1][0] = 0.f; tile[tid + 1][33] = 0.f; }
  __syncthreads();

  const float* wc = w9 + ch * 9;
  float s[4] = {0.f, 0.f, 0.f, 0.f};
#pragma unroll
  for (int dy = 0; dy < 3; dy++) {
    const float* tr = &tile[y + dy][x0];
    float c0 = tr[0], c1 = tr[1], c2 = tr[2], c3 = tr[3], c4 = tr[4], c5 = tr[5];
    float wa = wc[dy * 3], wb = wc[dy * 3 + 1], wd = wc[dy * 3 + 2];
    s[0] += c0 * wa + c1 * wb + c2 * wd;
    s[1] += c1 * wa + c2 * wb + c3 * wd;
    s[2] += c2 * wa + c3 * wb + c4 * wd;
    s[3] += c3 * wa + c4 * wb + c5 * wd;
  }

  float inv = 1.f;
  if (NORM) {
    float ss = s[0] * s[0] + s[1] * s[1] + s[2] * s[2] + s[3] * s[3];
    ss = wredsum(ss);
    const int lane = tid & 63, wid = tid >> 6;
    if (lane == 0) red[wid] = ss;
    __syncthreads();
    inv = 1.0f / fmaxf(sqrtf(red[0] + red[1] + red[2] + red[3]), 1e-12f);
  }
  ushort4 o4;
  o4.x = f2bfu(s[0] * inv);
  o4.y = f2bfu(s[1] * inv);
  o4.z = f2bfu(s[2] * inv);
  o4.w = f2bfu(s[3] * inv);
  *(ushort4*)(out + ((size_t)bc << 10) + (y << 5) + x0) = o4;
}

// ---------------------------------------------------------------------------
// K3: grouped 3x3 (2 in-ch per group, pad 1) + fused l2norm.
// block 256, 4 px/thread, ushort4 I/O. grid: nb*C4.
// ---------------------------------------------------------------------------
__global__ void __launch_bounds__(256) gq3x3v(const bf16* __restrict__ in,
                                              const float* __restrict__ wq,
                                              bf16* __restrict__ out, int C4) {
  __shared__ float t0[34][36];
  __shared__ float t1[34][36];
  __shared__ float red[4];
  const int bo = blockIdx.x;
  const int o = bo % C4;
  const int b = bo / C4;
  const int ic0 = (o >> 1) << 1;
  const int tid = threadIdx.x;
  const int y = tid >> 3;
  const int x0 = (tid & 7) << 2;
  const bf16* p0 = in + (((size_t)b * C4 + ic0) << 10);

  ushort4 u0 = *(const ushort4*)(p0 + (y << 5) + x0);
  ushort4 u1 = *(const ushort4*)(p0 + 1024 + (y << 5) + x0);
  t0[y + 1][x0 + 1] = bfu2f(u0.x);
  t0[y + 1][x0 + 2] = bfu2f(u0.y);
  t0[y + 1][x0 + 3] = bfu2f(u0.z);
  t0[y + 1][x0 + 4] = bfu2f(u0.w);
  t1[y + 1][x0 + 1] = bfu2f(u1.x);
  t1[y + 1][x0 + 2] = bfu2f(u1.y);
  t1[y + 1][x0 + 3] = bfu2f(u1.z);
  t1[y + 1][x0 + 4] = bfu2f(u1.w);
  if (tid < 34) {
    t0[0][tid] = 0.f; t0[33][tid] = 0.f;
    t1[0][tid] = 0.f; t1[33][tid] = 0.f;
  }
  if (tid < 32) {
    t0[tid + 1][0] = 0.f; t0[tid + 1][33] = 0.f;
    t1[tid + 1][0] = 0.f; t1[tid + 1][33] = 0.f;
  }
  __syncthreads();

  const float* w = wq + o * 18;
  float s[4] = {0.f, 0.f, 0.f, 0.f};
#pragma unroll
  for (int dy = 0; dy < 3; dy++) {
    {
      const float* tr = &t0[y + dy][x0];
      float c0 = tr[0], c1 = tr[1], c2 = tr[2], c3 = tr[3], c4 = tr[4], c5 = tr[5];
      float wa = w[dy * 3], wb = w[dy * 3 + 1], wd = w[dy * 3 + 2];
      s[0] += c0 * wa + c1 * wb + c2 * wd;
      s[1] += c1 * wa + c2 * wb + c3 * wd;
      s[2] += c2 * wa + c3 * wb + c4 * wd;
      s[3] += c3 * wa + c4 * wb + c5 * wd;
    }
    {
      const float* tr = &t1[y + dy][x0];
      float c0 = tr[0], c1 = tr[1], c2 = tr[2], c3 = tr[3], c4 = tr[4], c5 = tr[5];
      float wa = w[9 + dy * 3], wb = w[9 + dy * 3 + 1], wd = w[9 + dy * 3 + 2];
      s[0] += c0 * wa + c1 * wb + c2 * wd;
      s[1] += c1 * wa + c2 * wb + c3 * wd;
      s[2] += c2 * wa + c3 * wb + c4 * wd;
      s[3] += c3 * wa + c4 * wb + c5 * wd;
    }
  }

  float ss = s[0] * s[0] + s[1] * s[1] + s[2] * s[2] + s[3] * s[3];
  ss = wredsum(ss);
  const int lane = tid & 63, wid = tid >> 6;
  if (lane == 0) red[wid] = ss;
  __syncthreads();
  float inv = 1.0f / fmaxf(sqrtf(red[0] + red[1] + red[2] + red[3]), 1e-12f);

  ushort4 o4;
  o4.x = f2bfu(s[0] * inv);
  o4.y = f2bfu(s[1] * inv);
  o4.z = f2bfu(s[2] * inv);
  o4.w = f2bfu(s[3] * inv);
  *(ushort4*)(out + ((size_t)bo << 10) + (y << 5) + x0) = o4;
}

// ---------------------------------------------------------------------------
// K5b: combine per-(z,slot) partials -> stats[z] = {mu, rstd}. 1 block, 64 thr.
// ---------------------------------------------------------------------------
__global__ void __launch_bounds__(64) inorm_fin(const float* __restrict__ part,
                                                float* __restrict__ stats,
                                                int nz, int nslots, int c) {
  const int t = threadIdx.x;
  if (t < nz) {
    float s = 0.f, s2 = 0.f;
    for (int i = 0; i < nslots; i++) {
      s += part[(t * 32 + i) * 2];
      s2 += part[(t * 32 + i) * 2 + 1];
    }
    const float n = (float)(c * 960);
    float mu = s / n;
    float var = s2 / n - mu * mu;
    stats[t * 2] = mu;
    stats[t * 2 + 1] = rsqrtf(var + 1e-5f);
  }
}

// ---------------------------------------------------------------------------
// K6: row softmax over 960: probs = softmax((attn-mu)*rstd), bf16 out
// ---------------------------------------------------------------------------
__global__ void __launch_bounds__(256) softmax_rows(const float* __restrict__ attn,
                                                    const float* __restrict__ stats,
                                                    bf16* __restrict__ probs, int c) {
  __shared__ float rm[4], rs[4];
  const int row = blockIdx.x;
  const int bh = row / c;
  const float* p = attn + (size_t)row * 960;
  bf16* op = probs + (size_t)row * 960;
  const float mu = stats[bh * 2], rstd = stats[bh * 2 + 1];
  const int tid = threadIdx.x;

  float v[4];
  float mx = -1e30f;
#pragma unroll
  for (int u = 0; u < 4; u++) {
    int j = tid + (u << 8);
    if (j < 960) {
      v[u] = (p[j] - mu) * rstd;
      mx = fmaxf(mx, v[u]);
    } else {
      v[u] = -1e30f;
    }
  }
  mx = wredmax(mx);
  const int lane = tid & 63, wid = tid >> 6;
  if (lane == 0) rm[wid] = mx;
  __syncthreads();
  mx = fmaxf(fmaxf(rm[0], rm[1]), fmaxf(rm[2], rm[3]));

  float sum = 0.f;
#pragma unroll
  for (int u = 0; u < 4; u++) {
    int j = tid + (u << 8);
    if (j < 960) {
      v[u] = __expf(v[u] - mx);
      sum += v[u];
    }
  }
  sum = wredsum(sum);
  if (lane == 0) rs[wid] = sum;
  __syncthreads();
  sum = rs[0] + rs[1] + rs[2] + rs[3];
  const float inv = 1.0f / sum;
#pragma unroll
  for (int u = 0; u < 4; u++) {
    int j = tid + (u << 8);
    if (j < 960) op[j] = __float2bfloat16(v[u] * inv);
  }
}

// ---------------------------------------------------------------------------
// Workspace plan (per group of nb batches). Byte sizes:
//   P1 = kbuf                    nb*7,864,320
//   P2 = vt                      nb*7,864,320
//   P3 = kexp/vexp/qexp | attnb  nb*7,864,320
//   P4 = [embT_all + Wmv_bf] | vhalf | embT_i/qbuf | probs
//   P5 = Wmk_bf | OtT            max(nb*1,048,576, 7,372,800)
//   FX: Wm_all 2,785,280 + Wp_all 696,320 + stats 512 + part 8,192
// nb=8 total: 234,177,024 B  (<= 239,075,584 proven available in round 2)
// ---------------------------------------------------------------------------
static size_t p4_size(int nb) {
  const int chunkB = (nb + 1) / 2;
  size_t a = (size_t)nb * 4194304;
  size_t b = (size_t)nb * 1966080 + 7372800;
  size_t c = (size_t)chunkB * 7864320;
  size_t m = a > b ? a : b;
  return m > c ? m : c;
}
static size_t p5_size(int nb) {
  size_t a = (size_t)nb * 1048576;
  return a > 7372800 ? a : 7372800;
}
static size_t total_need(int nb) {
  return 3 * (size_t)nb * 7864320 + p4_size(nb) + p5_size(nb) + 3490816;
}

static void run_group(const float* const emb[4], const float* emb_all,
                      const float* const Wq[4],
                      const float* Wmk, const float* Wmv,
                      const float* Wk, const float* Wv,
                      bf16* Wm_all, bf16* Wp_all,
                      float* out, const size_t* out_off,
                      char* ws, int nb, hipStream_t stream) {
  const size_t szBig = (size_t)nb * 7864320;
  char* P1 = ws;
  char* P2 = P1 + szBig;
  char* P3 = P2 + szBig;
  char* P4 = P3 + szBig;
  char* P5 = P4 + p4_size(nb);
  char* FX = P5 + p5_size(nb);

  bf16* kbuf = (bf16*)P1;
  bf16* vt   = (bf16*)P2;
  bf16* kvexp = (bf16*)P3;     // kexp, then vexp, then qexp
  float* attnb = (float*)P3;
  bf16* embT_all = (bf16*)P4;
  bf16* Wmv_bf = (bf16*)(P4 + (size_t)nb * 1966080);
  bf16* vhalf = (bf16*)P4;
  bf16* qbuf = (bf16*)P4;      // also embT_i, probs
  bf16* probsb = (bf16*)P4;
  bf16* Wmk_bf = (bf16*)P5;
  bf16* OtT = (bf16*)P5;
  float* stats = (float*)(FX + 3481600);        // 512 B
  float* part  = (float*)(FX + 3482112);        // 8192 B

  const float qk_scale = 1.0f / sqrtf((float)KV_);
  const int CHs[4] = {64, 128, 256, 512};
  const size_t wm_off[4] = {0, 16384, 81920, 344064};   // elems
  const size_t wp_off[4] = {0, 4096, 20480, 86016};
  const int chunkB = (nb + 1) / 2;

  // -- prologue: shared K/V --------------------------------------------------
  castw<<<3600, 256, 0, stream>>>(Wmk, Wmk_bf, 3686400);
  castw<<<3600, 256, 0, stream>>>(Wmv, Wmv_bf, 3686400);
  tcast<float><<<dim3(32, 30, nb), 256, 0, stream>>>(emb_all, embT_all, 960,
                                                     983040LL, 983040LL);
  // K: expand (P3) -> dw3x3+l2norm -> kbuf (P1)
  gemm_mfma<1, false><<<dim3(8, 30, nb), 256, 0, stream>>>(
      Wmk_bf, embT_all, kvexp, 3840, 1024, 960, 1, 0, 0, 983040LL, 0,
      3932160LL, 1024, 1.f, nullptr);
  dw3x3v<true><<<nb * CKV_, 256, 0, stream>>>(kvexp, Wk, kbuf, CKV_);
  // V: expand (P3) -> chunks: dw3x3 -> vhalf -> tcast -> vt
  gemm_mfma<1, false><<<dim3(8, 30, nb), 256, 0, stream>>>(
      Wmv_bf, embT_all, kvexp, 3840, 1024, 960, 1, 0, 0, 983040LL, 0,
      3932160LL, 1024, 1.f, nullptr);
  for (int cb = 0; cb < nb; cb += chunkB) {
    int cn = (nb - cb) < chunkB ? (nb - cb) : chunkB;
    dw3x3v<false><<<cn * CKV_, 256, 0, stream>>>(kvexp + (size_t)cb * 3932160,
                                                 Wv, vhalf, CKV_);
    tcast<bf16><<<dim3(32, 30, cn * 4), 256, 0, stream>>>(
        vhalf, vt + (size_t)cb * 3932160, 960, 983040LL, 983040LL);
  }

  // -- branches --------------------------------------------------------------
  for (int br = 0; br < 4; br++) {
    const int c = CHs[br];
    const int C4 = c * 4;
    const int mtiles = (c + 127) / 128;
    bf16* Wm_bf = Wm_all + wm_off[br];
    bf16* Wp_bf = Wp_all + wp_off[br];
    // embT_i in P4 (qbuf region)
    tcast<float><<<dim3(32, c / 32, nb), 256, 0, stream>>>(
        emb[br], qbuf, c, (long long)c * 1024, (long long)c * 1024);
    // q-expand -> P3 (qexp)
    gemm_mfma<1, false><<<dim3(8, C4 / 128, nb), 256, 0, stream>>>(
        Wm_bf, qbuf, kvexp, C4, 1024, c, 1, 0, 0, (long long)c * 1024, 0,
        (long long)C4 * 1024, 1024, 1.f, nullptr);
    // grouped 3x3 + l2norm: P3 -> qbuf (P4)
    gq3x3v<<<nb * C4, 256, 0, stream>>>(kvexp, Wq[br], qbuf, C4);
    // attn = scale * q k^T -> attnb (P3), with fused stats partials
    gemm_mfma<0, true><<<dim3(8, mtiles, nb * 4), 256, 0, stream>>>(
        qbuf, kbuf, attnb, c, 960, 1024, 1, (long long)c * 1024, 0, 983040LL,
        0, (long long)c * 960, 960, qk_scale, part);
    inorm_fin<<<1, 64, 0, stream>>>(part, stats, nb * 4, mtiles * 8, c);
    softmax_rows<<<nb * 4 * c, 256, 0, stream>>>(attnb, stats, probsb, c);
    // PV head-sum (nh=4, 0.25 folded) -> Ot[n][i] bf16 (P5)
    gemm_mfma<2, false><<<dim3(8, mtiles, nb), 256, 0, stream>>>(
        probsb, vt, OtT, c, 1024, 960, 4, (long long)4 * c * 960,
        (long long)c * 960, 3932160LL, 983040LL, (long long)1024 * c, c,
        0.25f, nullptr);
    // final projection -> f32 d_out
    gemm_mfma<0, false><<<dim3(8, mtiles, nb), 256, 0, stream>>>(
        Wp_bf, OtT, out + out_off[br], c, 1024, c, 1, 0, 0,
        (long long)1024 * c, 0, (long long)c * 1024, 1024, 1.f, nullptr);
  }
}

extern "C" void kernel_launch(void* const* d_in, const int* in_sizes, int n_in,
                              void* d_out, int out_size, void* d_ws, size_t ws_size,
                              hipStream_t stream) {
  const float* emb[4] = {(const float*)d_in[0], (const float*)d_in[1],
                         (const float*)d_in[2], (const float*)d_in[3]};
  const float* emb_all = (const float*)d_in[4];
  const float* Wm[4] = {(const float*)d_in[5], (const float*)d_in[8],
                        (const float*)d_in[11], (const float*)d_in[14]};
  const float* Wq[4] = {(const float*)d_in[6], (const float*)d_in[9],
                        (const float*)d_in[12], (const float*)d_in[15]};
  const float* Wp[4] = {(const float*)d_in[7], (const float*)d_in[10],
                        (const float*)d_in[13], (const float*)d_in[16]};
  const float* Wmk = (const float*)d_in[17];
  const float* Wmv = (const float*)d_in[18];
  const float* Wk = (const float*)d_in[19];
  const float* Wv = (const float*)d_in[20];
  float* out = (float*)d_out;

  const int CHs[4] = {64, 128, 256, 512};
  const size_t out_off_full[4] = {0, 524288, 1572864, 3670016};
  const size_t wm_off[4] = {0, 16384, 81920, 344064};
  const size_t wp_off[4] = {0, 4096, 20480, 86016};

  int nb = 1;
  if (ws_size >= total_need(8)) nb = 8;
  else if (ws_size >= total_need(4)) nb = 4;
  else if (ws_size >= total_need(2)) nb = 2;

  // FX region (persistent weight casts) lives at the tail of the plan
  char* FX = (char*)d_ws + 3 * (size_t)nb * 7864320 + p4_size(nb) + p5_size(nb);
  bf16* Wm_all = (bf16*)FX;
  bf16* Wp_all = (bf16*)(FX + 2785280);

  // prologue: cast all branch weights once
  for (int br = 0; br < 4; br++) {
    const int c = CHs[br];
    castw<<<(4 * c * c / 4 + 255) / 256, 256, 0, stream>>>(
        Wm[br], Wm_all + wm_off[br], 4 * c * c);
    castw<<<(c * c / 4 + 255) / 256, 256, 0, stream>>>(
        Wp[br], Wp_all + wp_off[br], c * c);
  }

  for (int b0 = 0; b0 < B_; b0 += nb) {
    const float* embB[4];
    for (int i = 0; i < 4; i++) embB[i] = emb[i] + (size_t)b0 * CHs[i] * HW_;
    const float* emb_allB = emb_all + (size_t)b0 * KV_ * HW_;
    size_t out_offB[4];
    for (int i = 0; i < 4; i++)
      out_offB[i] = out_off_full[i] + (size_t)b0 * CHs[i] * HW_;
    run_group(embB, emb_allB, Wq, Wmk, Wmv, Wk, Wv, Wm_all, Wp_all,
              out, out_offB, (char*)d_ws, nb, stream);
  }
}

// Round 7
// 1050.833 us; speedup vs baseline: 9.9667x; 1.0401x over previous
//
#include <hip/hip_runtime.h>
#include <hip/hip_bf16.h>
#include <math.h>

typedef __hip_bfloat16 bf16;
typedef __attribute__((ext_vector_type(8))) short short8;
typedef __attribute__((ext_vector_type(4))) float f32x4;
typedef long long ll;

#define B_ 8
#define HEADS_ 4
#define KV_ 960
#define HW_ 1024
#define CKV_ 3840   // KV_*HEADS_

// ---------------------------------------------------------------------------
// helpers
// ---------------------------------------------------------------------------
__device__ __forceinline__ float wredsum(float v) {
#pragma unroll
  for (int o = 32; o > 0; o >>= 1) v += __shfl_xor(v, o);
  return v;
}
__device__ __forceinline__ float wredmax(float v) {
#pragma unroll
  for (int o = 32; o > 0; o >>= 1) v = fmaxf(v, __shfl_xor(v, o));
  return v;
}

__device__ __forceinline__ float bfu2f(unsigned short u) {
  union { unsigned int i; float f; } c;
  c.i = ((unsigned int)u) << 16;
  return c.f;
}
__device__ __forceinline__ unsigned short f2bfu(float f) {
  bf16 h = __float2bfloat16(f);
  return *(unsigned short*)&h;
}

__device__ __forceinline__ void gl_lds16(const void* g, void* l) {
  __builtin_amdgcn_global_load_lds(
      (const __attribute__((address_space(1))) unsigned*)g,
      (__attribute__((address_space(3))) unsigned*)l, 16, 0, 0);
}

// ---------------------------------------------------------------------------
// K0a: elementwise f32 -> bf16 cast (weights). n % 4 == 0.
// ---------------------------------------------------------------------------
__global__ void __launch_bounds__(256) castw(const float* __restrict__ in,
                                             bf16* __restrict__ out, int n) {
  int i = (blockIdx.x * 256 + threadIdx.x) * 4;
  if (i < n) {
    float4 v = *(const float4*)(in + i);
    out[i] = __float2bfloat16(v.x);
    out[i + 1] = __float2bfloat16(v.y);
    out[i + 2] = __float2bfloat16(v.z);
    out[i + 3] = __float2bfloat16(v.w);
  }
}

// ---------------------------------------------------------------------------
// K0b: transpose+cast: in [z][R][1024] (f32 or bf16) -> out [z][1024][R] bf16.
// ---------------------------------------------------------------------------
template <typename InT>
__global__ void __launch_bounds__(256) tcast(const InT* __restrict__ in,
                                             bf16* __restrict__ out, int R,
                                             ll inZ, ll outZ) {
  __shared__ float t[32][33];
  const int x = threadIdx.x & 31, y0 = threadIdx.x >> 5;
  const int c0 = blockIdx.x << 5, r0 = blockIdx.y << 5;
  const InT* ip = in + (ll)blockIdx.z * inZ + (ll)r0 * 1024 + c0;
  bf16* op = out + (ll)blockIdx.z * outZ + (ll)c0 * R + r0;
#pragma unroll
  for (int i = 0; i < 4; i++) {
    int r = y0 + i * 8;
    float v;
    if constexpr (__is_same(InT, float)) v = ip[(ll)r * 1024 + x];
    else v = __bfloat162float(ip[(ll)r * 1024 + x]);
    t[r][x] = v;
  }
  __syncthreads();
#pragma unroll
  for (int i = 0; i < 4; i++) {
    int cc = y0 + i * 8;
    op[(ll)cc * R + x] = __float2bfloat16(t[x][cc]);
  }
}

// ---------------------------------------------------------------------------
// gemm_mfma: 128x128 / BK=32 / 2-phase dbuf kernel (R6, proven) — used for
// small-M shapes (c in {64,128} branches).
// ---------------------------------------------------------------------------
template <int OUTMODE, bool STATS>
__global__ void __launch_bounds__(256) gemm_mfma(
    const bf16* __restrict__ A, const bf16* __restrict__ Bt, void* __restrict__ Y,
    int M, int N, int K, int nh,
    ll aZ, ll aH, ll bZ, ll bH, ll yZ, int ldy, float scale,
    float* __restrict__ part) {
  __shared__ bf16 As[2][128 * 32];
  __shared__ bf16 Bs[2][128 * 32];
  __shared__ float rs1[4], rs2[4];
  const int tid = threadIdx.x;
  const int lane = tid & 63;
  const int wave = tid >> 6;
  const int wr = wave >> 1, wc = wave & 1;

  const int gy = gridDim.y, gz = gridDim.z;
  int orig = (blockIdx.z * gy + blockIdx.y) * 8 + blockIdx.x;
  int cpx = (gy * gz);
  int flat = (orig & 7) * cpx + (orig >> 3);
  const int lx = flat & 7;
  int rest = flat >> 3;
  const int ly = rest % gy;
  const int lz = rest / gy;

  const int z = lz;
  const int m0 = ly << 7, n0 = lx << 7;

  f32x4 acc[4][4];
#pragma unroll
  for (int i = 0; i < 4; i++)
#pragma unroll
    for (int j = 0; j < 4; j++) acc[i][j] = (f32x4){0.f, 0.f, 0.f, 0.f};

  const int frow = lane & 15;
  const int kq = lane >> 4;

  const bf16* Ah = A + (ll)z * aZ;
  const bf16* Bh = Bt + (ll)z * bZ;
  int k0n = 0;

  auto stage = [&](int buf) {
#pragma unroll
    for (int t = 0; t < 2; t++) {
      const int e = (wave * 2 + t) * 64 + lane;
      const int row = e >> 2;
      const int ks = (e & 3) ^ ((row >> 1) & 3);
      int gr = m0 + row; gr = gr < M ? gr : M - 1;
      gl_lds16(Ah + (ll)gr * K + k0n + ks * 8,
               (char*)&As[buf][0] + (wave * 2 + t) * 1024);
      int rn = n0 + row; rn = rn < N ? rn : N - 1;
      gl_lds16(Bh + (ll)rn * K + k0n + ks * 8,
               (char*)&Bs[buf][0] + (wave * 2 + t) * 1024);
    }
  };

  const int kpt = K >> 5;
  const int iters = nh * kpt;
  stage(0);
  __syncthreads();

  int buf = 0;
  for (int it = 0; it < iters; ++it) {
    if (it + 1 < iters) {
      k0n += 32;
      if (k0n == K) { k0n = 0; Ah += aH; Bh += bH; }
      stage(buf ^ 1);
    }
    short8 af[4], bfr[4];
#pragma unroll
    for (int fm = 0; fm < 4; fm++) {
      const int row = wr * 64 + fm * 16 + frow;
      af[fm] = *(const short8*)&As[buf][((row << 2) | (kq ^ ((row >> 1) & 3))) << 3];
    }
#pragma unroll
    for (int fn = 0; fn < 4; fn++) {
      const int row = wc * 64 + fn * 16 + frow;
      bfr[fn] = *(const short8*)&Bs[buf][((row << 2) | (kq ^ ((row >> 1) & 3))) << 3];
    }
#pragma unroll
    for (int fm = 0; fm < 4; fm++)
#pragma unroll
      for (int fn = 0; fn < 4; fn++)
        acc[fm][fn] = __builtin_amdgcn_mfma_f32_16x16x32_bf16(
            af[fm], bfr[fn], acc[fm][fn], 0, 0, 0);
    __syncthreads();
    buf ^= 1;
  }

  const int rq = kq << 2;
  float lsum = 0.f, lsq = 0.f;
#pragma unroll
  for (int fm = 0; fm < 4; fm++) {
    const int mrow = m0 + wr * 64 + fm * 16 + rq;
#pragma unroll
    for (int fn = 0; fn < 4; fn++) {
      const int ncol = n0 + wc * 64 + fn * 16 + frow;
      if (ncol >= N) continue;
      if constexpr (OUTMODE == 0) {
        float* Yp = (float*)Y + (ll)z * yZ;
#pragma unroll
        for (int i = 0; i < 4; i++)
          if (mrow + i < M) {
            float v = acc[fm][fn][i] * scale;
            Yp[(ll)(mrow + i) * ldy + ncol] = v;
            if constexpr (STATS) { lsum += v; lsq += v * v; }
          }
      } else if constexpr (OUTMODE == 1) {
        bf16* Yp = (bf16*)Y + (ll)z * yZ;
#pragma unroll
        for (int i = 0; i < 4; i++)
          if (mrow + i < M)
            Yp[(ll)(mrow + i) * ldy + ncol] =
                __float2bfloat16(acc[fm][fn][i] * scale);
      } else {
        if (mrow < M) {
          bf16* Yp = (bf16*)Y + (ll)z * yZ + (ll)ncol * ldy + mrow;
#pragma unroll
          for (int i = 0; i < 4; i++)
            Yp[i] = __float2bfloat16(acc[fm][fn][i] * scale);
        }
      }
    }
  }
  if constexpr (STATS) {
    lsum = wredsum(lsum);
    lsq = wredsum(lsq);
    if (lane == 0) { rs1[wave] = lsum; rs2[wave] = lsq; }
    __syncthreads();
    if (tid == 0) {
      int slot = ly * 8 + lx;
      part[((ll)z * 32 + slot) * 2] = rs1[0] + rs1[1] + rs1[2] + rs1[3];
      part[((ll)z * 32 + slot) * 2 + 1] = rs2[0] + rs2[1] + rs2[2] + rs2[3];
    }
  }
}

// ---------------------------------------------------------------------------
// gemm8: 256x256 tile, BK=64, 512 thr (8 waves 2Mx4N), double-buffered LDS,
// 4-phase K-tile schedule with counted vmcnt (never 0 in steady state),
// setprio around MFMA clusters, kslot^row&7 LDS swizzle (uniform bank spread).
// Staging order per tile: B r0,r1 | B r2,r3 | A r0,r2 | A r1,r3 (2/phase).
// Phase p computes m-frag pair (2p, 2p+1) over 4 n-frags x 2 k-halves.
// Sync: p0: vmcnt(2)+bar (needs oldest 6 = B all + A r0,r2); p2: vmcnt(4)+bar.
// ---------------------------------------------------------------------------
template <int OUTMODE, bool STATS>
__global__ void __launch_bounds__(512, 2) gemm8(
    const bf16* __restrict__ A, const bf16* __restrict__ Bt, void* __restrict__ Y,
    int M, int N, int K, int nh,
    ll aZ, ll aH, ll bZ, ll bH, ll yZ, int ldy, float scale,
    float* __restrict__ part) {
  __shared__ char lds[131072];           // [A0|A1|B0|B1] each 32KB
  __shared__ float rs1[8], rs2[8];
  const int tid = threadIdx.x;
  const int lane = tid & 63;
  const int wave = tid >> 6;             // 0..7
  const int wm = wave >> 2, wn = wave & 3;

  // general bijective XCD-chunked remap
  const int nx = gridDim.x, my = gridDim.y;
  const int nwg = nx * my * gridDim.z;
  int orig = (blockIdx.z * my + blockIdx.y) * nx + blockIdx.x;
  int q8 = nwg >> 3, r8 = nwg & 7;
  int xcd = orig & 7, bidx = orig >> 3;
  int flat = (xcd < r8) ? xcd * (q8 + 1) + bidx
                        : r8 * (q8 + 1) + (xcd - r8) * q8 + bidx;
  const int lx = flat % nx;
  int rest = flat / nx;
  const int ly = rest % my;
  const int lz = rest / my;

  const int m0 = ly << 8, n0 = lx << 8;
  const int ktiles = K >> 6;
  const int nt = nh * ktiles;

  f32x4 acc[8][4];
#pragma unroll
  for (int i = 0; i < 8; i++)
#pragma unroll
    for (int j = 0; j < 4; j++) acc[i][j] = (f32x4){0.f, 0.f, 0.f, 0.f};

  const int frow = lane & 15;
  const int kq = lane >> 4;
  const int swz = frow & 7;

  // stage one 8KB round (r = 0..3) of matrix (matB) for tile tt into buf.
  auto stageRound = [&](int matB, int r, int tt, int buf) {
    int h = tt / ktiles;
    int koff = (tt % ktiles) << 6;
    int s = (r << 9) + tid;              // 0..2047
    int row = s >> 3;
    int ks = (s & 7) ^ (row & 7);
    const bf16* src;
    char* dst;
    if (!matB) {
      int gr = m0 + row; gr = gr < M ? gr : M - 1;
      src = A + (ll)lz * aZ + (ll)h * aH + (ll)gr * K + koff + (ks << 3);
      dst = lds + buf * 32768 + (((r << 3) + wave) << 10);
    } else {
      int gr = n0 + row; gr = gr < N ? gr : N - 1;
      src = Bt + (ll)lz * bZ + (ll)h * bH + (ll)gr * K + koff + (ks << 3);
      dst = lds + 65536 + buf * 32768 + (((r << 3) + wave) << 10);
    }
    gl_lds16(src, dst);
  };

  auto readA = [&](int fm, int kh, int cur) -> short8 {
    int row = wm * 128 + fm * 16 + frow;
    int slot = (kq + (kh << 2)) ^ swz;
    return *(const short8*)(lds + cur * 32768 + row * 128 + slot * 16);
  };
  auto readB = [&](int fn, int kh, int cur) -> short8 {
    int row = wn * 64 + fn * 16 + frow;
    int slot = (kq + (kh << 2)) ^ swz;
    return *(const short8*)(lds + 65536 + cur * 32768 + row * 128 + slot * 16);
  };

  // prologue: tile 0 in steady-state order
  stageRound(1, 0, 0, 0); stageRound(1, 1, 0, 0);
  stageRound(1, 2, 0, 0); stageRound(1, 3, 0, 0);
  stageRound(0, 0, 0, 0); stageRound(0, 2, 0, 0);
  stageRound(0, 1, 0, 0); stageRound(0, 3, 0, 0);

  int cur = 0;
  for (int tt = 0; tt < nt; ++tt) {
    const bool hasNext = (tt + 1 < nt);
    short8 bfr[4][2];
#pragma unroll
    for (int p = 0; p < 4; p++) {
      if (p == 0) {
        if (hasNext) asm volatile("s_waitcnt vmcnt(2)" ::: "memory");
        else         asm volatile("s_waitcnt vmcnt(0)" ::: "memory");
        __builtin_amdgcn_s_barrier();
        __builtin_amdgcn_sched_barrier(0);
#pragma unroll
        for (int fn = 0; fn < 4; fn++)
#pragma unroll
          for (int kh = 0; kh < 2; kh++) bfr[fn][kh] = readB(fn, kh, cur);
      }
      if (p == 2) {
        if (hasNext) asm volatile("s_waitcnt vmcnt(4)" ::: "memory");
        __builtin_amdgcn_s_barrier();
        __builtin_amdgcn_sched_barrier(0);
      }
      short8 a0k0 = readA(2 * p, 0, cur), a0k1 = readA(2 * p, 1, cur);
      short8 a1k0 = readA(2 * p + 1, 0, cur), a1k1 = readA(2 * p + 1, 1, cur);
      if (hasNext) {
        if (p == 0) { stageRound(1, 0, tt + 1, cur ^ 1); stageRound(1, 1, tt + 1, cur ^ 1); }
        else if (p == 1) { stageRound(1, 2, tt + 1, cur ^ 1); stageRound(1, 3, tt + 1, cur ^ 1); }
        else if (p == 2) { stageRound(0, 0, tt + 1, cur ^ 1); stageRound(0, 2, tt + 1, cur ^ 1); }
        else { stageRound(0, 1, tt + 1, cur ^ 1); stageRound(0, 3, tt + 1, cur ^ 1); }
      }
      __builtin_amdgcn_s_setprio(1);
#pragma unroll
      for (int fn = 0; fn < 4; fn++) {
        acc[2 * p][fn] = __builtin_amdgcn_mfma_f32_16x16x32_bf16(
            a0k0, bfr[fn][0], acc[2 * p][fn], 0, 0, 0);
        acc[2 * p][fn] = __builtin_amdgcn_mfma_f32_16x16x32_bf16(
            a0k1, bfr[fn][1], acc[2 * p][fn], 0, 0, 0);
        acc[2 * p + 1][fn] = __builtin_amdgcn_mfma_f32_16x16x32_bf16(
            a1k0, bfr[fn][0], acc[2 * p + 1][fn], 0, 0, 0);
        acc[2 * p + 1][fn] = __builtin_amdgcn_mfma_f32_16x16x32_bf16(
            a1k1, bfr[fn][1], acc[2 * p + 1][fn], 0, 0, 0);
      }
      __builtin_amdgcn_s_setprio(0);
    }
    cur ^= 1;
  }

  const int rq = kq << 2;   // C/D: row=(lane>>4)*4+reg, col=lane&15
  float lsum = 0.f, lsq = 0.f;
#pragma unroll
  for (int fm = 0; fm < 8; fm++) {
    const int mrow = m0 + wm * 128 + fm * 16 + rq;
#pragma unroll
    for (int fn = 0; fn < 4; fn++) {
      const int ncol = n0 + wn * 64 + fn * 16 + frow;
      if (ncol >= N) continue;
      if constexpr (OUTMODE == 0) {
        float* Yp = (float*)Y + (ll)lz * yZ;
#pragma unroll
        for (int i = 0; i < 4; i++)
          if (mrow + i < M) {
            float v = acc[fm][fn][i] * scale;
            Yp[(ll)(mrow + i) * ldy + ncol] = v;
            if constexpr (STATS) { lsum += v; lsq += v * v; }
          }
      } else if constexpr (OUTMODE == 1) {
        bf16* Yp = (bf16*)Y + (ll)lz * yZ;
#pragma unroll
        for (int i = 0; i < 4; i++)
          if (mrow + i < M)
            Yp[(ll)(mrow + i) * ldy + ncol] =
                __float2bfloat16(acc[fm][fn][i] * scale);
      } else {
        if (mrow < M) {
          bf16* Yp = (bf16*)Y + (ll)lz * yZ + (ll)ncol * ldy + mrow;
#pragma unroll
          for (int i = 0; i < 4; i++)
            Yp[i] = __float2bfloat16(acc[fm][fn][i] * scale);
        }
      }
    }
  }
  if constexpr (STATS) {
    lsum = wredsum(lsum);
    lsq = wredsum(lsq);
    if (lane == 0) { rs1[wave] = lsum; rs2[wave] = lsq; }
    __syncthreads();
    if (tid == 0) {
      float s = 0.f, s2 = 0.f;
#pragma unroll
      for (int w = 0; w < 8; w++) { s += rs1[w]; s2 += rs2[w]; }
      int slot = ly * nx + lx;
      part[((ll)lz * 32 + slot) * 2] = s;
      part[((ll)lz * 32 + slot) * 2 + 1] = s2;
    }
  }
}

// ---------------------------------------------------------------------------
// K2: depthwise 3x3 (pad 1), optional fused l2norm. 256 thr, 4 px/thread.
// ---------------------------------------------------------------------------
template <bool NORM>
__global__ void __launch_bounds__(256) dw3x3v(const bf16* __restrict__ in,
                                              const float* __restrict__ w9,
                                              bf16* __restrict__ out, int C) {
  __shared__ float tile[34][36];
  __shared__ float red[4];
  const int bc = blockIdx.x;
  const int ch = bc % C;
  const int tid = threadIdx.x;
  const int y = tid >> 3;
  const int x0 = (tid & 7) << 2;
  const bf16* ip = in + ((size_t)bc << 10);

  ushort4 u = *(const ushort4*)(ip + (y << 5) + x0);
  tile[y + 1][x0 + 1] = bfu2f(u.x);
  tile[y + 1][x0 + 2] = bfu2f(u.y);
  tile[y + 1][x0 + 3] = bfu2f(u.z);
  tile[y + 1][x0 + 4] = bfu2f(u.w);
  if (tid < 34) { tile[0][tid] = 0.f; tile[33][tid] = 0.f; }
  if (tid < 32) { tile[tid + 1][0] = 0.f; tile[tid + 1][33] = 0.f; }
  __syncthreads();

  const float* wc = w9 + ch * 9;
  float s[4] = {0.f, 0.f, 0.f, 0.f};
#pragma unroll
  for (int dy = 0; dy < 3; dy++) {
    const float* tr = &tile[y + dy][x0];
    float c0 = tr[0], c1 = tr[1], c2 = tr[2], c3 = tr[3], c4 = tr[4], c5 = tr[5];
    float wa = wc[dy * 3], wb = wc[dy * 3 + 1], wd = wc[dy * 3 + 2];
    s[0] += c0 * wa + c1 * wb + c2 * wd;
    s[1] += c1 * wa + c2 * wb + c3 * wd;
    s[2] += c2 * wa + c3 * wb + c4 * wd;
    s[3] += c3 * wa + c4 * wb + c5 * wd;
  }

  float inv = 1.f;
  if (NORM) {
    float ss = s[0] * s[0] + s[1] * s[1] + s[2] * s[2] + s[3] * s[3];
    ss = wredsum(ss);
    const int lane = tid & 63, wid = tid >> 6;
    if (lane == 0) red[wid] = ss;
    __syncthreads();
    inv = 1.0f / fmaxf(sqrtf(red[0] + red[1] + red[2] + red[3]), 1e-12f);
  }
  ushort4 o4;
  o4.x = f2bfu(s[0] * inv);
  o4.y = f2bfu(s[1] * inv);
  o4.z = f2bfu(s[2] * inv);
  o4.w = f2bfu(s[3] * inv);
  *(ushort4*)(out + ((size_t)bc << 10) + (y << 5) + x0) = o4;
}

// ---------------------------------------------------------------------------
// K3: grouped 3x3 (2 in-ch per group) + fused l2norm. 256 thr, 4 px/thread.
// ---------------------------------------------------------------------------
__global__ void __launch_bounds__(256) gq3x3v(const bf16* __restrict__ in,
                                              const float* __restrict__ wq,
                                              bf16* __restrict__ out, int C4) {
  __shared__ float t0[34][36];
  __shared__ float t1[34][36];
  __shared__ float red[4];
  const int bo = blockIdx.x;
  const int o = bo % C4;
  const int b = bo / C4;
  const int ic0 = (o >> 1) << 1;
  const int tid = threadIdx.x;
  const int y = tid >> 3;
  const int x0 = (tid & 7) << 2;
  const bf16* p0 = in + (((size_t)b * C4 + ic0) << 10);

  ushort4 u0 = *(const ushort4*)(p0 + (y << 5) + x0);
  ushort4 u1 = *(const ushort4*)(p0 + 1024 + (y << 5) + x0);
  t0[y + 1][x0 + 1] = bfu2f(u0.x);
  t0[y + 1][x0 + 2] = bfu2f(u0.y);
  t0[y + 1][x0 + 3] = bfu2f(u0.z);
  t0[y + 1][x0 + 4] = bfu2f(u0.w);
  t1[y + 1][x0 + 1] = bfu2f(u1.x);
  t1[y + 1][x0 + 2] = bfu2f(u1.y);
  t1[y + 1][x0 + 3] = bfu2f(u1.z);
  t1[y + 1][x0 + 4] = bfu2f(u1.w);
  if (tid < 34) {
    t0[0][tid] = 0.f; t0[33][tid] = 0.f;
    t1[0][tid] = 0.f; t1[33][tid] = 0.f;
  }
  if (tid < 32) {
    t0[tid + 1][0] = 0.f; t0[tid + 1][33] = 0.f;
    t1[tid + 1][0] = 0.f; t1[tid + 1][33] = 0.f;
  }
  __syncthreads();

  const float* w = wq + o * 18;
  float s[4] = {0.f, 0.f, 0.f, 0.f};
#pragma unroll
  for (int dy = 0; dy < 3; dy++) {
    {
      const float* tr = &t0[y + dy][x0];
      float c0 = tr[0], c1 = tr[1], c2 = tr[2], c3 = tr[3], c4 = tr[4], c5 = tr[5];
      float wa = w[dy * 3], wb = w[dy * 3 + 1], wd = w[dy * 3 + 2];
      s[0] += c0 * wa + c1 * wb + c2 * wd;
      s[1] += c1 * wa + c2 * wb + c3 * wd;
      s[2] += c2 * wa + c3 * wb + c4 * wd;
      s[3] += c3 * wa + c4 * wb + c5 * wd;
    }
    {
      const float* tr = &t1[y + dy][x0];
      float c0 = tr[0], c1 = tr[1], c2 = tr[2], c3 = tr[3], c4 = tr[4], c5 = tr[5];
      float wa = w[9 + dy * 3], wb = w[9 + dy * 3 + 1], wd = w[9 + dy * 3 + 2];
      s[0] += c0 * wa + c1 * wb + c2 * wd;
      s[1] += c1 * wa + c2 * wb + c3 * wd;
      s[2] += c2 * wa + c3 * wb + c4 * wd;
      s[3] += c3 * wa + c4 * wb + c5 * wd;
    }
  }

  float ss = s[0] * s[0] + s[1] * s[1] + s[2] * s[2] + s[3] * s[3];
  ss = wredsum(ss);
  const int lane = tid & 63, wid = tid >> 6;
  if (lane == 0) red[wid] = ss;
  __syncthreads();
  float inv = 1.0f / fmaxf(sqrtf(red[0] + red[1] + red[2] + red[3]), 1e-12f);

  ushort4 o4;
  o4.x = f2bfu(s[0] * inv);
  o4.y = f2bfu(s[1] * inv);
  o4.z = f2bfu(s[2] * inv);
  o4.w = f2bfu(s[3] * inv);
  *(ushort4*)(out + ((size_t)bo << 10) + (y << 5) + x0) = o4;
}

// ---------------------------------------------------------------------------
// K6: row softmax over 960 with inline InstanceNorm stats from partials.
// ---------------------------------------------------------------------------
__global__ void __launch_bounds__(256) softmax_rows(const float* __restrict__ attn,
                                                    const float* __restrict__ part,
                                                    int nslots,
                                                    bf16* __restrict__ probs, int c) {
  __shared__ float rm[4], rs[4];
  const int row = blockIdx.x;
  const int bh = row / c;
  const float* p = attn + (size_t)row * 960;
  bf16* op = probs + (size_t)row * 960;
  const int tid = threadIdx.x;

  float s = 0.f, s2 = 0.f;
  for (int i = 0; i < nslots; i++) {
    s += part[((ll)bh * 32 + i) * 2];
    s2 += part[((ll)bh * 32 + i) * 2 + 1];
  }
  const float n = (float)(c * 960);
  const float mu = s / n;
  const float var = s2 / n - mu * mu;
  const float rstd = rsqrtf(var + 1e-5f);

  float v[4];
  float mx = -1e30f;
#pragma unroll
  for (int u = 0; u < 4; u++) {
    int j = tid + (u << 8);
    if (j < 960) {
      v[u] = (p[j] - mu) * rstd;
      mx = fmaxf(mx, v[u]);
    } else {
      v[u] = -1e30f;
    }
  }
  mx = wredmax(mx);
  const int lane = tid & 63, wid = tid >> 6;
  if (lane == 0) rm[wid] = mx;
  __syncthreads();
  mx = fmaxf(fmaxf(rm[0], rm[1]), fmaxf(rm[2], rm[3]));

  float sum = 0.f;
#pragma unroll
  for (int u = 0; u < 4; u++) {
    int j = tid + (u << 8);
    if (j < 960) {
      v[u] = __expf(v[u] - mx);
      sum += v[u];
    }
  }
  sum = wredsum(sum);
  if (lane == 0) rs[wid] = sum;
  __syncthreads();
  sum = rs[0] + rs[1] + rs[2] + rs[3];
  const float inv = 1.0f / sum;
#pragma unroll
  for (int u = 0; u < 4; u++) {
    int j = tid + (u << 8);
    if (j < 960) op[j] = __float2bfloat16(v[u] * inv);
  }
}

// ---------------------------------------------------------------------------
// Workspace plan — identical to R6 (proven to fit).
// ---------------------------------------------------------------------------
static size_t p4_size(int nb) {
  const int chunkB = (nb + 1) / 2;
  size_t a = (size_t)nb * 4194304;
  size_t b = (size_t)nb * 1966080 + 7372800;
  size_t c = (size_t)chunkB * 7864320;
  size_t m = a > b ? a : b;
  return m > c ? m : c;
}
static size_t p5_size(int nb) {
  size_t a = (size_t)nb * 1048576;
  return a > 7372800 ? a : 7372800;
}
static size_t total_need(int nb) {
  return 3 * (size_t)nb * 7864320 + p4_size(nb) + p5_size(nb) + 3490816;
}

static void run_group(const float* const emb[4], const float* emb_all,
                      const float* const Wq[4],
                      const float* Wmk, const float* Wmv,
                      const float* Wk, const float* Wv,
                      bf16* Wm_all, bf16* Wp_all,
                      float* out, const size_t* out_off,
                      char* ws, int nb, hipStream_t stream) {
  const size_t szBig = (size_t)nb * 7864320;
  char* P1 = ws;
  char* P2 = P1 + szBig;
  char* P3 = P2 + szBig;
  char* P4 = P3 + szBig;
  char* P5 = P4 + p4_size(nb);
  char* FX = P5 + p5_size(nb);

  bf16* kbuf = (bf16*)P1;
  bf16* vt   = (bf16*)P2;
  bf16* kvexp = (bf16*)P3;
  float* attnb = (float*)P3;
  bf16* embT_all = (bf16*)P4;
  bf16* Wmv_bf = (bf16*)(P4 + (size_t)nb * 1966080);
  bf16* vhalf = (bf16*)P4;
  bf16* qbuf = (bf16*)P4;
  bf16* probsb = (bf16*)P4;
  bf16* Wmk_bf = (bf16*)P5;
  bf16* OtT = (bf16*)P5;
  float* part = (float*)(FX + 3482112);   // 8192 B

  const float qk_scale = 1.0f / sqrtf((float)KV_);
  const int CHs[4] = {64, 128, 256, 512};
  const size_t wm_off[4] = {0, 16384, 81920, 344064};
  const size_t wp_off[4] = {0, 4096, 20480, 86016};
  const int chunkB = (nb + 1) / 2;

  // -- prologue: shared K/V --------------------------------------------------
  castw<<<3600, 256, 0, stream>>>(Wmk, Wmk_bf, 3686400);
  castw<<<3600, 256, 0, stream>>>(Wmv, Wmv_bf, 3686400);
  tcast<float><<<dim3(32, 30, nb), 256, 0, stream>>>(emb_all, embT_all, 960,
                                                     983040LL, 983040LL);
  gemm8<1, false><<<dim3(4, 15, nb), 512, 0, stream>>>(
      Wmk_bf, embT_all, kvexp, 3840, 1024, 960, 1, 0, 0, 983040LL, 0,
      3932160LL, 1024, 1.f, nullptr);
  dw3x3v<true><<<nb * CKV_, 256, 0, stream>>>(kvexp, Wk, kbuf, CKV_);
  gemm8<1, false><<<dim3(4, 15, nb), 512, 0, stream>>>(
      Wmv_bf, embT_all, kvexp, 3840, 1024, 960, 1, 0, 0, 983040LL, 0,
      3932160LL, 1024, 1.f, nullptr);
  for (int cb = 0; cb < nb; cb += chunkB) {
    int cn = (nb - cb) < chunkB ? (nb - cb) : chunkB;
    dw3x3v<false><<<cn * CKV_, 256, 0, stream>>>(kvexp + (size_t)cb * 3932160,
                                                 Wv, vhalf, CKV_);
    tcast<bf16><<<dim3(32, 30, cn * 4), 256, 0, stream>>>(
        vhalf, vt + (size_t)cb * 3932160, 960, 983040LL, 983040LL);
  }

  // -- branches --------------------------------------------------------------
  for (int br = 0; br < 4; br++) {
    const int c = CHs[br];
    const int C4 = c * 4;
    const int mtiles = (c + 127) / 128;
    bf16* Wm_bf = Wm_all + wm_off[br];
    bf16* Wp_bf = Wp_all + wp_off[br];
    // embT_i in P4 (qbuf region)
    tcast<float><<<dim3(32, c / 32, nb), 256, 0, stream>>>(
        emb[br], qbuf, c, (ll)c * 1024, (ll)c * 1024);
    // q-expand -> P3
    gemm8<1, false><<<dim3(4, C4 / 256, nb), 512, 0, stream>>>(
        Wm_bf, qbuf, kvexp, C4, 1024, c, 1, 0, 0, (ll)c * 1024, 0,
        (ll)C4 * 1024, 1024, 1.f, nullptr);
    // grouped 3x3 + l2norm: P3 -> qbuf (P4)
    gq3x3v<<<nb * C4, 256, 0, stream>>>(kvexp, Wq[br], qbuf, C4);
    // attn = scale * q k^T -> attnb (P3), fused stats partials
    int nslots;
    if (c >= 256) {
      gemm8<0, true><<<dim3(4, c / 256, nb * 4), 512, 0, stream>>>(
          qbuf, kbuf, attnb, c, 960, 1024, 1, (ll)c * 1024, 0, 983040LL, 0,
          (ll)c * 960, 960, qk_scale, part);
      nslots = (c / 256) * 4;
    } else {
      gemm_mfma<0, true><<<dim3(8, mtiles, nb * 4), 256, 0, stream>>>(
          qbuf, kbuf, attnb, c, 960, 1024, 1, (ll)c * 1024, 0, 983040LL, 0,
          (ll)c * 960, 960, qk_scale, part);
      nslots = mtiles * 8;
    }
    softmax_rows<<<nb * 4 * c, 256, 0, stream>>>(attnb, part, nslots, probsb, c);
    // PV head-sum (nh=4, 0.25 folded) -> Ot[n][i] bf16 (P5)
    if (c >= 256) {
      gemm8<2, false><<<dim3(4, c / 256, nb), 512, 0, stream>>>(
          probsb, vt, OtT, c, 1024, 960, 4, (ll)4 * c * 960, (ll)c * 960,
          3932160LL, 983040LL, (ll)1024 * c, c, 0.25f, nullptr);
    } else {
      gemm_mfma<2, false><<<dim3(8, mtiles, nb), 256, 0, stream>>>(
          probsb, vt, OtT, c, 1024, 960, 4, (ll)4 * c * 960, (ll)c * 960,
          3932160LL, 983040LL, (ll)1024 * c, c, 0.25f, nullptr);
    }
    // final projection -> f32 d_out
    if (c >= 256) {
      gemm8<0, false><<<dim3(4, c / 256, nb), 512, 0, stream>>>(
          Wp_bf, OtT, out + out_off[br], c, 1024, c, 1, 0, 0,
          (ll)1024 * c, 0, (ll)c * 1024, 1024, 1.f, nullptr);
    } else {
      gemm_mfma<0, false><<<dim3(8, mtiles, nb), 256, 0, stream>>>(
          Wp_bf, OtT, out + out_off[br], c, 1024, c, 1, 0, 0,
          (ll)1024 * c, 0, (ll)c * 1024, 1024, 1.f, nullptr);
    }
  }
}

extern "C" void kernel_launch(void* const* d_in, const int* in_sizes, int n_in,
                              void* d_out, int out_size, void* d_ws, size_t ws_size,
                              hipStream_t stream) {
  const float* emb[4] = {(const float*)d_in[0], (const float*)d_in[1],
                         (const float*)d_in[2], (const float*)d_in[3]};
  const float* emb_all = (const float*)d_in[4];
  const float* Wm[4] = {(const float*)d_in[5], (const float*)d_in[8],
                        (const float*)d_in[11], (const float*)d_in[14]};
  const float* Wq[4] = {(const float*)d_in[6], (const float*)d_in[9],
                        (const float*)d_in[12], (const float*)d_in[15]};
  const float* Wp[4] = {(const float*)d_in[7], (const float*)d_in[10],
                        (const float*)d_in[13], (const float*)d_in[16]};
  const float* Wmk = (const float*)d_in[17];
  const float* Wmv = (const float*)d_in[18];
  const float* Wk = (const float*)d_in[19];
  const float* Wv = (const float*)d_in[20];
  float* out = (float*)d_out;

  const int CHs[4] = {64, 128, 256, 512};
  const size_t out_off_full[4] = {0, 524288, 1572864, 3670016};
  const size_t wm_off[4] = {0, 16384, 81920, 344064};
  const size_t wp_off[4] = {0, 4096, 20480, 86016};

  int nb = 1;
  if (ws_size >= total_need(8)) nb = 8;
  else if (ws_size >= total_need(4)) nb = 4;
  else if (ws_size >= total_need(2)) nb = 2;

  char* FX = (char*)d_ws + 3 * (size_t)nb * 7864320 + p4_size(nb) + p5_size(nb);
  bf16* Wm_all = (bf16*)FX;
  bf16* Wp_all = (bf16*)(FX + 2785280);

  for (int br = 0; br < 4; br++) {
    const int c = CHs[br];
    castw<<<(4 * c * c / 4 + 255) / 256, 256, 0, stream>>>(
        Wm[br], Wm_all + wm_off[br], 4 * c * c);
    castw<<<(c * c / 4 + 255) / 256, 256, 0, stream>>>(
        Wp[br], Wp_all + wp_off[br], c * c);
  }

  for (int b0 = 0; b0 < B_; b0 += nb) {
    const float* embB[4];
    for (int i = 0; i < 4; i++) embB[i] = emb[i] + (size_t)b0 * CHs[i] * HW_;
    const float* emb_allB = emb_all + (size_t)b0 * KV_ * HW_;
    size_t out_offB[4];
    for (int i = 0; i < 4; i++)
      out_offB[i] = out_off_full[i] + (size_t)b0 * CHs[i] * HW_;
    run_group(embB, emb_allB, Wq, Wmk, Wmv, Wk, Wv, Wm_all, Wp_all,
              out, out_offB, (char*)d_ws, nb, stream);
  }
}

// Round 8
// 838.103 us; speedup vs baseline: 12.4965x; 1.2538x over previous
//
#include <hip/hip_runtime.h>
#include <hip/hip_bf16.h>
#include <math.h>

typedef __hip_bfloat16 bf16;
typedef __attribute__((ext_vector_type(8))) short short8;
typedef __attribute__((ext_vector_type(4))) float f32x4;
typedef long long ll;

#define B_ 8
#define HEADS_ 4
#define KV_ 960
#define HW_ 1024
#define CKV_ 3840   // KV_*HEADS_

// ---------------------------------------------------------------------------
// helpers
// ---------------------------------------------------------------------------
__device__ __forceinline__ float wredsum(float v) {
#pragma unroll
  for (int o = 32; o > 0; o >>= 1) v += __shfl_xor(v, o);
  return v;
}
__device__ __forceinline__ float wredmax(float v) {
#pragma unroll
  for (int o = 32; o > 0; o >>= 1) v = fmaxf(v, __shfl_xor(v, o));
  return v;
}

__device__ __forceinline__ float bfu2f(unsigned short u) {
  union { unsigned int i; float f; } c;
  c.i = ((unsigned int)u) << 16;
  return c.f;
}
__device__ __forceinline__ unsigned short f2bfu(float f) {
  bf16 h = __float2bfloat16(f);
  return *(unsigned short*)&h;
}

__device__ __forceinline__ void gl_lds16(const void* g, void* l) {
  __builtin_amdgcn_global_load_lds(
      (const __attribute__((address_space(1))) unsigned*)g,
      (__attribute__((address_space(3))) unsigned*)l, 16, 0, 0);
}

// ---------------------------------------------------------------------------
// K0a: elementwise f32 -> bf16 cast (weights). n % 4 == 0.
// ---------------------------------------------------------------------------
__global__ void __launch_bounds__(256) castw(const float* __restrict__ in,
                                             bf16* __restrict__ out, int n) {
  int i = (blockIdx.x * 256 + threadIdx.x) * 4;
  if (i < n) {
    float4 v = *(const float4*)(in + i);
    out[i] = __float2bfloat16(v.x);
    out[i + 1] = __float2bfloat16(v.y);
    out[i + 2] = __float2bfloat16(v.z);
    out[i + 3] = __float2bfloat16(v.w);
  }
}

// ---------------------------------------------------------------------------
// K0b: transpose+cast: in [z][R][1024] (f32 or bf16) -> out [z][1024][R] bf16.
// ---------------------------------------------------------------------------
template <typename InT>
__global__ void __launch_bounds__(256) tcast(const InT* __restrict__ in,
                                             bf16* __restrict__ out, int R,
                                             ll inZ, ll outZ) {
  __shared__ float t[32][33];
  const int x = threadIdx.x & 31, y0 = threadIdx.x >> 5;
  const int c0 = blockIdx.x << 5, r0 = blockIdx.y << 5;
  const InT* ip = in + (ll)blockIdx.z * inZ + (ll)r0 * 1024 + c0;
  bf16* op = out + (ll)blockIdx.z * outZ + (ll)c0 * R + r0;
#pragma unroll
  for (int i = 0; i < 4; i++) {
    int r = y0 + i * 8;
    float v;
    if constexpr (__is_same(InT, float)) v = ip[(ll)r * 1024 + x];
    else v = __bfloat162float(ip[(ll)r * 1024 + x]);
    t[r][x] = v;
  }
  __syncthreads();
#pragma unroll
  for (int i = 0; i < 4; i++) {
    int cc = y0 + i * 8;
    op[(ll)cc * R + x] = __float2bfloat16(t[x][cc]);
  }
}

// ---------------------------------------------------------------------------
// gemm_mfma: 128x128 / BK=32 / 2-phase dbuf (proven). For grids that can't
// reach ~256 blocks of gemm8 (which needs 1 block/CU worth of spread).
// ---------------------------------------------------------------------------
template <int OUTMODE, bool STATS>
__global__ void __launch_bounds__(256) gemm_mfma(
    const bf16* __restrict__ A, const bf16* __restrict__ Bt, void* __restrict__ Y,
    int M, int N, int K, int nh,
    ll aZ, ll aH, ll bZ, ll bH, ll yZ, int ldy, float scale,
    float* __restrict__ part) {
  __shared__ bf16 As[2][128 * 32];
  __shared__ bf16 Bs[2][128 * 32];
  __shared__ float rs1[4], rs2[4];
  const int tid = threadIdx.x;
  const int lane = tid & 63;
  const int wave = tid >> 6;
  const int wr = wave >> 1, wc = wave & 1;

  const int gy = gridDim.y, gz = gridDim.z;
  int orig = (blockIdx.z * gy + blockIdx.y) * 8 + blockIdx.x;
  int cpx = (gy * gz);
  int flat = (orig & 7) * cpx + (orig >> 3);
  const int lx = flat & 7;
  int rest = flat >> 3;
  const int ly = rest % gy;
  const int lz = rest / gy;

  const int z = lz;
  const int m0 = ly << 7, n0 = lx << 7;

  f32x4 acc[4][4];
#pragma unroll
  for (int i = 0; i < 4; i++)
#pragma unroll
    for (int j = 0; j < 4; j++) acc[i][j] = (f32x4){0.f, 0.f, 0.f, 0.f};

  const int frow = lane & 15;
  const int kq = lane >> 4;

  const bf16* Ah = A + (ll)z * aZ;
  const bf16* Bh = Bt + (ll)z * bZ;
  int k0n = 0;

  auto stage = [&](int buf) {
#pragma unroll
    for (int t = 0; t < 2; t++) {
      const int e = (wave * 2 + t) * 64 + lane;
      const int row = e >> 2;
      const int ks = (e & 3) ^ ((row >> 1) & 3);
      int gr = m0 + row; gr = gr < M ? gr : M - 1;
      gl_lds16(Ah + (ll)gr * K + k0n + ks * 8,
               (char*)&As[buf][0] + (wave * 2 + t) * 1024);
      int rn = n0 + row; rn = rn < N ? rn : N - 1;
      gl_lds16(Bh + (ll)rn * K + k0n + ks * 8,
               (char*)&Bs[buf][0] + (wave * 2 + t) * 1024);
    }
  };

  const int kpt = K >> 5;
  const int iters = nh * kpt;
  stage(0);
  __syncthreads();

  int buf = 0;
  for (int it = 0; it < iters; ++it) {
    if (it + 1 < iters) {
      k0n += 32;
      if (k0n == K) { k0n = 0; Ah += aH; Bh += bH; }
      stage(buf ^ 1);
    }
    short8 af[4], bfr[4];
#pragma unroll
    for (int fm = 0; fm < 4; fm++) {
      const int row = wr * 64 + fm * 16 + frow;
      af[fm] = *(const short8*)&As[buf][((row << 2) | (kq ^ ((row >> 1) & 3))) << 3];
    }
#pragma unroll
    for (int fn = 0; fn < 4; fn++) {
      const int row = wc * 64 + fn * 16 + frow;
      bfr[fn] = *(const short8*)&Bs[buf][((row << 2) | (kq ^ ((row >> 1) & 3))) << 3];
    }
#pragma unroll
    for (int fm = 0; fm < 4; fm++)
#pragma unroll
      for (int fn = 0; fn < 4; fn++)
        acc[fm][fn] = __builtin_amdgcn_mfma_f32_16x16x32_bf16(
            af[fm], bfr[fn], acc[fm][fn], 0, 0, 0);
    __syncthreads();
    buf ^= 1;
  }

  const int rq = kq << 2;
  float lsum = 0.f, lsq = 0.f;
#pragma unroll
  for (int fm = 0; fm < 4; fm++) {
    const int mrow = m0 + wr * 64 + fm * 16 + rq;
#pragma unroll
    for (int fn = 0; fn < 4; fn++) {
      const int ncol = n0 + wc * 64 + fn * 16 + frow;
      if (ncol >= N) continue;
      if constexpr (OUTMODE == 0) {
        float* Yp = (float*)Y + (ll)z * yZ;
#pragma unroll
        for (int i = 0; i < 4; i++)
          if (mrow + i < M) {
            float v = acc[fm][fn][i] * scale;
            Yp[(ll)(mrow + i) * ldy + ncol] = v;
            if constexpr (STATS) { lsum += v; lsq += v * v; }
          }
      } else if constexpr (OUTMODE == 1) {
        bf16* Yp = (bf16*)Y + (ll)z * yZ;
#pragma unroll
        for (int i = 0; i < 4; i++)
          if (mrow + i < M)
            Yp[(ll)(mrow + i) * ldy + ncol] =
                __float2bfloat16(acc[fm][fn][i] * scale);
      } else {
        if (mrow < M) {
          bf16* Yp = (bf16*)Y + (ll)z * yZ + (ll)ncol * ldy + mrow;
#pragma unroll
          for (int i = 0; i < 4; i++)
            Yp[i] = __float2bfloat16(acc[fm][fn][i] * scale);
        }
      }
    }
  }
  if constexpr (STATS) {
    lsum = wredsum(lsum);
    lsq = wredsum(lsq);
    if (lane == 0) { rs1[wave] = lsum; rs2[wave] = lsq; }
    __syncthreads();
    if (tid == 0) {
      int slot = ly * 8 + lx;
      part[((ll)z * 32 + slot) * 2] = rs1[0] + rs1[1] + rs1[2] + rs1[3];
      part[((ll)z * 32 + slot) * 2 + 1] = rs2[0] + rs2[1] + rs2[2] + rs2[3];
    }
  }
}

// ---------------------------------------------------------------------------
// gemm8: 256x256, BK=64, 512 thr, dbuf, 4-phase counted-vmcnt, setprio.
// ~5.4 TF/CU measured (R7). Needs >=256 blocks to fill the device (1 blk/CU).
// ---------------------------------------------------------------------------
template <int OUTMODE, bool STATS>
__global__ void __launch_bounds__(512, 2) gemm8(
    const bf16* __restrict__ A, const bf16* __restrict__ Bt, void* __restrict__ Y,
    int M, int N, int K, int nh,
    ll aZ, ll aH, ll bZ, ll bH, ll yZ, int ldy, float scale,
    float* __restrict__ part) {
  __shared__ char lds[131072];           // [A0|A1|B0|B1] each 32KB
  __shared__ float rs1[8], rs2[8];
  const int tid = threadIdx.x;
  const int lane = tid & 63;
  const int wave = tid >> 6;
  const int wm = wave >> 2, wn = wave & 3;

  const int nx = gridDim.x, my = gridDim.y;
  const int nwg = nx * my * gridDim.z;
  int orig = (blockIdx.z * my + blockIdx.y) * nx + blockIdx.x;
  int q8 = nwg >> 3, r8 = nwg & 7;
  int xcd = orig & 7, bidx = orig >> 3;
  int flat = (xcd < r8) ? xcd * (q8 + 1) + bidx
                        : r8 * (q8 + 1) + (xcd - r8) * q8 + bidx;
  const int lx = flat % nx;
  int rest = flat / nx;
  const int ly = rest % my;
  const int lz = rest / my;

  const int m0 = ly << 8, n0 = lx << 8;
  const int ktiles = K >> 6;
  const int nt = nh * ktiles;

  f32x4 acc[8][4];
#pragma unroll
  for (int i = 0; i < 8; i++)
#pragma unroll
    for (int j = 0; j < 4; j++) acc[i][j] = (f32x4){0.f, 0.f, 0.f, 0.f};

  const int frow = lane & 15;
  const int kq = lane >> 4;
  const int swz = frow & 7;

  auto stageRound = [&](int matB, int r, int tt, int buf) {
    int h = tt / ktiles;
    int koff = (tt % ktiles) << 6;
    int s = (r << 9) + tid;
    int row = s >> 3;
    int ks = (s & 7) ^ (row & 7);
    const bf16* src;
    char* dst;
    if (!matB) {
      int gr = m0 + row; gr = gr < M ? gr : M - 1;
      src = A + (ll)lz * aZ + (ll)h * aH + (ll)gr * K + koff + (ks << 3);
      dst = lds + buf * 32768 + (((r << 3) + wave) << 10);
    } else {
      int gr = n0 + row; gr = gr < N ? gr : N - 1;
      src = Bt + (ll)lz * bZ + (ll)h * bH + (ll)gr * K + koff + (ks << 3);
      dst = lds + 65536 + buf * 32768 + (((r << 3) + wave) << 10);
    }
    gl_lds16(src, dst);
  };

  auto readA = [&](int fm, int kh, int cur) -> short8 {
    int row = wm * 128 + fm * 16 + frow;
    int slot = (kq + (kh << 2)) ^ swz;
    return *(const short8*)(lds + cur * 32768 + row * 128 + slot * 16);
  };
  auto readB = [&](int fn, int kh, int cur) -> short8 {
    int row = wn * 64 + fn * 16 + frow;
    int slot = (kq + (kh << 2)) ^ swz;
    return *(const short8*)(lds + 65536 + cur * 32768 + row * 128 + slot * 16);
  };

  stageRound(1, 0, 0, 0); stageRound(1, 1, 0, 0);
  stageRound(1, 2, 0, 0); stageRound(1, 3, 0, 0);
  stageRound(0, 0, 0, 0); stageRound(0, 2, 0, 0);
  stageRound(0, 1, 0, 0); stageRound(0, 3, 0, 0);

  int cur = 0;
  for (int tt = 0; tt < nt; ++tt) {
    const bool hasNext = (tt + 1 < nt);
    short8 bfr[4][2];
#pragma unroll
    for (int p = 0; p < 4; p++) {
      if (p == 0) {
        if (hasNext) asm volatile("s_waitcnt vmcnt(2)" ::: "memory");
        else         asm volatile("s_waitcnt vmcnt(0)" ::: "memory");
        __builtin_amdgcn_s_barrier();
        __builtin_amdgcn_sched_barrier(0);
#pragma unroll
        for (int fn = 0; fn < 4; fn++)
#pragma unroll
          for (int kh = 0; kh < 2; kh++) bfr[fn][kh] = readB(fn, kh, cur);
      }
      if (p == 2) {
        if (hasNext) asm volatile("s_waitcnt vmcnt(4)" ::: "memory");
        __builtin_amdgcn_s_barrier();
        __builtin_amdgcn_sched_barrier(0);
      }
      short8 a0k0 = readA(2 * p, 0, cur), a0k1 = readA(2 * p, 1, cur);
      short8 a1k0 = readA(2 * p + 1, 0, cur), a1k1 = readA(2 * p + 1, 1, cur);
      if (hasNext) {
        if (p == 0) { stageRound(1, 0, tt + 1, cur ^ 1); stageRound(1, 1, tt + 1, cur ^ 1); }
        else if (p == 1) { stageRound(1, 2, tt + 1, cur ^ 1); stageRound(1, 3, tt + 1, cur ^ 1); }
        else if (p == 2) { stageRound(0, 0, tt + 1, cur ^ 1); stageRound(0, 2, tt + 1, cur ^ 1); }
        else { stageRound(0, 1, tt + 1, cur ^ 1); stageRound(0, 3, tt + 1, cur ^ 1); }
      }
      __builtin_amdgcn_s_setprio(1);
#pragma unroll
      for (int fn = 0; fn < 4; fn++) {
        acc[2 * p][fn] = __builtin_amdgcn_mfma_f32_16x16x32_bf16(
            a0k0, bfr[fn][0], acc[2 * p][fn], 0, 0, 0);
        acc[2 * p][fn] = __builtin_amdgcn_mfma_f32_16x16x32_bf16(
            a0k1, bfr[fn][1], acc[2 * p][fn], 0, 0, 0);
        acc[2 * p + 1][fn] = __builtin_amdgcn_mfma_f32_16x16x32_bf16(
            a1k0, bfr[fn][0], acc[2 * p + 1][fn], 0, 0, 0);
        acc[2 * p + 1][fn] = __builtin_amdgcn_mfma_f32_16x16x32_bf16(
            a1k1, bfr[fn][1], acc[2 * p + 1][fn], 0, 0, 0);
      }
      __builtin_amdgcn_s_setprio(0);
    }
    cur ^= 1;
  }

  const int rq = kq << 2;
  float lsum = 0.f, lsq = 0.f;
#pragma unroll
  for (int fm = 0; fm < 8; fm++) {
    const int mrow = m0 + wm * 128 + fm * 16 + rq;
#pragma unroll
    for (int fn = 0; fn < 4; fn++) {
      const int ncol = n0 + wn * 64 + fn * 16 + frow;
      if (ncol >= N) continue;
      if constexpr (OUTMODE == 0) {
        float* Yp = (float*)Y + (ll)lz * yZ;
#pragma unroll
        for (int i = 0; i < 4; i++)
          if (mrow + i < M) {
            float v = acc[fm][fn][i] * scale;
            Yp[(ll)(mrow + i) * ldy + ncol] = v;
            if constexpr (STATS) { lsum += v; lsq += v * v; }
          }
      } else if constexpr (OUTMODE == 1) {
        bf16* Yp = (bf16*)Y + (ll)lz * yZ;
#pragma unroll
        for (int i = 0; i < 4; i++)
          if (mrow + i < M)
            Yp[(ll)(mrow + i) * ldy + ncol] =
                __float2bfloat16(acc[fm][fn][i] * scale);
      } else {
        if (mrow < M) {
          bf16* Yp = (bf16*)Y + (ll)lz * yZ + (ll)ncol * ldy + mrow;
#pragma unroll
          for (int i = 0; i < 4; i++)
            Yp[i] = __float2bfloat16(acc[fm][fn][i] * scale);
        }
      }
    }
  }
  if constexpr (STATS) {
    lsum = wredsum(lsum);
    lsq = wredsum(lsq);
    if (lane == 0) { rs1[wave] = lsum; rs2[wave] = lsq; }
    __syncthreads();
    if (tid == 0) {
      float s = 0.f, s2 = 0.f;
#pragma unroll
      for (int w = 0; w < 8; w++) { s += rs1[w]; s2 += rs2[w]; }
      int slot = ly * nx + lx;
      part[((ll)lz * 32 + slot) * 2] = s;
      part[((ll)lz * 32 + slot) * 2 + 1] = s2;
    }
  }
}

// ---------------------------------------------------------------------------
// pv_reduce: OtT[b][off] = 0.25 * sum_{s<4} part[(b*4+s)][off]  (bf16 in/out)
// plane = 1<<planeShift elems. grid: total/1024 blocks of 256 (4 elems/thr).
// ---------------------------------------------------------------------------
__global__ void __launch_bounds__(256) pv_reduce(const bf16* __restrict__ part,
                                                 bf16* __restrict__ out,
                                                 int planeShift) {
  const ll idx = ((ll)blockIdx.x * 256 + threadIdx.x) * 4;
  const int b = (int)(idx >> planeShift);
  const ll off = idx - ((ll)b << planeShift);
  const bf16* base = part + (((ll)b * 4) << planeShift) + off;
  float a0 = 0.f, a1 = 0.f, a2 = 0.f, a3 = 0.f;
#pragma unroll
  for (int s = 0; s < 4; s++) {
    ushort4 u = *(const ushort4*)(base + ((ll)s << planeShift));
    a0 += bfu2f(u.x); a1 += bfu2f(u.y); a2 += bfu2f(u.z); a3 += bfu2f(u.w);
  }
  ushort4 o;
  o.x = f2bfu(a0 * 0.25f);
  o.y = f2bfu(a1 * 0.25f);
  o.z = f2bfu(a2 * 0.25f);
  o.w = f2bfu(a3 * 0.25f);
  *(ushort4*)(out + idx) = o;
}

// ---------------------------------------------------------------------------
// K2: depthwise 3x3 (pad 1), optional fused l2norm. 256 thr, 4 px/thread.
// ---------------------------------------------------------------------------
template <bool NORM>
__global__ void __launch_bounds__(256) dw3x3v(const bf16* __restrict__ in,
                                              const float* __restrict__ w9,
                                              bf16* __restrict__ out, int C) {
  __shared__ float tile[34][36];
  __shared__ float red[4];
  const int bc = blockIdx.x;
  const int ch = bc % C;
  const int tid = threadIdx.x;
  const int y = tid >> 3;
  const int x0 = (tid & 7) << 2;
  const bf16* ip = in + ((size_t)bc << 10);

  ushort4 u = *(const ushort4*)(ip + (y << 5) + x0);
  tile[y + 1][x0 + 1] = bfu2f(u.x);
  tile[y + 1][x0 + 2] = bfu2f(u.y);
  tile[y + 1][x0 + 3] = bfu2f(u.z);
  tile[y + 1][x0 + 4] = bfu2f(u.w);
  if (tid < 34) { tile[0][tid] = 0.f; tile[33][tid] = 0.f; }
  if (tid < 32) { tile[tid + 1][0] = 0.f; tile[tid + 1][33] = 0.f; }
  __syncthreads();

  const float* wc = w9 + ch * 9;
  float s[4] = {0.f, 0.f, 0.f, 0.f};
#pragma unroll
  for (int dy = 0; dy < 3; dy++) {
    const float* tr = &tile[y + dy][x0];
    float c0 = tr[0], c1 = tr[1], c2 = tr[2], c3 = tr[3], c4 = tr[4], c5 = tr[5];
    float wa = wc[dy * 3], wb = wc[dy * 3 + 1], wd = wc[dy * 3 + 2];
    s[0] += c0 * wa + c1 * wb + c2 * wd;
    s[1] += c1 * wa + c2 * wb + c3 * wd;
    s[2] += c2 * wa + c3 * wb + c4 * wd;
    s[3] += c3 * wa + c4 * wb + c5 * wd;
  }

  float inv = 1.f;
  if (NORM) {
    float ss = s[0] * s[0] + s[1] * s[1] + s[2] * s[2] + s[3] * s[3];
    ss = wredsum(ss);
    const int lane = tid & 63, wid = tid >> 6;
    if (lane == 0) red[wid] = ss;
    __syncthreads();
    inv = 1.0f / fmaxf(sqrtf(red[0] + red[1] + red[2] + red[3]), 1e-12f);
  }
  ushort4 o4;
  o4.x = f2bfu(s[0] * inv);
  o4.y = f2bfu(s[1] * inv);
  o4.z = f2bfu(s[2] * inv);
  o4.w = f2bfu(s[3] * inv);
  *(ushort4*)(out + ((size_t)bc << 10) + (y << 5) + x0) = o4;
}

// ---------------------------------------------------------------------------
// K3: grouped 3x3 (2 in-ch per group) + fused l2norm. 256 thr, 4 px/thread.
// ---------------------------------------------------------------------------
__global__ void __launch_bounds__(256) gq3x3v(const bf16* __restrict__ in,
                                              const float* __restrict__ wq,
                                              bf16* __restrict__ out, int C4) {
  __shared__ float t0[34][36];
  __shared__ float t1[34][36];
  __shared__ float red[4];
  const int bo = blockIdx.x;
  const int o = bo % C4;
  const int b = bo / C4;
  const int ic0 = (o >> 1) << 1;
  const int tid = threadIdx.x;
  const int y = tid >> 3;
  const int x0 = (tid & 7) << 2;
  const bf16* p0 = in + (((size_t)b * C4 + ic0) << 10);

  ushort4 u0 = *(const ushort4*)(p0 + (y << 5) + x0);
  ushort4 u1 = *(const ushort4*)(p0 + 1024 + (y << 5) + x0);
  t0[y + 1][x0 + 1] = bfu2f(u0.x);
  t0[y + 1][x0 + 2] = bfu2f(u0.y);
  t0[y + 1][x0 + 3] = bfu2f(u0.z);
  t0[y + 1][x0 + 4] = bfu2f(u0.w);
  t1[y + 1][x0 + 1] = bfu2f(u1.x);
  t1[y + 1][x0 + 2] = bfu2f(u1.y);
  t1[y + 1][x0 + 3] = bfu2f(u1.z);
  t1[y + 1][x0 + 4] = bfu2f(u1.w);
  if (tid < 34) {
    t0[0][tid] = 0.f; t0[33][tid] = 0.f;
    t1[0][tid] = 0.f; t1[33][tid] = 0.f;
  }
  if (tid < 32) {
    t0[tid + 1][0] = 0.f; t0[tid + 1][33] = 0.f;
    t1[tid + 1][0] = 0.f; t1[tid + 1][33] = 0.f;
  }
  __syncthreads();

  const float* w = wq + o * 18;
  float s[4] = {0.f, 0.f, 0.f, 0.f};
#pragma unroll
  for (int dy = 0; dy < 3; dy++) {
    {
      const float* tr = &t0[y + dy][x0];
      float c0 = tr[0], c1 = tr[1], c2 = tr[2], c3 = tr[3], c4 = tr[4], c5 = tr[5];
      float wa = w[dy * 3], wb = w[dy * 3 + 1], wd = w[dy * 3 + 2];
      s[0] += c0 * wa + c1 * wb + c2 * wd;
      s[1] += c1 * wa + c2 * wb + c3 * wd;
      s[2] += c2 * wa + c3 * wb + c4 * wd;
      s[3] += c3 * wa + c4 * wb + c5 * wd;
    }
    {
      const float* tr = &t1[y + dy][x0];
      float c0 = tr[0], c1 = tr[1], c2 = tr[2], c3 = tr[3], c4 = tr[4], c5 = tr[5];
      float wa = w[9 + dy * 3], wb = w[9 + dy * 3 + 1], wd = w[9 + dy * 3 + 2];
      s[0] += c0 * wa + c1 * wb + c2 * wd;
      s[1] += c1 * wa + c2 * wb + c3 * wd;
      s[2] += c2 * wa + c3 * wb + c4 * wd;
      s[3] += c3 * wa + c4 * wb + c5 * wd;
    }
  }

  float ss = s[0] * s[0] + s[1] * s[1] + s[2] * s[2] + s[3] * s[3];
  ss = wredsum(ss);
  const int lane = tid & 63, wid = tid >> 6;
  if (lane == 0) red[wid] = ss;
  __syncthreads();
  float inv = 1.0f / fmaxf(sqrtf(red[0] + red[1] + red[2] + red[3]), 1e-12f);

  ushort4 o4;
  o4.x = f2bfu(s[0] * inv);
  o4.y = f2bfu(s[1] * inv);
  o4.z = f2bfu(s[2] * inv);
  o4.w = f2bfu(s[3] * inv);
  *(ushort4*)(out + ((size_t)bo << 10) + (y << 5) + x0) = o4;
}

// ---------------------------------------------------------------------------
// K6: row softmax over 960 with inline InstanceNorm stats from partials.
// ---------------------------------------------------------------------------
__global__ void __launch_bounds__(256) softmax_rows(const float* __restrict__ attn,
                                                    const float* __restrict__ part,
                                                    int nslots,
                                                    bf16* __restrict__ probs, int c) {
  __shared__ float rm[4], rs[4];
  const int row = blockIdx.x;
  const int bh = row / c;
  const float* p = attn + (size_t)row * 960;
  bf16* op = probs + (size_t)row * 960;
  const int tid = threadIdx.x;

  float s = 0.f, s2 = 0.f;
  for (int i = 0; i < nslots; i++) {
    s += part[((ll)bh * 32 + i) * 2];
    s2 += part[((ll)bh * 32 + i) * 2 + 1];
  }
  const float n = (float)(c * 960);
  const float mu = s / n;
  const float var = s2 / n - mu * mu;
  const float rstd = rsqrtf(var + 1e-5f);

  float v[4];
  float mx = -1e30f;
#pragma unroll
  for (int u = 0; u < 4; u++) {
    int j = tid + (u << 8);
    if (j < 960) {
      v[u] = (p[j] - mu) * rstd;
      mx = fmaxf(mx, v[u]);
    } else {
      v[u] = -1e30f;
    }
  }
  mx = wredmax(mx);
  const int lane = tid & 63, wid = tid >> 6;
  if (lane == 0) rm[wid] = mx;
  __syncthreads();
  mx = fmaxf(fmaxf(rm[0], rm[1]), fmaxf(rm[2], rm[3]));

  float sum = 0.f;
#pragma unroll
  for (int u = 0; u < 4; u++) {
    int j = tid + (u << 8);
    if (j < 960) {
      v[u] = __expf(v[u] - mx);
      sum += v[u];
    }
  }
  sum = wredsum(sum);
  if (lane == 0) rs[wid] = sum;
  __syncthreads();
  sum = rs[0] + rs[1] + rs[2] + rs[3];
  const float inv = 1.0f / sum;
#pragma unroll
  for (int u = 0; u < 4; u++) {
    int j = tid + (u << 8);
    if (j < 960) op[j] = __float2bfloat16(v[u] * inv);
  }
}

// ---------------------------------------------------------------------------
// Workspace plan — identical to R6/R7 (proven to fit).
// PV bf16 partials [nb*4][1024][c] (<=33.6MB) reuse P3 after softmax.
// ---------------------------------------------------------------------------
static size_t p4_size(int nb) {
  const int chunkB = (nb + 1) / 2;
  size_t a = (size_t)nb * 4194304;
  size_t b = (size_t)nb * 1966080 + 7372800;
  size_t c = (size_t)chunkB * 7864320;
  size_t m = a > b ? a : b;
  return m > c ? m : c;
}
static size_t p5_size(int nb) {
  size_t a = (size_t)nb * 1048576;
  return a > 7372800 ? a : 7372800;
}
static size_t total_need(int nb) {
  return 3 * (size_t)nb * 7864320 + p4_size(nb) + p5_size(nb) + 3490816;
}

static void run_group(const float* const emb[4], const float* emb_all,
                      const float* const Wq[4],
                      const float* Wmk, const float* Wmv,
                      const float* Wk, const float* Wv,
                      bf16* Wm_all, bf16* Wp_all,
                      float* out, const size_t* out_off,
                      char* ws, int nb, hipStream_t stream) {
  const size_t szBig = (size_t)nb * 7864320;
  char* P1 = ws;
  char* P2 = P1 + szBig;
  char* P3 = P2 + szBig;
  char* P4 = P3 + szBig;
  char* P5 = P4 + p4_size(nb);
  char* FX = P5 + p5_size(nb);

  bf16* kbuf = (bf16*)P1;
  bf16* vt   = (bf16*)P2;
  bf16* kvexp = (bf16*)P3;
  float* attnb = (float*)P3;
  bf16* pvpart = (bf16*)P3;   // PV per-head partials (attnb dead post-softmax)
  bf16* embT_all = (bf16*)P4;
  bf16* Wmv_bf = (bf16*)(P4 + (size_t)nb * 1966080);
  bf16* vhalf = (bf16*)P4;
  bf16* qbuf = (bf16*)P4;
  bf16* probsb = (bf16*)P4;
  bf16* Wmk_bf = (bf16*)P5;
  bf16* OtT = (bf16*)P5;
  float* part = (float*)(FX + 3482112);   // 8192 B

  const float qk_scale = 1.0f / sqrtf((float)KV_);
  const int CHs[4] = {64, 128, 256, 512};
  const size_t wm_off[4] = {0, 16384, 81920, 344064};
  const size_t wp_off[4] = {0, 4096, 20480, 86016};
  const int chunkB = (nb + 1) / 2;

  // -- prologue: shared K/V --------------------------------------------------
  castw<<<3600, 256, 0, stream>>>(Wmk, Wmk_bf, 3686400);
  castw<<<3600, 256, 0, stream>>>(Wmv, Wmv_bf, 3686400);
  tcast<float><<<dim3(32, 30, nb), 256, 0, stream>>>(emb_all, embT_all, 960,
                                                     983040LL, 983040LL);
  gemm8<1, false><<<dim3(4, 15, nb), 512, 0, stream>>>(
      Wmk_bf, embT_all, kvexp, 3840, 1024, 960, 1, 0, 0, 983040LL, 0,
      3932160LL, 1024, 1.f, nullptr);
  dw3x3v<true><<<nb * CKV_, 256, 0, stream>>>(kvexp, Wk, kbuf, CKV_);
  gemm8<1, false><<<dim3(4, 15, nb), 512, 0, stream>>>(
      Wmv_bf, embT_all, kvexp, 3840, 1024, 960, 1, 0, 0, 983040LL, 0,
      3932160LL, 1024, 1.f, nullptr);
  for (int cb = 0; cb < nb; cb += chunkB) {
    int cn = (nb - cb) < chunkB ? (nb - cb) : chunkB;
    dw3x3v<false><<<cn * CKV_, 256, 0, stream>>>(kvexp + (size_t)cb * 3932160,
                                                 Wv, vhalf, CKV_);
    tcast<bf16><<<dim3(32, 30, cn * 4), 256, 0, stream>>>(
        vhalf, vt + (size_t)cb * 3932160, 960, 983040LL, 983040LL);
  }

  // -- branches --------------------------------------------------------------
  for (int br = 0; br < 4; br++) {
    const int c = CHs[br];
    const int C4 = c * 4;
    const int mtiles = (c + 127) / 128;
    bf16* Wm_bf = Wm_all + wm_off[br];
    bf16* Wp_bf = Wp_all + wp_off[br];
    int planeShift = 10;
    for (int t = c; t > 1; t >>= 1) planeShift++;   // log2(1024*c)

    // embT_i in P4 (qbuf region)
    tcast<float><<<dim3(32, c / 32, nb), 256, 0, stream>>>(
        emb[br], qbuf, c, (ll)c * 1024, (ll)c * 1024);
    // q-expand -> P3
    if (c == 512) {
      gemm8<1, false><<<dim3(4, C4 / 256, nb), 512, 0, stream>>>(
          Wm_bf, qbuf, kvexp, C4, 1024, c, 1, 0, 0, (ll)c * 1024, 0,
          (ll)C4 * 1024, 1024, 1.f, nullptr);
    } else {
      gemm_mfma<1, false><<<dim3(8, C4 / 128, nb), 256, 0, stream>>>(
          Wm_bf, qbuf, kvexp, C4, 1024, c, 1, 0, 0, (ll)c * 1024, 0,
          (ll)C4 * 1024, 1024, 1.f, nullptr);
    }
    // grouped 3x3 + l2norm: P3 -> qbuf (P4)
    gq3x3v<<<nb * C4, 256, 0, stream>>>(kvexp, Wq[br], qbuf, C4);
    // attn = scale * q k^T -> attnb (P3), fused stats partials
    int nslots;
    if (c == 512) {
      gemm8<0, true><<<dim3(4, c / 256, nb * 4), 512, 0, stream>>>(
          qbuf, kbuf, attnb, c, 960, 1024, 1, (ll)c * 1024, 0, 983040LL, 0,
          (ll)c * 960, 960, qk_scale, part);
      nslots = (c / 256) * 4;
    } else {
      gemm_mfma<0, true><<<dim3(8, mtiles, nb * 4), 256, 0, stream>>>(
          qbuf, kbuf, attnb, c, 960, 1024, 1, (ll)c * 1024, 0, 983040LL, 0,
          (ll)c * 960, 960, qk_scale, part);
      nslots = mtiles * 8;
    }
    softmax_rows<<<nb * 4 * c, 256, 0, stream>>>(attnb, part, nslots, probsb, c);
    // PV split-head: z=(b,h), nh=1, bf16 transposed partials -> P3
    if (c == 512) {
      gemm8<2, false><<<dim3(4, c / 256, nb * 4), 512, 0, stream>>>(
          probsb, vt, pvpart, c, 1024, 960, 1, (ll)c * 960, 0, 983040LL, 0,
          (ll)1024 * c, c, 1.f, nullptr);
    } else {
      gemm_mfma<2, false><<<dim3(8, mtiles, nb * 4), 256, 0, stream>>>(
          probsb, vt, pvpart, c, 1024, 960, 1, (ll)c * 960, 0, 983040LL, 0,
          (ll)1024 * c, c, 1.f, nullptr);
    }
    // head-sum + 0.25 -> OtT (P5)
    pv_reduce<<<nb * c, 256, 0, stream>>>(pvpart, OtT, planeShift);
    // final projection -> f32 d_out
    gemm_mfma<0, false><<<dim3(8, mtiles, nb), 256, 0, stream>>>(
        Wp_bf, OtT, out + out_off[br], c, 1024, c, 1, 0, 0,
        (ll)1024 * c, 0, (ll)c * 1024, 1024, 1.f, nullptr);
  }
}

extern "C" void kernel_launch(void* const* d_in, const int* in_sizes, int n_in,
                              void* d_out, int out_size, void* d_ws, size_t ws_size,
                              hipStream_t stream) {
  const float* emb[4] = {(const float*)d_in[0], (const float*)d_in[1],
                         (const float*)d_in[2], (const float*)d_in[3]};
  const float* emb_all = (const float*)d_in[4];
  const float* Wm[4] = {(const float*)d_in[5], (const float*)d_in[8],
                        (const float*)d_in[11], (const float*)d_in[14]};
  const float* Wq[4] = {(const float*)d_in[6], (const float*)d_in[9],
                        (const float*)d_in[12], (const float*)d_in[15]};
  const float* Wp[4] = {(const float*)d_in[7], (const float*)d_in[10],
                        (const float*)d_in[13], (const float*)d_in[16]};
  const float* Wmk = (const float*)d_in[17];
  const float* Wmv = (const float*)d_in[18];
  const float* Wk = (const float*)d_in[19];
  const float* Wv = (const float*)d_in[20];
  float* out = (float*)d_out;

  const int CHs[4] = {64, 128, 256, 512};
  const size_t out_off_full[4] = {0, 524288, 1572864, 3670016};
  const size_t wm_off[4] = {0, 16384, 81920, 344064};
  const size_t wp_off[4] = {0, 4096, 20480, 86016};

  int nb = 1;
  if (ws_size >= total_need(8)) nb = 8;
  else if (ws_size >= total_need(4)) nb = 4;
  else if (ws_size >= total_need(2)) nb = 2;

  char* FX = (char*)d_ws + 3 * (size_t)nb * 7864320 + p4_size(nb) + p5_size(nb);
  bf16* Wm_all = (bf16*)FX;
  bf16* Wp_all = (bf16*)(FX + 2785280);

  for (int br = 0; br < 4; br++) {
    const int c = CHs[br];
    castw<<<(4 * c * c / 4 + 255) / 256, 256, 0, stream>>>(
        Wm[br], Wm_all + wm_off[br], 4 * c * c);
    castw<<<(c * c / 4 + 255) / 256, 256, 0, stream>>>(
        Wp[br], Wp_all + wp_off[br], c * c);
  }

  for (int b0 = 0; b0 < B_; b0 += nb) {
    const float* embB[4];
    for (int i = 0; i < 4; i++) embB[i] = emb[i] + (size_t)b0 * CHs[i] * HW_;
    const float* emb_allB = emb_all + (size_t)b0 * KV_ * HW_;
    size_t out_offB[4];
    for (int i = 0; i < 4; i++)
      out_offB[i] = out_off_full[i] + (size_t)b0 * CHs[i] * HW_;
    run_group(embB, emb_allB, Wq, Wmk, Wmv, Wk, Wv, Wm_all, Wp_all,
              out, out_offB, (char*)d_ws, nb, stream);
  }
}

// Round 10
// 809.983 us; speedup vs baseline: 12.9304x; 1.0347x over previous
//
#include <hip/hip_runtime.h>
#include <hip/hip_bf16.h>
#include <math.h>

typedef __hip_bfloat16 bf16;
typedef __attribute__((ext_vector_type(8))) short short8;
typedef __attribute__((ext_vector_type(8))) unsigned short u16x8;
typedef __attribute__((ext_vector_type(4))) float f32x4;
typedef long long ll;

#define B_ 8
#define HEADS_ 4
#define KV_ 960
#define HW_ 1024
#define CKV_ 3840   // KV_*HEADS_

// ---------------------------------------------------------------------------
// helpers
// ---------------------------------------------------------------------------
__device__ __forceinline__ float wredsum(float v) {
#pragma unroll
  for (int o = 32; o > 0; o >>= 1) v += __shfl_xor(v, o);
  return v;
}
__device__ __forceinline__ float wredmax(float v) {
#pragma unroll
  for (int o = 32; o > 0; o >>= 1) v = fmaxf(v, __shfl_xor(v, o));
  return v;
}

__device__ __forceinline__ float bfu2f(unsigned short u) {
  union { unsigned int i; float f; } c;
  c.i = ((unsigned int)u) << 16;
  return c.f;
}
__device__ __forceinline__ unsigned short f2bfu(float f) {
  bf16 h = __float2bfloat16(f);
  return *(unsigned short*)&h;
}

__device__ __forceinline__ void gl_lds16(const void* g, void* l) {
  __builtin_amdgcn_global_load_lds(
      (const __attribute__((address_space(1))) unsigned*)g,
      (__attribute__((address_space(3))) unsigned*)l, 16, 0, 0);
}

// ---------------------------------------------------------------------------
// K0a: elementwise f32 -> bf16 cast (weights). n % 4 == 0.
// ---------------------------------------------------------------------------
__global__ void __launch_bounds__(256) castw(const float* __restrict__ in,
                                             bf16* __restrict__ out, int n) {
  int i = (blockIdx.x * 256 + threadIdx.x) * 4;
  if (i < n) {
    float4 v = *(const float4*)(in + i);
    out[i] = __float2bfloat16(v.x);
    out[i + 1] = __float2bfloat16(v.y);
    out[i + 2] = __float2bfloat16(v.z);
    out[i + 3] = __float2bfloat16(v.w);
  }
}

// ---------------------------------------------------------------------------
// K0b: transpose+cast: in [z][R][1024] f32 -> out [z][1024][R] bf16.
// ---------------------------------------------------------------------------
template <typename InT>
__global__ void __launch_bounds__(256) tcast(const InT* __restrict__ in,
                                             bf16* __restrict__ out, int R,
                                             ll inZ, ll outZ) {
  __shared__ float t[32][33];
  const int x = threadIdx.x & 31, y0 = threadIdx.x >> 5;
  const int c0 = blockIdx.x << 5, r0 = blockIdx.y << 5;
  const InT* ip = in + (ll)blockIdx.z * inZ + (ll)r0 * 1024 + c0;
  bf16* op = out + (ll)blockIdx.z * outZ + (ll)c0 * R + r0;
#pragma unroll
  for (int i = 0; i < 4; i++) {
    int r = y0 + i * 8;
    float v;
    if constexpr (__is_same(InT, float)) v = ip[(ll)r * 1024 + x];
    else v = __bfloat162float(ip[(ll)r * 1024 + x]);
    t[r][x] = v;
  }
  __syncthreads();
#pragma unroll
  for (int i = 0; i < 4; i++) {
    int cc = y0 + i * 8;
    op[(ll)cc * R + x] = __float2bfloat16(t[x][cc]);
  }
}

// ---------------------------------------------------------------------------
// gemm_mfma: 128x128 / BK=32 / 2-phase dbuf (proven).
// ---------------------------------------------------------------------------
template <int OUTMODE, bool STATS>
__global__ void __launch_bounds__(256) gemm_mfma(
    const bf16* __restrict__ A, const bf16* __restrict__ Bt, void* __restrict__ Y,
    int M, int N, int K, int nh,
    ll aZ, ll aH, ll bZ, ll bH, ll yZ, int ldy, float scale,
    float* __restrict__ part) {
  __shared__ bf16 As[2][128 * 32];
  __shared__ bf16 Bs[2][128 * 32];
  __shared__ float rs1[4], rs2[4];
  const int tid = threadIdx.x;
  const int lane = tid & 63;
  const int wave = tid >> 6;
  const int wr = wave >> 1, wc = wave & 1;

  const int gy = gridDim.y, gz = gridDim.z;
  int orig = (blockIdx.z * gy + blockIdx.y) * 8 + blockIdx.x;
  int cpx = (gy * gz);
  int flat = (orig & 7) * cpx + (orig >> 3);
  const int lx = flat & 7;
  int rest = flat >> 3;
  const int ly = rest % gy;
  const int lz = rest / gy;

  const int z = lz;
  const int m0 = ly << 7, n0 = lx << 7;

  f32x4 acc[4][4];
#pragma unroll
  for (int i = 0; i < 4; i++)
#pragma unroll
    for (int j = 0; j < 4; j++) acc[i][j] = (f32x4){0.f, 0.f, 0.f, 0.f};

  const int frow = lane & 15;
  const int kq = lane >> 4;

  const bf16* Ah = A + (ll)z * aZ;
  const bf16* Bh = Bt + (ll)z * bZ;
  int k0n = 0;

  auto stage = [&](int buf) {
#pragma unroll
    for (int t = 0; t < 2; t++) {
      const int e = (wave * 2 + t) * 64 + lane;
      const int row = e >> 2;
      const int ks = (e & 3) ^ ((row >> 1) & 3);
      int gr = m0 + row; gr = gr < M ? gr : M - 1;
      gl_lds16(Ah + (ll)gr * K + k0n + ks * 8,
               (char*)&As[buf][0] + (wave * 2 + t) * 1024);
      int rn = n0 + row; rn = rn < N ? rn : N - 1;
      gl_lds16(Bh + (ll)rn * K + k0n + ks * 8,
               (char*)&Bs[buf][0] + (wave * 2 + t) * 1024);
    }
  };

  const int kpt = K >> 5;
  const int iters = nh * kpt;
  stage(0);
  __syncthreads();

  int buf = 0;
  for (int it = 0; it < iters; ++it) {
    if (it + 1 < iters) {
      k0n += 32;
      if (k0n == K) { k0n = 0; Ah += aH; Bh += bH; }
      stage(buf ^ 1);
    }
    short8 af[4], bfr[4];
#pragma unroll
    for (int fm = 0; fm < 4; fm++) {
      const int row = wr * 64 + fm * 16 + frow;
      af[fm] = *(const short8*)&As[buf][((row << 2) | (kq ^ ((row >> 1) & 3))) << 3];
    }
#pragma unroll
    for (int fn = 0; fn < 4; fn++) {
      const int row = wc * 64 + fn * 16 + frow;
      bfr[fn] = *(const short8*)&Bs[buf][((row << 2) | (kq ^ ((row >> 1) & 3))) << 3];
    }
#pragma unroll
    for (int fm = 0; fm < 4; fm++)
#pragma unroll
      for (int fn = 0; fn < 4; fn++)
        acc[fm][fn] = __builtin_amdgcn_mfma_f32_16x16x32_bf16(
            af[fm], bfr[fn], acc[fm][fn], 0, 0, 0);
    __syncthreads();
    buf ^= 1;
  }

  const int rq = kq << 2;
  float lsum = 0.f, lsq = 0.f;
#pragma unroll
  for (int fm = 0; fm < 4; fm++) {
    const int mrow = m0 + wr * 64 + fm * 16 + rq;
#pragma unroll
    for (int fn = 0; fn < 4; fn++) {
      const int ncol = n0 + wc * 64 + fn * 16 + frow;
      if (ncol >= N) continue;
      if constexpr (OUTMODE == 0) {
        float* Yp = (float*)Y + (ll)z * yZ;
#pragma unroll
        for (int i = 0; i < 4; i++)
          if (mrow + i < M) {
            float v = acc[fm][fn][i] * scale;
            Yp[(ll)(mrow + i) * ldy + ncol] = v;
            if constexpr (STATS) { lsum += v; lsq += v * v; }
          }
      } else if constexpr (OUTMODE == 1) {
        bf16* Yp = (bf16*)Y + (ll)z * yZ;
#pragma unroll
        for (int i = 0; i < 4; i++)
          if (mrow + i < M)
            Yp[(ll)(mrow + i) * ldy + ncol] =
                __float2bfloat16(acc[fm][fn][i] * scale);
      } else {
        if (mrow < M) {
          bf16* Yp = (bf16*)Y + (ll)z * yZ + (ll)ncol * ldy + mrow;
#pragma unroll
          for (int i = 0; i < 4; i++)
            Yp[i] = __float2bfloat16(acc[fm][fn][i] * scale);
        }
      }
    }
  }
  if constexpr (STATS) {
    lsum = wredsum(lsum);
    lsq = wredsum(lsq);
    if (lane == 0) { rs1[wave] = lsum; rs2[wave] = lsq; }
    __syncthreads();
    if (tid == 0) {
      int slot = ly * 8 + lx;
      part[((ll)z * 32 + slot) * 2] = rs1[0] + rs1[1] + rs1[2] + rs1[3];
      part[((ll)z * 32 + slot) * 2 + 1] = rs2[0] + rs2[1] + rs2[2] + rs2[3];
    }
  }
}

// ---------------------------------------------------------------------------
// gemm8: 256x256, BK=64, 512 thr, dbuf, 4-phase counted-vmcnt, setprio.
// ---------------------------------------------------------------------------
template <int OUTMODE, bool STATS>
__global__ void __launch_bounds__(512, 2) gemm8(
    const bf16* __restrict__ A, const bf16* __restrict__ Bt, void* __restrict__ Y,
    int M, int N, int K, int nh,
    ll aZ, ll aH, ll bZ, ll bH, ll yZ, int ldy, float scale,
    float* __restrict__ part) {
  __shared__ char lds[131072];           // [A0|A1|B0|B1] each 32KB
  __shared__ float rs1[8], rs2[8];
  const int tid = threadIdx.x;
  const int lane = tid & 63;
  const int wave = tid >> 6;
  const int wm = wave >> 2, wn = wave & 3;

  const int nx = gridDim.x, my = gridDim.y;
  const int nwg = nx * my * gridDim.z;
  int orig = (blockIdx.z * my + blockIdx.y) * nx + blockIdx.x;
  int q8 = nwg >> 3, r8 = nwg & 7;
  int xcd = orig & 7, bidx = orig >> 3;
  int flat = (xcd < r8) ? xcd * (q8 + 1) + bidx
                        : r8 * (q8 + 1) + (xcd - r8) * q8 + bidx;
  const int lx = flat % nx;
  int rest = flat / nx;
  const int ly = rest % my;
  const int lz = rest / my;

  const int m0 = ly << 8, n0 = lx << 8;
  const int ktiles = K >> 6;
  const int nt = nh * ktiles;

  f32x4 acc[8][4];
#pragma unroll
  for (int i = 0; i < 8; i++)
#pragma unroll
    for (int j = 0; j < 4; j++) acc[i][j] = (f32x4){0.f, 0.f, 0.f, 0.f};

  const int frow = lane & 15;
  const int kq = lane >> 4;
  const int swz = frow & 7;

  auto stageRound = [&](int matB, int r, int tt, int buf) {
    int h = tt / ktiles;
    int koff = (tt % ktiles) << 6;
    int s = (r << 9) + tid;
    int row = s >> 3;
    int ks = (s & 7) ^ (row & 7);
    const bf16* src;
    char* dst;
    if (!matB) {
      int gr = m0 + row; gr = gr < M ? gr : M - 1;
      src = A + (ll)lz * aZ + (ll)h * aH + (ll)gr * K + koff + (ks << 3);
      dst = lds + buf * 32768 + (((r << 3) + wave) << 10);
    } else {
      int gr = n0 + row; gr = gr < N ? gr : N - 1;
      src = Bt + (ll)lz * bZ + (ll)h * bH + (ll)gr * K + koff + (ks << 3);
      dst = lds + 65536 + buf * 32768 + (((r << 3) + wave) << 10);
    }
    gl_lds16(src, dst);
  };

  auto readA = [&](int fm, int kh, int cur) -> short8 {
    int row = wm * 128 + fm * 16 + frow;
    int slot = (kq + (kh << 2)) ^ swz;
    return *(const short8*)(lds + cur * 32768 + row * 128 + slot * 16);
  };
  auto readB = [&](int fn, int kh, int cur) -> short8 {
    int row = wn * 64 + fn * 16 + frow;
    int slot = (kq + (kh << 2)) ^ swz;
    return *(const short8*)(lds + 65536 + cur * 32768 + row * 128 + slot * 16);
  };

  stageRound(1, 0, 0, 0); stageRound(1, 1, 0, 0);
  stageRound(1, 2, 0, 0); stageRound(1, 3, 0, 0);
  stageRound(0, 0, 0, 0); stageRound(0, 2, 0, 0);
  stageRound(0, 1, 0, 0); stageRound(0, 3, 0, 0);

  int cur = 0;
  for (int tt = 0; tt < nt; ++tt) {
    const bool hasNext = (tt + 1 < nt);
    short8 bfr[4][2];
#pragma unroll
    for (int p = 0; p < 4; p++) {
      if (p == 0) {
        if (hasNext) asm volatile("s_waitcnt vmcnt(2)" ::: "memory");
        else         asm volatile("s_waitcnt vmcnt(0)" ::: "memory");
        __builtin_amdgcn_s_barrier();
        __builtin_amdgcn_sched_barrier(0);
#pragma unroll
        for (int fn = 0; fn < 4; fn++)
#pragma unroll
          for (int kh = 0; kh < 2; kh++) bfr[fn][kh] = readB(fn, kh, cur);
      }
      if (p == 2) {
        if (hasNext) asm volatile("s_waitcnt vmcnt(4)" ::: "memory");
        __builtin_amdgcn_s_barrier();
        __builtin_amdgcn_sched_barrier(0);
      }
      short8 a0k0 = readA(2 * p, 0, cur), a0k1 = readA(2 * p, 1, cur);
      short8 a1k0 = readA(2 * p + 1, 0, cur), a1k1 = readA(2 * p + 1, 1, cur);
      if (hasNext) {
        if (p == 0) { stageRound(1, 0, tt + 1, cur ^ 1); stageRound(1, 1, tt + 1, cur ^ 1); }
        else if (p == 1) { stageRound(1, 2, tt + 1, cur ^ 1); stageRound(1, 3, tt + 1, cur ^ 1); }
        else if (p == 2) { stageRound(0, 0, tt + 1, cur ^ 1); stageRound(0, 2, tt + 1, cur ^ 1); }
        else { stageRound(0, 1, tt + 1, cur ^ 1); stageRound(0, 3, tt + 1, cur ^ 1); }
      }
      __builtin_amdgcn_s_setprio(1);
#pragma unroll
      for (int fn = 0; fn < 4; fn++) {
        acc[2 * p][fn] = __builtin_amdgcn_mfma_f32_16x16x32_bf16(
            a0k0, bfr[fn][0], acc[2 * p][fn], 0, 0, 0);
        acc[2 * p][fn] = __builtin_amdgcn_mfma_f32_16x16x32_bf16(
            a0k1, bfr[fn][1], acc[2 * p][fn], 0, 0, 0);
        acc[2 * p + 1][fn] = __builtin_amdgcn_mfma_f32_16x16x32_bf16(
            a1k0, bfr[fn][0], acc[2 * p + 1][fn], 0, 0, 0);
        acc[2 * p + 1][fn] = __builtin_amdgcn_mfma_f32_16x16x32_bf16(
            a1k1, bfr[fn][1], acc[2 * p + 1][fn], 0, 0, 0);
      }
      __builtin_amdgcn_s_setprio(0);
    }
    cur ^= 1;
  }

  const int rq = kq << 2;
  float lsum = 0.f, lsq = 0.f;
#pragma unroll
  for (int fm = 0; fm < 8; fm++) {
    const int mrow = m0 + wm * 128 + fm * 16 + rq;
#pragma unroll
    for (int fn = 0; fn < 4; fn++) {
      const int ncol = n0 + wn * 64 + fn * 16 + frow;
      if (ncol >= N) continue;
      if constexpr (OUTMODE == 0) {
        float* Yp = (float*)Y + (ll)lz * yZ;
#pragma unroll
        for (int i = 0; i < 4; i++)
          if (mrow + i < M) {
            float v = acc[fm][fn][i] * scale;
            Yp[(ll)(mrow + i) * ldy + ncol] = v;
            if constexpr (STATS) { lsum += v; lsq += v * v; }
          }
      } else if constexpr (OUTMODE == 1) {
        bf16* Yp = (bf16*)Y + (ll)lz * yZ;
#pragma unroll
        for (int i = 0; i < 4; i++)
          if (mrow + i < M)
            Yp[(ll)(mrow + i) * ldy + ncol] =
                __float2bfloat16(acc[fm][fn][i] * scale);
      } else {
        if (mrow < M) {
          bf16* Yp = (bf16*)Y + (ll)lz * yZ + (ll)ncol * ldy + mrow;
#pragma unroll
          for (int i = 0; i < 4; i++)
            Yp[i] = __float2bfloat16(acc[fm][fn][i] * scale);
        }
      }
    }
  }
  if constexpr (STATS) {
    lsum = wredsum(lsum);
    lsq = wredsum(lsq);
    if (lane == 0) { rs1[wave] = lsum; rs2[wave] = lsq; }
    __syncthreads();
    if (tid == 0) {
      float s = 0.f, s2 = 0.f;
#pragma unroll
      for (int w = 0; w < 8; w++) { s += rs1[w]; s2 += rs2[w]; }
      int slot = ly * nx + lx;
      part[((ll)lz * 32 + slot) * 2] = s;
      part[((ll)lz * 32 + slot) * 2 + 1] = s2;
    }
  }
}

// ---------------------------------------------------------------------------
// pv_reduce: OtT[b][off] = 0.25 * sum_{s<4} part[(b*4+s)][off]  (bf16)
// ---------------------------------------------------------------------------
__global__ void __launch_bounds__(256) pv_reduce(const bf16* __restrict__ part,
                                                 bf16* __restrict__ out,
                                                 int planeShift) {
  const ll idx = ((ll)blockIdx.x * 256 + threadIdx.x) * 4;
  const int b = (int)(idx >> planeShift);
  const ll off = idx - ((ll)b << planeShift);
  const bf16* base = part + (((ll)b * 4) << planeShift) + off;
  float a0 = 0.f, a1 = 0.f, a2 = 0.f, a3 = 0.f;
#pragma unroll
  for (int s = 0; s < 4; s++) {
    ushort4 u = *(const ushort4*)(base + ((ll)s << planeShift));
    a0 += bfu2f(u.x); a1 += bfu2f(u.y); a2 += bfu2f(u.z); a3 += bfu2f(u.w);
  }
  ushort4 o;
  o.x = f2bfu(a0 * 0.25f);
  o.y = f2bfu(a1 * 0.25f);
  o.z = f2bfu(a2 * 0.25f);
  o.w = f2bfu(a3 * 0.25f);
  *(ushort4*)(out + idx) = o;
}

// ---------------------------------------------------------------------------
// K2: depthwise 3x3 (pad 1), optional fused l2norm. 256 thr, 4 px/thread.
// (kept for the K path, which needs row-major output + plane l2norm)
// ---------------------------------------------------------------------------
template <bool NORM>
__global__ void __launch_bounds__(256) dw3x3v(const bf16* __restrict__ in,
                                              const float* __restrict__ w9,
                                              bf16* __restrict__ out, int C) {
  __shared__ float tile[34][36];
  __shared__ float red[4];
  const int bc = blockIdx.x;
  const int ch = bc % C;
  const int tid = threadIdx.x;
  const int y = tid >> 3;
  const int x0 = (tid & 7) << 2;
  const bf16* ip = in + ((size_t)bc << 10);

  ushort4 u = *(const ushort4*)(ip + (y << 5) + x0);
  tile[y + 1][x0 + 1] = bfu2f(u.x);
  tile[y + 1][x0 + 2] = bfu2f(u.y);
  tile[y + 1][x0 + 3] = bfu2f(u.z);
  tile[y + 1][x0 + 4] = bfu2f(u.w);
  if (tid < 34) { tile[0][tid] = 0.f; tile[33][tid] = 0.f; }
  if (tid < 32) { tile[tid + 1][0] = 0.f; tile[tid + 1][33] = 0.f; }
  __syncthreads();

  const float* wc = w9 + ch * 9;
  float s[4] = {0.f, 0.f, 0.f, 0.f};
#pragma unroll
  for (int dy = 0; dy < 3; dy++) {
    const float* tr = &tile[y + dy][x0];
    float c0 = tr[0], c1 = tr[1], c2 = tr[2], c3 = tr[3], c4 = tr[4], c5 = tr[5];
    float wa = wc[dy * 3], wb = wc[dy * 3 + 1], wd = wc[dy * 3 + 2];
    s[0] += c0 * wa + c1 * wb + c2 * wd;
    s[1] += c1 * wa + c2 * wb + c3 * wd;
    s[2] += c2 * wa + c3 * wb + c4 * wd;
    s[3] += c3 * wa + c4 * wb + c5 * wd;
  }

  float inv = 1.f;
  if (NORM) {
    float ss = s[0] * s[0] + s[1] * s[1] + s[2] * s[2] + s[3] * s[3];
    ss = wredsum(ss);
    const int lane = tid & 63, wid = tid >> 6;
    if (lane == 0) red[wid] = ss;
    __syncthreads();
    inv = 1.0f / fmaxf(sqrtf(red[0] + red[1] + red[2] + red[3]), 1e-12f);
  }
  ushort4 o4;
  o4.x = f2bfu(s[0] * inv);
  o4.y = f2bfu(s[1] * inv);
  o4.z = f2bfu(s[2] * inv);
  o4.w = f2bfu(s[3] * inv);
  *(ushort4*)(out + ((size_t)bc << 10) + (y << 5) + x0) = o4;
}

// ---------------------------------------------------------------------------
// dwtcast: V path fused depthwise-3x3 + transpose. One pass.
// in  = vexp [b][3840 ch][1024 px]   (kvexp region)
// out = vt   [b*4+h][1024 px][960 j] bf16, out(px, j) = conv3x3(ch=h*960+j, px)
// grid: (30 j-tiles, 32 image rows, nb*4). block 256.
// ---------------------------------------------------------------------------
__global__ void __launch_bounds__(256) dwtcast(const bf16* __restrict__ in,
                                               const float* __restrict__ w9,
                                               bf16* __restrict__ out) {
  __shared__ float t[3][32][34];   // [row][ch][px+pad]; pad cols 0,33 = zero
  const int jt = blockIdx.x;       // 0..29
  const int y = blockIdx.y;        // 0..31
  const int bh = blockIdx.z;       // 0..nb*4-1
  const int b = bh >> 2, h = bh & 3;
  const int j0 = jt << 5;
  const int tid = threadIdx.x;

  // load: 3 rows x 32 ch x 32 px. 192 jobs of 16 px (2x u16x8 = 32B).
  if (tid < 192) {
    const int rr = tid / 64;            // 0..2  -> image row y-1+rr
    const int rem = tid - rr * 64;
    const int jc = rem >> 1;            // 0..31 channel in tile
    const int half = rem & 1;           // 0/1   -> px 0..15 / 16..31
    const int iy = y - 1 + rr;
    float* dstp = &t[rr][jc][1 + (half << 4)];
    if (iy < 0 || iy > 31) {
#pragma unroll
      for (int u = 0; u < 16; u++) dstp[u] = 0.f;
    } else {
      const bf16* src = in + (((ll)b * CKV_ + h * KV_ + j0 + jc) << 10) +
                        (iy << 5) + (half << 4);
      u16x8 v0 = *(const u16x8*)src;
      u16x8 v1 = *(const u16x8*)(src + 8);
#pragma unroll
      for (int u = 0; u < 8; u++) dstp[u] = bfu2f(v0[u]);
#pragma unroll
      for (int u = 0; u < 8; u++) dstp[8 + u] = bfu2f(v1[u]);
    }
  }
  // zero pad columns 0 and 33
  if (tid < 96) {
    const int rr = tid / 32, jc = tid - rr * 32;
    t[rr][jc][0] = 0.f;
    t[rr][jc][33] = 0.f;
  }
  __syncthreads();

  // compute: jp = tid&15 -> channels ch0=2*jp, ch0+1 ; xq = tid>>4 -> px xq, xq+16
  const int jp = tid & 15;
  const int xq = tid >> 4;
  const int ch0 = jp << 1;
  const float* wA = w9 + ((size_t)h * KV_ + j0 + ch0) * 9;
  const float* wB = wA + 9;

  bf16* orow = out + (ll)bh * 983040 + (ll)j0 + (ch0);
#pragma unroll
  for (int sx = 0; sx < 2; sx++) {
    const int x = xq + (sx << 4);
    float sA = 0.f, sB = 0.f;
#pragma unroll
    for (int dy = 0; dy < 3; dy++) {
      const float* rA = &t[dy][ch0][x];
      const float* rB = &t[dy][ch0 + 1][x];
      sA += rA[0] * wA[dy * 3] + rA[1] * wA[dy * 3 + 1] + rA[2] * wA[dy * 3 + 2];
      sB += rB[0] * wB[dy * 3] + rB[1] * wB[dy * 3 + 1] + rB[2] * wB[dy * 3 + 2];
    }
    const int n = (y << 5) + x;
    ushort2 o;
    o.x = f2bfu(sA);
    o.y = f2bfu(sB);
    *(ushort2*)(orow + (ll)n * 960) = o;
  }
}

// ---------------------------------------------------------------------------
// K3: grouped 3x3 (2 in-ch per group) + fused l2norm. 256 thr, 4 px/thread.
// ---------------------------------------------------------------------------
__global__ void __launch_bounds__(256) gq3x3v(const bf16* __restrict__ in,
                                              const float* __restrict__ wq,
                                              bf16* __restrict__ out, int C4) {
  __shared__ float t0[34][36];
  __shared__ float t1[34][36];
  __shared__ float red[4];
  const int bo = blockIdx.x;
  const int o = bo % C4;
  const int b = bo / C4;
  const int ic0 = (o >> 1) << 1;
  const int tid = threadIdx.x;
  const int y = tid >> 3;
  const int x0 = (tid & 7) << 2;
  const bf16* p0 = in + (((size_t)b * C4 + ic0) << 10);

  ushort4 u0 = *(const ushort4*)(p0 + (y << 5) + x0);
  ushort4 u1 = *(const ushort4*)(p0 + 1024 + (y << 5) + x0);
  t0[y + 1][x0 + 1] = bfu2f(u0.x);
  t0[y + 1][x0 + 2] = bfu2f(u0.y);
  t0[y + 1][x0 + 3] = bfu2f(u0.z);
  t0[y + 1][x0 + 4] = bfu2f(u0.w);
  t1[y + 1][x0 + 1] = bfu2f(u1.x);
  t1[y + 1][x0 + 2] = bfu2f(u1.y);
  t1[y + 1][x0 + 3] = bfu2f(u1.z);
  t1[y + 1][x0 + 4] = bfu2f(u1.w);
  if (tid < 34) {
    t0[0][tid] = 0.f; t0[33][tid] = 0.f;
    t1[0][tid] = 0.f; t1[33][tid] = 0.f;
  }
  if (tid < 32) {
    t0[tid + 1][0] = 0.f; t0[tid + 1][33] = 0.f;
    t1[tid + 1][0] = 0.f; t1[tid + 1][33] = 0.f;
  }
  __syncthreads();

  const float* w = wq + o * 18;
  float s[4] = {0.f, 0.f, 0.f, 0.f};
#pragma unroll
  for (int dy = 0; dy < 3; dy++) {
    {
      const float* tr = &t0[y + dy][x0];
      float c0 = tr[0], c1 = tr[1], c2 = tr[2], c3 = tr[3], c4 = tr[4], c5 = tr[5];
      float wa = w[dy * 3], wb = w[dy * 3 + 1], wd = w[dy * 3 + 2];
      s[0] += c0 * wa + c1 * wb + c2 * wd;
      s[1] += c1 * wa + c2 * wb + c3 * wd;
      s[2] += c2 * wa + c3 * wb + c4 * wd;
      s[3] += c3 * wa + c4 * wb + c5 * wd;
    }
    {
      const float* tr = &t1[y + dy][x0];
      float c0 = tr[0], c1 = tr[1], c2 = tr[2], c3 = tr[3], c4 = tr[4], c5 = tr[5];
      float wa = w[9 + dy * 3], wb = w[9 + dy * 3 + 1], wd = w[9 + dy * 3 + 2];
      s[0] += c0 * wa + c1 * wb + c2 * wd;
      s[1] += c1 * wa + c2 * wb + c3 * wd;
      s[2] += c2 * wa + c3 * wb + c4 * wd;
      s[3] += c3 * wa + c4 * wb + c5 * wd;
    }
  }

  float ss = s[0] * s[0] + s[1] * s[1] + s[2] * s[2] + s[3] * s[3];
  ss = wredsum(ss);
  const int lane = tid & 63, wid = tid >> 6;
  if (lane == 0) red[wid] = ss;
  __syncthreads();
  float inv = 1.0f / fmaxf(sqrtf(red[0] + red[1] + red[2] + red[3]), 1e-12f);

  ushort4 o4;
  o4.x = f2bfu(s[0] * inv);
  o4.y = f2bfu(s[1] * inv);
  o4.z = f2bfu(s[2] * inv);
  o4.w = f2bfu(s[3] * inv);
  *(ushort4*)(out + ((size_t)bo << 10) + (y << 5) + x0) = o4;
}

// ---------------------------------------------------------------------------
// K6: row softmax over 960 with inline InstanceNorm stats from partials.
// ---------------------------------------------------------------------------
__global__ void __launch_bounds__(256) softmax_rows(const float* __restrict__ attn,
                                                    const float* __restrict__ part,
                                                    int nslots,
                                                    bf16* __restrict__ probs, int c) {
  __shared__ float rm[4], rs[4];
  const int row = blockIdx.x;
  const int bh = row / c;
  const float* p = attn + (size_t)row * 960;
  bf16* op = probs + (size_t)row * 960;
  const int tid = threadIdx.x;

  float s = 0.f, s2 = 0.f;
  for (int i = 0; i < nslots; i++) {
    s += part[((ll)bh * 32 + i) * 2];
    s2 += part[((ll)bh * 32 + i) * 2 + 1];
  }
  const float n = (float)(c * 960);
  const float mu = s / n;
  const float var = s2 / n - mu * mu;
  const float rstd = rsqrtf(var + 1e-5f);

  float v[4];
  float mx = -1e30f;
#pragma unroll
  for (int u = 0; u < 4; u++) {
    int j = tid + (u << 8);
    if (j < 960) {
      v[u] = (p[j] - mu) * rstd;
      mx = fmaxf(mx, v[u]);
    } else {
      v[u] = -1e30f;
    }
  }
  mx = wredmax(mx);
  const int lane = tid & 63, wid = tid >> 6;
  if (lane == 0) rm[wid] = mx;
  __syncthreads();
  mx = fmaxf(fmaxf(rm[0], rm[1]), fmaxf(rm[2], rm[3]));

  float sum = 0.f;
#pragma unroll
  for (int u = 0; u < 4; u++) {
    int j = tid + (u << 8);
    if (j < 960) {
      v[u] = __expf(v[u] - mx);
      sum += v[u];
    }
  }
  sum = wredsum(sum);
  if (lane == 0) rs[wid] = sum;
  __syncthreads();
  sum = rs[0] + rs[1] + rs[2] + rs[3];
  const float inv = 1.0f / sum;
#pragma unroll
  for (int u = 0; u < 4; u++) {
    int j = tid + (u << 8);
    if (j < 960) op[j] = __float2bfloat16(v[u] * inv);
  }
}

// ---------------------------------------------------------------------------
// Workspace plan — identical to R6/R7/R8 (proven to fit).
// ---------------------------------------------------------------------------
static size_t p4_size(int nb) {
  const int chunkB = (nb + 1) / 2;
  size_t a = (size_t)nb * 4194304;
  size_t b = (size_t)nb * 1966080 + 7372800;
  size_t c = (size_t)chunkB * 7864320;
  size_t m = a > b ? a : b;
  return m > c ? m : c;
}
static size_t p5_size(int nb) {
  size_t a = (size_t)nb * 1048576;
  return a > 7372800 ? a : 7372800;
}
static size_t total_need(int nb) {
  return 3 * (size_t)nb * 7864320 + p4_size(nb) + p5_size(nb) + 3490816;
}

static void run_group(const float* const emb[4], const float* emb_all,
                      const float* const Wq[4],
                      const float* Wmk, const float* Wmv,
                      const float* Wk, const float* Wv,
                      bf16* Wm_all, bf16* Wp_all,
                      float* out, const size_t* out_off,
                      char* ws, int nb, hipStream_t stream) {
  const size_t szBig = (size_t)nb * 7864320;
  char* P1 = ws;
  char* P2 = P1 + szBig;
  char* P3 = P2 + szBig;
  char* P4 = P3 + szBig;
  char* P5 = P4 + p4_size(nb);
  char* FX = P5 + p5_size(nb);

  bf16* kbuf = (bf16*)P1;
  bf16* vt   = (bf16*)P2;
  bf16* kvexp = (bf16*)P3;
  float* attnb = (float*)P3;
  bf16* pvpart = (bf16*)P3;   // PV per-head partials (attnb dead post-softmax)
  bf16* embT_all = (bf16*)P4;
  bf16* Wmv_bf = (bf16*)(P4 + (size_t)nb * 1966080);
  bf16* qbuf = (bf16*)P4;
  bf16* probsb = (bf16*)P4;
  bf16* Wmk_bf = (bf16*)P5;
  bf16* OtT = (bf16*)P5;
  float* part = (float*)(FX + 3482112);   // 8192 B

  const float qk_scale = 1.0f / sqrtf((float)KV_);
  const int CHs[4] = {64, 128, 256, 512};
  const size_t wm_off[4] = {0, 16384, 81920, 344064};
  const size_t wp_off[4] = {0, 4096, 20480, 86016};

  // -- prologue: shared K/V --------------------------------------------------
  castw<<<3600, 256, 0, stream>>>(Wmk, Wmk_bf, 3686400);
  castw<<<3600, 256, 0, stream>>>(Wmv, Wmv_bf, 3686400);
  tcast<float><<<dim3(32, 30, nb), 256, 0, stream>>>(emb_all, embT_all, 960,
                                                     983040LL, 983040LL);
  gemm8<1, false><<<dim3(4, 15, nb), 512, 0, stream>>>(
      Wmk_bf, embT_all, kvexp, 3840, 1024, 960, 1, 0, 0, 983040LL, 0,
      3932160LL, 1024, 1.f, nullptr);
  dw3x3v<true><<<nb * CKV_, 256, 0, stream>>>(kvexp, Wk, kbuf, CKV_);
  gemm8<1, false><<<dim3(4, 15, nb), 512, 0, stream>>>(
      Wmv_bf, embT_all, kvexp, 3840, 1024, 960, 1, 0, 0, 983040LL, 0,
      3932160LL, 1024, 1.f, nullptr);
  // fused V depthwise-3x3 + transpose -> vt (single pass)
  dwtcast<<<dim3(30, 32, nb * 4), 256, 0, stream>>>(kvexp, Wv, vt);

  // -- branches --------------------------------------------------------------
  for (int br = 0; br < 4; br++) {
    const int c = CHs[br];
    const int C4 = c * 4;
    const int mtiles = (c + 127) / 128;
    bf16* Wm_bf = Wm_all + wm_off[br];
    bf16* Wp_bf = Wp_all + wp_off[br];
    int planeShift = 10;
    for (int t = c; t > 1; t >>= 1) planeShift++;   // log2(1024*c)

    // embT_i in P4 (qbuf region)
    tcast<float><<<dim3(32, c / 32, nb), 256, 0, stream>>>(
        emb[br], qbuf, c, (ll)c * 1024, (ll)c * 1024);
    // q-expand -> P3
    if (c == 512) {
      gemm8<1, false><<<dim3(4, C4 / 256, nb), 512, 0, stream>>>(
          Wm_bf, qbuf, kvexp, C4, 1024, c, 1, 0, 0, (ll)c * 1024, 0,
          (ll)C4 * 1024, 1024, 1.f, nullptr);
    } else {
      gemm_mfma<1, false><<<dim3(8, C4 / 128, nb), 256, 0, stream>>>(
          Wm_bf, qbuf, kvexp, C4, 1024, c, 1, 0, 0, (ll)c * 1024, 0,
          (ll)C4 * 1024, 1024, 1.f, nullptr);
    }
    // grouped 3x3 + l2norm: P3 -> qbuf (P4)
    gq3x3v<<<nb * C4, 256, 0, stream>>>(kvexp, Wq[br], qbuf, C4);
    // attn = scale * q k^T -> attnb (P3), fused stats partials
    int nslots;
    if (c == 512) {
      gemm8<0, true><<<dim3(4, c / 256, nb * 4), 512, 0, stream>>>(
          qbuf, kbuf, attnb, c, 960, 1024, 1, (ll)c * 1024, 0, 983040LL, 0,
          (ll)c * 960, 960, qk_scale, part);
      nslots = (c / 256) * 4;
    } else {
      gemm_mfma<0, true><<<dim3(8, mtiles, nb * 4), 256, 0, stream>>>(
          qbuf, kbuf, attnb, c, 960, 1024, 1, (ll)c * 1024, 0, 983040LL, 0,
          (ll)c * 960, 960, qk_scale, part);
      nslots = mtiles * 8;
    }
    softmax_rows<<<nb * 4 * c, 256, 0, stream>>>(attnb, part, nslots, probsb, c);
    // PV split-head: z=(b,h), nh=1, bf16 transposed partials -> P3
    if (c == 512) {
      gemm8<2, false><<<dim3(4, c / 256, nb * 4), 512, 0, stream>>>(
          probsb, vt, pvpart, c, 1024, 960, 1, (ll)c * 960, 0, 983040LL, 0,
          (ll)1024 * c, c, 1.f, nullptr);
    } else {
      gemm_mfma<2, false><<<dim3(8, mtiles, nb * 4), 256, 0, stream>>>(
          probsb, vt, pvpart, c, 1024, 960, 1, (ll)c * 960, 0, 983040LL, 0,
          (ll)1024 * c, c, 1.f, nullptr);
    }
    // head-sum + 0.25 -> OtT (P5)
    pv_reduce<<<nb * c, 256, 0, stream>>>(pvpart, OtT, planeShift);
    // final projection -> f32 d_out
    gemm_mfma<0, false><<<dim3(8, mtiles, nb), 256, 0, stream>>>(
        Wp_bf, OtT, out + out_off[br], c, 1024, c, 1, 0, 0,
        (ll)1024 * c, 0, (ll)c * 1024, 1024, 1.f, nullptr);
  }
}

extern "C" void kernel_launch(void* const* d_in, const int* in_sizes, int n_in,
                              void* d_out, int out_size, void* d_ws, size_t ws_size,
                              hipStream_t stream) {
  const float* emb[4] = {(const float*)d_in[0], (const float*)d_in[1],
                         (const float*)d_in[2], (const float*)d_in[3]};
  const float* emb_all = (const float*)d_in[4];
  const float* Wm[4] = {(const float*)d_in[5], (const float*)d_in[8],
                        (const float*)d_in[11], (const float*)d_in[14]};
  const float* Wq[4] = {(const float*)d_in[6], (const float*)d_in[9],
                        (const float*)d_in[12], (const float*)d_in[15]};
  const float* Wp[4] = {(const float*)d_in[7], (const float*)d_in[10],
                        (const float*)d_in[13], (const float*)d_in[16]};
  const float* Wmk = (const float*)d_in[17];
  const float* Wmv = (const float*)d_in[18];
  const float* Wk = (const float*)d_in[19];
  const float* Wv = (const float*)d_in[20];
  float* out = (float*)d_out;

  const int CHs[4] = {64, 128, 256, 512};
  const size_t out_off_full[4] = {0, 524288, 1572864, 3670016};
  const size_t wm_off[4] = {0, 16384, 81920, 344064};
  const size_t wp_off[4] = {0, 4096, 20480, 86016};

  int nb = 1;
  if (ws_size >= total_need(8)) nb = 8;
  else if (ws_size >= total_need(4)) nb = 4;
  else if (ws_size >= total_need(2)) nb = 2;

  char* FX = (char*)d_ws + 3 * (size_t)nb * 7864320 + p4_size(nb) + p5_size(nb);
  bf16* Wm_all = (bf16*)FX;
  bf16* Wp_all = (bf16*)(FX + 2785280);

  for (int br = 0; br < 4; br++) {
    const int c = CHs[br];
    castw<<<(4 * c * c / 4 + 255) / 256, 256, 0, stream>>>(
        Wm[br], Wm_all + wm_off[br], 4 * c * c);
    castw<<<(c * c / 4 + 255) / 256, 256, 0, stream>>>(
        Wp[br], Wp_all + wp_off[br], c * c);
  }

  for (int b0 = 0; b0 < B_; b0 += nb) {
    const float* embB[4];
    for (int i = 0; i < 4; i++) embB[i] = emb[i] + (size_t)b0 * CHs[i] * HW_;
    const float* emb_allB = emb_all + (size_t)b0 * KV_ * HW_;
    size_t out_offB[4];
    for (int i = 0; i < 4; i++)
      out_offB[i] = out_off_full[i] + (size_t)b0 * CHs[i] * HW_;
    run_group(embB, emb_allB, Wq, Wmk, Wmv, Wk, Wv, Wm_all, Wp_all,
              out, out_offB, (char*)d_ws, nb, stream);
  }
}